// Round 11
// baseline (477.070 us; speedup 1.0000x reference)
//
#include <hip/hip_runtime.h>

#define N2 2048      // B*P
#define N8 8192      // B*P*UP
#define CDIM 384
#define H1C 192      // C/2
#define H2C 96       // C/4
#define PDIM 512
#define KRR 16
#define FOLDH 256
#define XCAP 256
#define XTILE 1024
#define INFF 3.0e38f

__device__ __forceinline__ float frelu(float x) { return x > 0.f ? x : 0.f; }

// ---------------- 64-lane bitonic sorts (ascending) --------------------------------
__device__ __forceinline__ void bitonic64_val(float& d, int lane) {
    #pragma unroll
    for (int k = 2; k <= 64; k <<= 1) {
        #pragma unroll
        for (int j = k >> 1; j > 0; j >>= 1) {
            float od = __shfl_xor(d, j);
            bool lower = (lane & j) == 0;
            bool olt = od < d;
            bool take = lower ? olt : !olt;
            if (lane & k) take = !take;
            if (take) d = od;
        }
    }
}

__device__ __forceinline__ void bitonic64_pair(float& d, int& c, int lane) {
    #pragma unroll
    for (int k = 2; k <= 64; k <<= 1) {
        #pragma unroll
        for (int j = k >> 1; j > 0; j >>= 1) {
            float od = __shfl_xor(d, j);
            int   oc = __shfl_xor(c, j);
            bool lower = (lane & j) == 0;
            bool olt = (od < d) || (od == d && oc < c);
            bool take = lower ? olt : !olt;
            if (lane & k) take = !take;
            if (take) { d = od; c = oc; }
        }
    }
}

// ---------------- slow exact select fallback (cnt > 64, rare) ----------------------
__device__ __forceinline__ void select_slow(const float* bd, const int* bi, int cnt,
                                            int ksel, int row, int n, int* out, int lane) {
    float cd[4]; int cix[4];
    #pragma unroll
    for (int s = 0; s < 4; ++s) {
        int c = lane + 64*s;
        bool v = c < cnt;
        cd[s]  = v ? bd[c] : INFF;
        cix[s] = v ? bi[c] : 0x7fffffff;
    }
    for (int r = 0; r < ksel; ++r) {
        float lv = cd[0]; int li = cix[0];
        #pragma unroll
        for (int s = 1; s < 4; ++s) {
            if (cd[s] < lv || (cd[s] == lv && cix[s] < li)) { lv = cd[s]; li = cix[s]; }
        }
        float wv = lv; int wi = li;
        #pragma unroll
        for (int s = 1; s < 64; s <<= 1) {
            float ov = __shfl_xor(wv, s); int oi = __shfl_xor(wi, s);
            if (ov < wv || (ov == wv && oi < wi)) { wv = ov; wi = oi; }
        }
        if (lane == 0) {
            int safe = ((unsigned)wi < (unsigned)n) ? wi : ((row + 1) & (n - 1));
            out[row*ksel + r] = safe;
        }
        #pragma unroll
        for (int s = 0; s < 4; ++s) {
            if (cd[s] == wv && cix[s] == wi) { cd[s] = INFF; cix[s] = 0x7fffffff; }
        }
    }
}

// ---------------- row squared norms (wave per row; single + paired) ----------------
__global__ __launch_bounds__(256) void rowsq_kernel(const float* __restrict__ x,
                                                    float* __restrict__ sq, int d) {
    int wave = threadIdx.x >> 6, lane = threadIdx.x & 63;
    int row = blockIdx.x*4 + wave;
    float acc = 0.f;
    for (int k = lane; k < d; k += 64) { float v = x[(size_t)row*d + k]; acc += v*v; }
    #pragma unroll
    for (int s = 1; s < 64; s <<= 1) acc += __shfl_xor(acc, s);
    if (lane == 0) sq[row] = acc;
}

__global__ __launch_bounds__(256) void rowsqpair_kernel(const float* __restrict__ xA,
                                                        float* __restrict__ sqA,
                                                        const float* __restrict__ xB,
                                                        float* __restrict__ sqB, int d) {
    const float* x = blockIdx.y ? xB : xA;
    float* sq = blockIdx.y ? sqB : sqA;
    int wave = threadIdx.x >> 6, lane = threadIdx.x & 63;
    int row = blockIdx.x*4 + wave;
    float acc = 0.f;
    for (int k = lane; k < d; k += 64) { float v = x[(size_t)row*d + k]; acc += v*v; }
    #pragma unroll
    for (int s = 1; s < 64; s <<= 1) acc += __shfl_xor(acc, s);
    if (lane == 0) sq[row] = acc;
}

// ---------------- triangular symmetric dist: direct + mirrored tile ----------------
__device__ __forceinline__ void disttri_body(const float* __restrict__ x, const float* __restrict__ sq,
                                             float* __restrict__ dist, int n, int K) {
    int l = blockIdx.x;
    int by = (int)((sqrtf(8.f*(float)l + 1.f) - 1.f)*0.5f);
    while ((by+1)*(by+2)/2 <= l) ++by;
    while (by*(by+1)/2 > l) --by;
    int bx = l - by*(by+1)/2;
    int row0 = by*64, col0 = bx*64;
    __shared__ __align__(16) float As[16][68];
    __shared__ __align__(16) float Bs[16][68];
    __shared__ __align__(16) float T[64][68];
    int tx = threadIdx.x, ty = threadIdx.y;
    int t = ty*16 + tx;
    float acc[4][4] = {};
    for (int k0 = 0; k0 < K; k0 += 16) {
        #pragma unroll
        for (int r = 0; r < 4; ++r) {
            int e = t + 256*r; int kk = e & 15, mm = e >> 4;
            As[kk][mm] = x[(size_t)(row0+mm)*K + k0+kk];
            Bs[kk][mm] = x[(size_t)(col0+mm)*K + k0+kk];
        }
        __syncthreads();
        #pragma unroll
        for (int kk = 0; kk < 16; ++kk) {
            float4 a4 = *(const float4*)&As[kk][ty*4];
            float4 b4 = *(const float4*)&Bs[kk][tx*4];
            acc[0][0] += a4.x*b4.x; acc[0][1] += a4.x*b4.y; acc[0][2] += a4.x*b4.z; acc[0][3] += a4.x*b4.w;
            acc[1][0] += a4.y*b4.x; acc[1][1] += a4.y*b4.y; acc[1][2] += a4.y*b4.z; acc[1][3] += a4.y*b4.w;
            acc[2][0] += a4.z*b4.x; acc[2][1] += a4.z*b4.y; acc[2][2] += a4.z*b4.z; acc[2][3] += a4.z*b4.w;
            acc[3][0] += a4.w*b4.x; acc[3][1] += a4.w*b4.y; acc[3][2] += a4.w*b4.z; acc[3][3] += a4.w*b4.w;
        }
        __syncthreads();
    }
    bool mirror = (row0 != col0);
    #pragma unroll
    for (int i2 = 0; i2 < 4; ++i2) {
        int row = row0 + ty*4 + i2;
        float sr = sq[row];
        float4 o;
        o.x = sr + sq[col0+tx*4+0] - 2.f*acc[i2][0];
        o.y = sr + sq[col0+tx*4+1] - 2.f*acc[i2][1];
        o.z = sr + sq[col0+tx*4+2] - 2.f*acc[i2][2];
        o.w = sr + sq[col0+tx*4+3] - 2.f*acc[i2][3];
        *(float4*)&dist[(size_t)row*n + col0 + tx*4] = o;
        if (mirror) {
            T[tx*4+0][ty*4+i2] = o.x;
            T[tx*4+1][ty*4+i2] = o.y;
            T[tx*4+2][ty*4+i2] = o.z;
            T[tx*4+3][ty*4+i2] = o.w;
        }
    }
    if (mirror) {
        __syncthreads();
        #pragma unroll
        for (int i2 = 0; i2 < 4; ++i2) {
            int orow = col0 + ty*4 + i2;
            float4 o = *(const float4*)&T[ty*4+i2][tx*4];
            *(float4*)&dist[(size_t)orow*n + row0 + tx*4] = o;
        }
    }
}

__global__ __launch_bounds__(256) void dist64tri_kernel(const float* __restrict__ x,
                                                        const float* __restrict__ sq,
                                                        float* __restrict__ dist, int n, int K) {
    disttri_body(x, sq, dist, n, K);
}

__global__ __launch_bounds__(256) void distpairtri_kernel(const float* __restrict__ xA,
                                                          const float* __restrict__ sqA,
                                                          float* __restrict__ dA,
                                                          const float* __restrict__ xB,
                                                          const float* __restrict__ sqB,
                                                          float* __restrict__ dB, int n, int K) {
    const float* x  = blockIdx.z ? xB : xA;
    const float* sq = blockIdx.z ? sqB : sqA;
    float* dist     = blockIdx.z ? dB : dA;
    disttri_body(x, sq, dist, n, K);
}

// ---------------- shared 64x64 GEMM tile body: C = A @ (Bw - BwB) + bias -----------
__device__ __forceinline__ void gemm_body(const float* __restrict__ A, const float* __restrict__ Bw,
                                          const float* __restrict__ BwB, const float* __restrict__ bias,
                                          float* __restrict__ C, int m, int K) {
    __shared__ __align__(16) float As[16][68];
    __shared__ __align__(16) float Bs[16][68];
    int tx = threadIdx.x, ty = threadIdx.y;
    int t = ty*16 + tx;
    int row0 = blockIdx.y*64, col0 = blockIdx.x*64;
    float acc[4][4] = {};
    for (int k0 = 0; k0 < K; k0 += 16) {
        #pragma unroll
        for (int r = 0; r < 4; ++r) {
            int e = t + 256*r; int kk = e & 15, mm = e >> 4;
            As[kk][mm] = (k0 + kk < K) ? A[(size_t)(row0+mm)*K + k0+kk] : 0.f;
        }
        #pragma unroll
        for (int r = 0; r < 4; ++r) {
            int e = t + 256*r; int nn = e & 63, kk = e >> 6;
            int col = col0 + nn, k = k0 + kk;
            float bv = 0.f;
            if (k < K && col < m) {
                bv = Bw[(size_t)k*m + col];
                if (BwB) bv -= BwB[(size_t)k*m + col];
            }
            Bs[kk][nn] = bv;
        }
        __syncthreads();
        #pragma unroll
        for (int kk = 0; kk < 16; ++kk) {
            float4 a4 = *(const float4*)&As[kk][ty*4];
            float4 b4 = *(const float4*)&Bs[kk][tx*4];
            acc[0][0] += a4.x*b4.x; acc[0][1] += a4.x*b4.y; acc[0][2] += a4.x*b4.z; acc[0][3] += a4.x*b4.w;
            acc[1][0] += a4.y*b4.x; acc[1][1] += a4.y*b4.y; acc[1][2] += a4.y*b4.z; acc[1][3] += a4.y*b4.w;
            acc[2][0] += a4.z*b4.x; acc[2][1] += a4.z*b4.y; acc[2][2] += a4.z*b4.z; acc[2][3] += a4.z*b4.w;
            acc[3][0] += a4.w*b4.x; acc[3][1] += a4.w*b4.y; acc[3][2] += a4.w*b4.z; acc[3][3] += a4.w*b4.w;
        }
        __syncthreads();
    }
    #pragma unroll
    for (int i2 = 0; i2 < 4; ++i2) {
        int row = row0 + ty*4 + i2;
        #pragma unroll
        for (int j2 = 0; j2 < 4; ++j2) {
            int col = col0 + tx*4 + j2;
            if (col < m) C[(size_t)row*m + col] = acc[i2][j2] + (bias ? bias[col] : 0.f);
        }
    }
}

__global__ __launch_bounds__(256) void gemmquad_kernel(
    const float* A0, const float* Bw0, const float* BwB0, const float* bias0, float* C0,
    const float* A1, const float* Bw1, const float* BwB1, const float* bias1, float* C1,
    const float* A2, const float* Bw2, const float* BwB2, const float* bias2, float* C2,
    const float* A3, const float* Bw3, const float* BwB3, const float* bias3, float* C3,
    int m, int K) {
    int z = blockIdx.z;
    const float* A    = (z==0)?A0 :(z==1)?A1 :(z==2)?A2 :A3;
    const float* Bw   = (z==0)?Bw0:(z==1)?Bw1:(z==2)?Bw2:Bw3;
    const float* BwB  = (z==0)?BwB0:(z==1)?BwB1:(z==2)?BwB2:BwB3;
    const float* bias = (z==0)?bias0:(z==1)?bias1:(z==2)?bias2:bias3;
    float* C          = (z==0)?C0 :(z==1)?C1 :(z==2)?C2 :C3;
    gemm_body(A, Bw, BwB, bias, C, m, K);
}

// ---------------- EdgeConv layer-2 gather-GEMM with FUSED max-reduce ---------------
// Row (i*EPT+e): e<EREAL -> real edge (SELF: e==0 is self), else duplicate self
// (max unaffected). Each 64-row block covers exactly 64/EPT points; after the
// k-loop the tile is staged in LDS and reduced over e, writing h[i][col] only.
template<int EPT, int SELF, int EREAL, int IDXS, int YT>
__device__ __forceinline__ void edge_fused_body(const float* __restrict__ u, const float* __restrict__ v,
                                                const int* __restrict__ idx,
                                                const float* __restrict__ Bw, const float* __restrict__ bias,
                                                float* __restrict__ hout, int m, int K, int npts) {
    if ((int)blockIdx.y >= YT) return;
    constexpr int LOG2EPT = (EPT == 16) ? 4 : (EPT == 8) ? 3 : 2;
    constexpr int PPB = 64 / EPT;
    __shared__ __align__(16) float As[16][68];
    __shared__ __align__(16) float Bs[16][68];
    __shared__ __align__(16) float Cs[64][68];
    int tx = threadIdx.x, ty = threadIdx.y;
    int t = ty*16 + tx;
    int row0 = blockIdx.y*64, col0 = blockIdx.x*64;
    float acc[4][4] = {};
    for (int k0 = 0; k0 < K; k0 += 16) {
        #pragma unroll
        for (int r = 0; r < 4; ++r) {
            int e_ = t + 256*r; int kk = e_ & 15, mm = e_ >> 4;
            int row = row0 + mm, k = k0 + kk;
            int i = row >> LOG2EPT;
            int e = row - (i << LOG2EPT);
            int j;
            if (SELF && e == 0) j = i;
            else if (e < EREAL) j = idx[i*IDXS + (e - SELF)];
            else j = i;
            j = ((unsigned)j < (unsigned)npts) ? j : i;
            As[kk][mm] = frelu(u[(size_t)i*K + k] + v[(size_t)j*K + k]);
        }
        #pragma unroll
        for (int r = 0; r < 4; ++r) {
            int e_ = t + 256*r; int nn = e_ & 63, kk = e_ >> 6;
            int col = col0 + nn;
            Bs[kk][nn] = (col < m) ? Bw[(size_t)(k0+kk)*m + col] : 0.f;
        }
        __syncthreads();
        #pragma unroll
        for (int kk = 0; kk < 16; ++kk) {
            float4 a4 = *(const float4*)&As[kk][ty*4];
            float4 b4 = *(const float4*)&Bs[kk][tx*4];
            acc[0][0] += a4.x*b4.x; acc[0][1] += a4.x*b4.y; acc[0][2] += a4.x*b4.z; acc[0][3] += a4.x*b4.w;
            acc[1][0] += a4.y*b4.x; acc[1][1] += a4.y*b4.y; acc[1][2] += a4.y*b4.z; acc[1][3] += a4.y*b4.w;
            acc[2][0] += a4.z*b4.x; acc[2][1] += a4.z*b4.y; acc[2][2] += a4.z*b4.z; acc[2][3] += a4.z*b4.w;
            acc[3][0] += a4.w*b4.x; acc[3][1] += a4.w*b4.y; acc[3][2] += a4.w*b4.z; acc[3][3] += a4.w*b4.w;
        }
        __syncthreads();
    }
    #pragma unroll
    for (int i2 = 0; i2 < 4; ++i2) {
        #pragma unroll
        for (int j2 = 0; j2 < 4; ++j2) {
            int col = col0 + tx*4 + j2;
            Cs[ty*4+i2][tx*4+j2] = acc[i2][j2] + ((col < m) ? bias[col] : 0.f);
        }
    }
    __syncthreads();
    for (int tt = t; tt < PPB*64; tt += 256) {
        int p = tt >> 6, c = tt & 63;
        int col = col0 + c;
        if (col < m) {
            float best = Cs[p*EPT][c];
            #pragma unroll
            for (int e = 1; e < EPT; ++e) best = fmaxf(best, Cs[p*EPT + e][c]);
            int i = (row0 >> LOG2EPT) + p;
            hout[(size_t)i*m + col] = best;
        }
    }
}

__global__ __launch_bounds__(256) void edge_fused1_kernel(const float* u1, const float* v1,
                                                          const int* cidx1,
                                                          const float* Bw, const float* bias,
                                                          float* h_ctx, float* h_tgt, int npts) {
    if (blockIdx.z == 0) edge_fused_body<16,0,16,16,512>(u1, v1, cidx1, Bw, bias, h_ctx, H1C, H1C, npts);
    else                 edge_fused_body<8,1,5,16,256>(u1, v1, cidx1, Bw, bias, h_tgt, H1C, H1C, npts);
}

__global__ __launch_bounds__(256) void edge_fused2_kernel(const float* u2c, const float* v2c,
                                                          const float* u2t, const float* v2t,
                                                          const int* cidx2, const int* tidx2,
                                                          const float* Bw, const float* bias,
                                                          float* cfeat, float* tfeat, int npts) {
    if (blockIdx.z == 0) edge_fused_body<8,0,8,8,256>(u2c, v2c, cidx2, Bw, bias, cfeat, H2C, H2C, npts);
    else                 edge_fused_body<4,1,3,2,128>(u2t, v2t, tidx2, Bw, bias, tfeat, H2C, H2C, npts);
}

// ---------------- ctx deform head: out = xyz + 0.05 * mlp2(cfeat) ------------------
__global__ __launch_bounds__(128) void cdef_kernel(const float* __restrict__ cfeat,
                                                   const float* __restrict__ cdw1, const float* __restrict__ cdb1,
                                                   const float* __restrict__ cdw2, const float* __restrict__ cdb2,
                                                   const float* __restrict__ ctx_xyz,
                                                   float* __restrict__ out_ctx) {
    int i = blockIdx.x, tid = threadIdx.x, wave = tid >> 6, lane = tid & 63;
    __shared__ float sf_[96], st2_[96];
    if (tid < 96) sf_[tid] = cfeat[(size_t)i*H2C + tid];
    __syncthreads();
    if (tid < 96) {
        float a = cdb1[tid];
        for (int k = 0; k < 96; ++k) a += sf_[k]*cdw1[k*96 + tid];
        st2_[tid] = frelu(a);
    }
    __syncthreads();
    if (wave == 0) {
        float s0 = st2_[lane];
        float p0 = s0*cdw2[lane*3+0], p1 = s0*cdw2[lane*3+1], p2 = s0*cdw2[lane*3+2];
        if (lane < 32) {
            float s1 = st2_[lane+64];
            p0 += s1*cdw2[(lane+64)*3+0];
            p1 += s1*cdw2[(lane+64)*3+1];
            p2 += s1*cdw2[(lane+64)*3+2];
        }
        #pragma unroll
        for (int s = 1; s < 64; s <<= 1) {
            p0 += __shfl_xor(p0, s); p1 += __shfl_xor(p1, s); p2 += __shfl_xor(p2, s);
        }
        if (lane == 0) {
            out_ctx[i*3+0] = ctx_xyz[i*3+0] + 0.05f*(cdb2[0] + p0);
            out_ctx[i*3+1] = ctx_xyz[i*3+1] + 0.05f*(cdb2[1] + p1);
            out_ctx[i*3+2] = ctx_xyz[i*3+2] + 0.05f*(cdb2[2] + p2);
        }
    }
}

// refiner gather-GEMM pair: A row gathered from [featd(96) | xyzg(3)], K = 99
__global__ __launch_bounds__(256) void gatherpair_kernel(
    const float* __restrict__ featd, const float* __restrict__ xyzg,
    const float* Bw0, const float* BwB0, const float* bias0, float* C0,
    const float* Bw1, const float* BwB1, const float* bias1, float* C1,
    int m, int K) {
    int z = blockIdx.z;
    const float* Bw   = z ? Bw1 : Bw0;
    const float* BwB  = z ? BwB1 : BwB0;
    const float* bias = z ? bias1 : bias0;
    float* C          = z ? C1 : C0;
    __shared__ __align__(16) float As[16][68];
    __shared__ __align__(16) float Bs[16][68];
    int tx = threadIdx.x, ty = threadIdx.y;
    int t = ty*16 + tx;
    int row0 = blockIdx.y*64, col0 = blockIdx.x*64;
    float acc[4][4] = {};
    for (int k0 = 0; k0 < K; k0 += 16) {
        #pragma unroll
        for (int r = 0; r < 4; ++r) {
            int e = t + 256*r; int kk = e & 15, mm = e >> 4;
            int k = k0 + kk, grow = row0 + mm;
            float av = 0.f;
            if (k < K) {
                if (k < 96) { int b = grow >> 11, p = (grow & 2047) >> 2;
                              av = featd[(size_t)(b*PDIM + p)*H2C + k]; }
                else av = xyzg[(size_t)grow*3 + (k - 96)];
            }
            As[kk][mm] = av;
        }
        #pragma unroll
        for (int r = 0; r < 4; ++r) {
            int e = t + 256*r; int nn = e & 63, kk = e >> 6;
            int col = col0 + nn, k = k0 + kk;
            float bv = 0.f;
            if (k < K && col < m) {
                bv = Bw[(size_t)k*m + col];
                if (BwB) bv -= BwB[(size_t)k*m + col];
            }
            Bs[kk][nn] = bv;
        }
        __syncthreads();
        #pragma unroll
        for (int kk = 0; kk < 16; ++kk) {
            float4 a4 = *(const float4*)&As[kk][ty*4];
            float4 b4 = *(const float4*)&Bs[kk][tx*4];
            acc[0][0] += a4.x*b4.x; acc[0][1] += a4.x*b4.y; acc[0][2] += a4.x*b4.z; acc[0][3] += a4.x*b4.w;
            acc[1][0] += a4.y*b4.x; acc[1][1] += a4.y*b4.y; acc[1][2] += a4.y*b4.z; acc[1][3] += a4.y*b4.w;
            acc[2][0] += a4.z*b4.x; acc[2][1] += a4.z*b4.y; acc[2][2] += a4.z*b4.z; acc[2][3] += a4.z*b4.w;
            acc[3][0] += a4.w*b4.x; acc[3][1] += a4.w*b4.y; acc[3][2] += a4.w*b4.z; acc[3][3] += a4.w*b4.w;
        }
        __syncthreads();
    }
    #pragma unroll
    for (int i2 = 0; i2 < 4; ++i2) {
        int row = row0 + ty*4 + i2;
        #pragma unroll
        for (int j2 = 0; j2 < 4; ++j2) {
            int col = col0 + tx*4 + j2;
            if (col < m) C[(size_t)row*m + col] = acc[i2][j2] + (bias ? bias[col] : 0.f);
        }
    }
}

// ---------------- knn from dist rows (4 rows/block, bitonic select) ----------------
__global__ __launch_bounds__(256) void knn_dist_rt_kernel(const float* __restrict__ dA,
                                                          const float* __restrict__ dB, int n,
                                                          int* __restrict__ outA, int* __restrict__ outB,
                                                          int kA, int kB, int nblkA) {
    int wave = threadIdx.x >> 6, lane = threadIdx.x & 63;
    bool useB = (int)blockIdx.x >= nblkA;
    const float* dist = useB ? dB : dA;
    int* out = useB ? outB : outA;
    int ksel = useB ? kB : kA;
    int bx = useB ? (int)blockIdx.x - nblkA : (int)blockIdx.x;
    int row = bx*4 + wave;
    __shared__ float bufd[4][XCAP];
    __shared__ int   bufi[4][XCAP];
    __shared__ int   lcnt[4];
    const float4* drow = (const float4*)(dist + (size_t)row*n);
    int nq = n >> 2;
    float mv = INFF;
    for (int i = lane; i < nq; i += 64) {
        float4 d4 = drow[i]; int base = i*4;
        float a = (base+0 == row) ? INFF : d4.x;
        float b = (base+1 == row) ? INFF : d4.y;
        float c = (base+2 == row) ? INFF : d4.z;
        float d = (base+3 == row) ? INFF : d4.w;
        mv = fminf(mv, fminf(fminf(a,b), fminf(c,d)));
    }
    float sd = mv;
    bitonic64_val(sd, lane);
    float Tv = __shfl(sd, ksel - 1);
    if (lane == 0) lcnt[wave] = 0;
    for (int i = lane; i < nq; i += 64) {
        float4 d4 = drow[i]; int base = i*4;
        float dv4[4] = {d4.x, d4.y, d4.z, d4.w};
        #pragma unroll
        for (int q = 0; q < 4; ++q) {
            int col = base + q;
            if (col != row && dv4[q] <= Tv) {
                int pos = atomicAdd(&lcnt[wave], 1);
                if (pos < XCAP) { bufd[wave][pos] = dv4[q]; bufi[wave][pos] = col; }
            }
        }
    }
    int cnt = lcnt[wave]; if (cnt > XCAP) cnt = XCAP;
    if (cnt <= 64) {
        float d = (lane < cnt) ? bufd[wave][lane] : INFF;
        int   c = (lane < cnt) ? bufi[wave][lane] : 0x7fffffff;
        bitonic64_pair(d, c, lane);
        if (lane < ksel) {
            int safe = ((unsigned)c < (unsigned)n) ? c : ((row + 1) & (n - 1));
            out[row*ksel + lane] = safe;
        }
    } else {
        select_slow(bufd[wave], bufi[wave], cnt, ksel, row, n, out, lane);
    }
}

// ---------------- knn over packed xyz: 16 rows/block, 4 rows/wave ------------------
__global__ __launch_bounds__(256) void knn_xyz16_kernel(const float4* __restrict__ pts, int n,
                                                        int* __restrict__ out_idx) {
    int tid = threadIdx.x, wave = tid >> 6, lane = tid & 63;
    int rbase = blockIdx.x*16 + wave*4;
    __shared__ __align__(16) float4 tile[XTILE];
    __shared__ float bufd[16][XCAP];
    __shared__ int   bufi[16][XCAP];
    __shared__ int   lcnt[16];
    float4 P0 = pts[rbase], P1 = pts[rbase+1], P2 = pts[rbase+2], P3 = pts[rbase+3];
    float mv0 = INFF, mv1 = INFF, mv2 = INFF, mv3 = INFF;
    for (int t0 = 0; t0 < n; t0 += XTILE) {
        __syncthreads();
        #pragma unroll
        for (int k = 0; k < XTILE/256; ++k) tile[tid + 256*k] = pts[t0 + tid + 256*k];
        __syncthreads();
        for (int c = lane; c < XTILE; c += 64) {
            float4 q = tile[c];
            int col = t0 + c;
            float d0 = P0.w + q.w - 2.f*(P0.x*q.x + P0.y*q.y + P0.z*q.z);
            float d1 = P1.w + q.w - 2.f*(P1.x*q.x + P1.y*q.y + P1.z*q.z);
            float d2 = P2.w + q.w - 2.f*(P2.x*q.x + P2.y*q.y + P2.z*q.z);
            float d3 = P3.w + q.w - 2.f*(P3.x*q.x + P3.y*q.y + P3.z*q.z);
            d0 = (col == rbase)   ? INFF : d0;
            d1 = (col == rbase+1) ? INFF : d1;
            d2 = (col == rbase+2) ? INFF : d2;
            d3 = (col == rbase+3) ? INFF : d3;
            mv0 = fminf(mv0, d0); mv1 = fminf(mv1, d1);
            mv2 = fminf(mv2, d2); mv3 = fminf(mv3, d3);
        }
    }
    bitonic64_val(mv0, lane); bitonic64_val(mv1, lane);
    bitonic64_val(mv2, lane); bitonic64_val(mv3, lane);
    float Tv0 = __shfl(mv0, 15), Tv1 = __shfl(mv1, 15);
    float Tv2 = __shfl(mv2, 15), Tv3 = __shfl(mv3, 15);
    if (lane < 4) lcnt[wave*4 + lane] = 0;
    for (int t0 = 0; t0 < n; t0 += XTILE) {
        __syncthreads();
        #pragma unroll
        for (int k = 0; k < XTILE/256; ++k) tile[tid + 256*k] = pts[t0 + tid + 256*k];
        __syncthreads();
        for (int c = lane; c < XTILE; c += 64) {
            float4 q = tile[c];
            int col = t0 + c;
            float d0 = P0.w + q.w - 2.f*(P0.x*q.x + P0.y*q.y + P0.z*q.z);
            float d1 = P1.w + q.w - 2.f*(P1.x*q.x + P1.y*q.y + P1.z*q.z);
            float d2 = P2.w + q.w - 2.f*(P2.x*q.x + P2.y*q.y + P2.z*q.z);
            float d3 = P3.w + q.w - 2.f*(P3.x*q.x + P3.y*q.y + P3.z*q.z);
            if (col != rbase && d0 <= Tv0) {
                int pos = atomicAdd(&lcnt[wave*4+0], 1);
                if (pos < XCAP) { bufd[wave*4+0][pos] = d0; bufi[wave*4+0][pos] = col; }
            }
            if (col != rbase+1 && d1 <= Tv1) {
                int pos = atomicAdd(&lcnt[wave*4+1], 1);
                if (pos < XCAP) { bufd[wave*4+1][pos] = d1; bufi[wave*4+1][pos] = col; }
            }
            if (col != rbase+2 && d2 <= Tv2) {
                int pos = atomicAdd(&lcnt[wave*4+2], 1);
                if (pos < XCAP) { bufd[wave*4+2][pos] = d2; bufi[wave*4+2][pos] = col; }
            }
            if (col != rbase+3 && d3 <= Tv3) {
                int pos = atomicAdd(&lcnt[wave*4+3], 1);
                if (pos < XCAP) { bufd[wave*4+3][pos] = d3; bufi[wave*4+3][pos] = col; }
            }
        }
    }
    for (int jj = 0; jj < 4; ++jj) {
        int brow = wave*4 + jj, row = rbase + jj;
        int cnt = lcnt[brow]; if (cnt > XCAP) cnt = XCAP;
        if (cnt <= 64) {
            float d = (lane < cnt) ? bufd[brow][lane] : INFF;
            int   c = (lane < cnt) ? bufi[brow][lane] : 0x7fffffff;
            bitonic64_pair(d, c, lane);
            if (lane < 16) {
                int safe = ((unsigned)c < (unsigned)n) ? c : ((row + 1) & (n - 1));
                out_idx[row*16 + lane] = safe;
            }
        } else {
            select_slow(bufd[brow], bufi[brow], cnt, 16, row, n, out_idx, lane);
        }
    }
}

// ---------------- refiner EdgeConv (H1=384, H2=3), wave per point ------------------
__global__ __launch_bounds__(256) void edge_ref_kernel(const float* __restrict__ ur,
                                                       const float* __restrict__ vr,
                                                       const float* __restrict__ w2,
                                                       const float* __restrict__ b2,
                                                       const int* __restrict__ idx,
                                                       const float* __restrict__ xyz_in,
                                                       float* __restrict__ out, int n) {
    int wave = threadIdx.x >> 6, lane = threadIdx.x & 63;
    int i = blockIdx.x*4 + wave;
    if (i >= n) return;
    float m0 = -INFF, m1 = -INFF, m2 = -INFF;
    float uh[6];
    #pragma unroll
    for (int t = 0; t < 6; ++t) uh[t] = ur[(size_t)i*384 + lane + 64*t];
    for (int e = 0; e < KRR; ++e) {
        int j = idx[i*KRR + e];
        j = ((unsigned)j < (unsigned)n) ? j : i;
        float a0 = 0.f, a1 = 0.f, a2 = 0.f;
        #pragma unroll
        for (int t = 0; t < 6; ++t) {
            int h = lane + 64*t;
            float tv = frelu(uh[t] + vr[(size_t)j*384 + h]);
            a0 += tv*w2[h*3+0]; a1 += tv*w2[h*3+1]; a2 += tv*w2[h*3+2];
        }
        #pragma unroll
        for (int s = 32; s > 0; s >>= 1) {
            a0 += __shfl_xor(a0, s); a1 += __shfl_xor(a1, s); a2 += __shfl_xor(a2, s);
        }
        m0 = fmaxf(m0, a0 + b2[0]); m1 = fmaxf(m1, a1 + b2[1]); m2 = fmaxf(m2, a2 + b2[2]);
    }
    if (lane == 0) {
        out[i*3+0] = xyz_in[i*3+0] + m0;
        out[i*3+1] = xyz_in[i*3+1] + m1;
        out[i*3+2] = xyz_in[i*3+2] + m2;
    }
}

// ---------------- folding MLP, fused upsample+noise in, xyz1 + packed pts out ------
__global__ __launch_bounds__(256) void fold_kernel(const float* __restrict__ pred_xyz,
                                                   const float* __restrict__ noise,
                                                   const float* __restrict__ featd,
                                                   const float* __restrict__ w1, const float* __restrict__ b1,
                                                   const float* __restrict__ w2, const float* __restrict__ b2,
                                                   const float* __restrict__ w3, const float* __restrict__ b3,
                                                   float* __restrict__ xyz1, float4* __restrict__ pts_out) {
    const int PTS = 16;
    int base = blockIdx.x * PTS;
    int tid = threadIdx.x;
    __shared__ __align__(16) float xin[PTS][100];
    __shared__ __align__(16) float h1[PTS][FOLDH];
    __shared__ __align__(16) float h2s[PTS][FOLDH];
    __shared__ float oxyz[PTS][3];
    for (int t = tid; t < PTS*100; t += 256) {
        int pt = t/100, k = t - pt*100;
        int gi = base + pt;
        float vv = 0.f;
        if (k < 3) {
            int b = gi >> 11, p = (gi & 2047) >> 2;
            vv = pred_xyz[(size_t)(b*PDIM + p)*3 + k] + 0.02f*noise[(size_t)gi*3 + k];
        } else if (k < 99) {
            int b = gi >> 11, p = (gi & 2047) >> 2;
            vv = featd[(size_t)(b*PDIM + p)*H2C + (k - 3)];
        }
        xin[pt][k] = vv;
    }
    __syncthreads();
    int c = tid;
    float acc[PTS];
    #pragma unroll
    for (int pt = 0; pt < PTS; ++pt) acc[pt] = b1[c];
    for (int k0 = 0; k0 < 96; k0 += 4) {
        float wa = w1[(k0+0)*FOLDH + c], wb = w1[(k0+1)*FOLDH + c];
        float wc = w1[(k0+2)*FOLDH + c], wd = w1[(k0+3)*FOLDH + c];
        #pragma unroll
        for (int pt = 0; pt < PTS; ++pt) {
            float4 xv = *(const float4*)&xin[pt][k0];
            acc[pt] += xv.x*wa + xv.y*wb + xv.z*wc + xv.w*wd;
        }
    }
    {
        float wa = w1[96*FOLDH + c], wb = w1[97*FOLDH + c], wc = w1[98*FOLDH + c];
        #pragma unroll
        for (int pt = 0; pt < PTS; ++pt) {
            float4 xv = *(const float4*)&xin[pt][96];
            acc[pt] += xv.x*wa + xv.y*wb + xv.z*wc;
        }
    }
    #pragma unroll
    for (int pt = 0; pt < PTS; ++pt) h1[pt][c] = frelu(acc[pt]);
    __syncthreads();
    #pragma unroll
    for (int pt = 0; pt < PTS; ++pt) acc[pt] = b2[c];
    for (int k0 = 0; k0 < FOLDH; k0 += 4) {
        float wa = w2[(k0+0)*FOLDH + c], wb = w2[(k0+1)*FOLDH + c];
        float wc = w2[(k0+2)*FOLDH + c], wd = w2[(k0+3)*FOLDH + c];
        #pragma unroll
        for (int pt = 0; pt < PTS; ++pt) {
            float4 hv = *(const float4*)&h1[pt][k0];
            acc[pt] += hv.x*wa + hv.y*wb + hv.z*wc + hv.w*wd;
        }
    }
    #pragma unroll
    for (int pt = 0; pt < PTS; ++pt) h2s[pt][c] = frelu(acc[pt]);
    __syncthreads();
    if (tid < PTS*3) {
        int pt = tid/3, cc = tid - pt*3;
        float a = b3[cc];
        for (int k0 = 0; k0 < FOLDH; k0 += 4) {
            float4 hv = *(const float4*)&h2s[pt][k0];
            a += hv.x*w3[(k0+0)*3+cc] + hv.y*w3[(k0+1)*3+cc] + hv.z*w3[(k0+2)*3+cc] + hv.w*w3[(k0+3)*3+cc];
        }
        int gi = base + pt;
        float res = xin[pt][cc] + a;
        xyz1[(size_t)gi*3 + cc] = res;
        oxyz[pt][cc] = res;
    }
    __syncthreads();
    if (tid < PTS) {
        float x = oxyz[tid][0], y = oxyz[tid][1], z = oxyz[tid][2];
        pts_out[base + tid] = make_float4(x, y, z, x*x + y*y + z*z);
    }
}

extern "C" void kernel_launch(void* const* d_in, const int* in_sizes, int n_in,
                              void* d_out, int out_size, void* d_ws, size_t ws_size,
                              hipStream_t stream) {
    const float* ctx_xyz    = (const float*)d_in[0];
    const float* ctx_tokens = (const float*)d_in[1];
    const float* pred_xyz   = (const float*)d_in[2];
    const float* noise      = (const float*)d_in[4];
    const float* c1w1 = (const float*)d_in[5];
    const float* c1b1 = (const float*)d_in[6];
    const float* c1w2 = (const float*)d_in[7];
    const float* c1b2 = (const float*)d_in[8];
    const float* c2w1 = (const float*)d_in[9];
    const float* c2b1 = (const float*)d_in[10];
    const float* c2w2 = (const float*)d_in[11];
    const float* c2b2 = (const float*)d_in[12];
    const float* cdw1 = (const float*)d_in[13];
    const float* cdb1 = (const float*)d_in[14];
    const float* cdw2 = (const float*)d_in[15];
    const float* cdb2 = (const float*)d_in[16];
    const float* fw1  = (const float*)d_in[17];
    const float* fb1  = (const float*)d_in[18];
    const float* fw2  = (const float*)d_in[19];
    const float* fb2  = (const float*)d_in[20];
    const float* fw3  = (const float*)d_in[21];
    const float* fb3  = (const float*)d_in[22];
    const float* rw1  = (const float*)d_in[23];
    const float* rb1  = (const float*)d_in[24];
    const float* rw2  = (const float*)d_in[25];
    const float* rb2  = (const float*)d_in[26];

    float* W = (float*)d_ws;
    // Zone A (staged aliasing): dist/distB (S1/S3) -> cfeat (S4) -> ur/vr (S8)
    float* dist  = W;                   // 2048*2048
    float* distB = W + 4194304;
    float* cfeat = W;                   // 2048*96 (after dist dead)
    float* ur    = W;                   // 8192*384 (after cfeat dead)
    float* vr    = W + 3145728;
    // Persistent zone:
    float* h_ctx = W + 8388608;         // 393,216
    float* h_tgt = h_ctx + 393216;
    float* UV    = h_tgt + 393216;      // [u1|v1] then [u2c|v2c|u2t|v2t]
    float* u1  = UV;            float* v1  = UV + 393216;
    float* u2c = UV;            float* v2c = UV + 196608;
    float* u2t = UV + 393216;   float* v2t = UV + 589824;
    float* tfeat = UV + 786432;         // 196,608
    float* xyz1  = tfeat + 196608;      // 24,576
    float4* pts  = (float4*)(xyz1 + 24576);
    float* sqb     = (float*)pts + 32768;
    float* sq_hctx = sqb + N2;
    float* sq_htgt = sq_hctx + N2;
    int* cidx1 = (int*)(sq_htgt + N2);
    int* cidx2 = cidx1 + N2*16;
    int* tidx2 = cidx2 + N2*8;
    int* ridx  = tidx2 + N2*2;

    float* out_ctx = (float*)d_out;
    float* out_tgt = out_ctx + N2*3;

    dim3 b16(16, 16);
    const int NTRI = 32*33/2;
    const float* NUL = nullptr;

    // --- S1: rowsq, dist(tokens), knn16 (tgt conv1 uses first 4 of cidx1)
    rowsq_kernel<<<N2/4, 256, 0, stream>>>(ctx_tokens, sqb, CDIM);
    dist64tri_kernel<<<NTRI, b16, 0, stream>>>(ctx_tokens, sqb, dist, N2, CDIM);
    knn_dist_rt_kernel<<<N2/4, 256, 0, stream>>>(dist, dist, N2, cidx1, cidx1, 16, 16, N2/4);

    // --- S2: u1/v1 GEMMs; conv1 fused gather-GEMM+max; row-sq of h
    gemmquad_kernel<<<dim3(3, 32, 2), b16, 0, stream>>>(
        ctx_tokens, c1w1, c1w1 + 384*192, c1b1, u1,
        ctx_tokens, c1w1 + 384*192, NUL, NUL, v1,
        ctx_tokens, c1w1, NUL, NUL, u1,   // unused (z<2)
        ctx_tokens, c1w1, NUL, NUL, v1,
        H1C, CDIM);
    edge_fused1_kernel<<<dim3(3, 512, 2), b16, 0, stream>>>(u1, v1, cidx1, c1w2, c1b2,
                                                            h_ctx, h_tgt, N2);
    rowsqpair_kernel<<<dim3(N2/4, 2), 256, 0, stream>>>(h_ctx, sq_hctx, h_tgt, sq_htgt, H1C);

    // --- S3: dist(h_ctx)+dist(h_tgt), paired knn, u2/v2 quad
    distpairtri_kernel<<<dim3(NTRI, 1, 2), b16, 0, stream>>>(h_ctx, sq_hctx, dist,
                                                             h_tgt, sq_htgt, distB, N2, H1C);
    knn_dist_rt_kernel<<<2*(N2/4), 256, 0, stream>>>(dist, distB, N2, cidx2, tidx2, 8, 2, N2/4);
    gemmquad_kernel<<<dim3(2, 32, 4), b16, 0, stream>>>(
        h_ctx, c2w1, c2w1 + 192*96, c2b1, u2c,
        h_ctx, c2w1 + 192*96, NUL, NUL, v2c,
        h_tgt, c2w1, c2w1 + 192*96, c2b1, u2t,
        h_tgt, c2w1 + 192*96, NUL, NUL, v2t,
        H2C, H1C);

    // --- S4: conv2 fused gather-GEMM+max; cdef head
    edge_fused2_kernel<<<dim3(2, 256, 2), b16, 0, stream>>>(u2c, v2c, u2t, v2t, cidx2, tidx2,
                                                            c2w2, c2b2, cfeat, tfeat, N2);
    cdef_kernel<<<N2, 128, 0, stream>>>(cfeat, cdw1, cdb1, cdw2, cdb2, ctx_xyz, out_ctx);

    // --- S6: folding MLP (fused upsample+noise; emits xyz1 + packed pts)
    fold_kernel<<<N8/16, 256, 0, stream>>>(pred_xyz, noise, tfeat, fw1, fb1, fw2, fb2, fw3, fb3, xyz1, pts);

    // --- S7: refiner knn (4 rows/wave)
    knn_xyz16_kernel<<<N8/16, 256, 0, stream>>>(pts, N8, ridx);

    // --- S8: refiner u/v gather-GEMMs, residual EdgeConv to output
    gatherpair_kernel<<<dim3(6, N8/64, 2), b16, 0, stream>>>(
        tfeat, xyz1,
        rw1, rw1 + 99*384, rb1, ur,
        rw1 + 99*384, NUL, NUL, vr,
        384, 99);
    edge_ref_kernel<<<N8/4, 256, 0, stream>>>(ur, vr, rw2, rb2, ridx, xyz1, out_tgt, N8);
}

// Round 12
// 465.818 us; speedup vs baseline: 1.0242x; 1.0242x over previous
//
#include <hip/hip_runtime.h>

#define N2 2048      // B*P
#define N8 8192      // B*P*UP
#define CDIM 384
#define H1C 192      // C/2
#define H2C 96       // C/4
#define PDIM 512
#define KRR 16
#define FOLDH 256
#define XCAP 256
#define XTILE 1024
#define INFF 3.0e38f

__device__ __forceinline__ float frelu(float x) { return x > 0.f ? x : 0.f; }

// ---------------- 64-lane bitonic sorts (ascending) --------------------------------
__device__ __forceinline__ void bitonic64_val(float& d, int lane) {
    #pragma unroll
    for (int k = 2; k <= 64; k <<= 1) {
        #pragma unroll
        for (int j = k >> 1; j > 0; j >>= 1) {
            float od = __shfl_xor(d, j);
            bool lower = (lane & j) == 0;
            bool olt = od < d;
            bool take = lower ? olt : !olt;
            if (lane & k) take = !take;
            if (take) d = od;
        }
    }
}

__device__ __forceinline__ void bitonic64_pair(float& d, int& c, int lane) {
    #pragma unroll
    for (int k = 2; k <= 64; k <<= 1) {
        #pragma unroll
        for (int j = k >> 1; j > 0; j >>= 1) {
            float od = __shfl_xor(d, j);
            int   oc = __shfl_xor(c, j);
            bool lower = (lane & j) == 0;
            bool olt = (od < d) || (od == d && oc < c);
            bool take = lower ? olt : !olt;
            if (lane & k) take = !take;
            if (take) { d = od; c = oc; }
        }
    }
}

// ---------------- slow exact select fallback (cnt > 64, rare) ----------------------
__device__ __forceinline__ void select_slow(const float* bd, const int* bi, int cnt,
                                            int ksel, int row, int n, int* out, int lane) {
    float cd[4]; int cix[4];
    #pragma unroll
    for (int s = 0; s < 4; ++s) {
        int c = lane + 64*s;
        bool v = c < cnt;
        cd[s]  = v ? bd[c] : INFF;
        cix[s] = v ? bi[c] : 0x7fffffff;
    }
    for (int r = 0; r < ksel; ++r) {
        float lv = cd[0]; int li = cix[0];
        #pragma unroll
        for (int s = 1; s < 4; ++s) {
            if (cd[s] < lv || (cd[s] == lv && cix[s] < li)) { lv = cd[s]; li = cix[s]; }
        }
        float wv = lv; int wi = li;
        #pragma unroll
        for (int s = 1; s < 64; s <<= 1) {
            float ov = __shfl_xor(wv, s); int oi = __shfl_xor(wi, s);
            if (ov < wv || (ov == wv && oi < wi)) { wv = ov; wi = oi; }
        }
        if (lane == 0) {
            int safe = ((unsigned)wi < (unsigned)n) ? wi : ((row + 1) & (n - 1));
            out[row*ksel + r] = safe;
        }
        #pragma unroll
        for (int s = 0; s < 4; ++s) {
            if (cd[s] == wv && cix[s] == wi) { cd[s] = INFF; cix[s] = 0x7fffffff; }
        }
    }
}

// ---------------- row squared norms (wave per row; single + paired) ----------------
__global__ __launch_bounds__(256) void rowsq_kernel(const float* __restrict__ x,
                                                    float* __restrict__ sq, int d) {
    int wave = threadIdx.x >> 6, lane = threadIdx.x & 63;
    int row = blockIdx.x*4 + wave;
    float acc = 0.f;
    for (int k = lane; k < d; k += 64) { float v = x[(size_t)row*d + k]; acc += v*v; }
    #pragma unroll
    for (int s = 1; s < 64; s <<= 1) acc += __shfl_xor(acc, s);
    if (lane == 0) sq[row] = acc;
}

__global__ __launch_bounds__(256) void rowsqpair_kernel(const float* __restrict__ xA,
                                                        float* __restrict__ sqA,
                                                        const float* __restrict__ xB,
                                                        float* __restrict__ sqB, int d) {
    const float* x = blockIdx.y ? xB : xA;
    float* sq = blockIdx.y ? sqB : sqA;
    int wave = threadIdx.x >> 6, lane = threadIdx.x & 63;
    int row = blockIdx.x*4 + wave;
    float acc = 0.f;
    for (int k = lane; k < d; k += 64) { float v = x[(size_t)row*d + k]; acc += v*v; }
    #pragma unroll
    for (int s = 1; s < 64; s <<= 1) acc += __shfl_xor(acc, s);
    if (lane == 0) sq[row] = acc;
}

// ---------------- triangular symmetric dist: direct + mirrored tile ----------------
__device__ __forceinline__ void disttri_body(const float* __restrict__ x, const float* __restrict__ sq,
                                             float* __restrict__ dist, int n, int K) {
    int l = blockIdx.x;
    int by = (int)((sqrtf(8.f*(float)l + 1.f) - 1.f)*0.5f);
    while ((by+1)*(by+2)/2 <= l) ++by;
    while (by*(by+1)/2 > l) --by;
    int bx = l - by*(by+1)/2;
    int row0 = by*64, col0 = bx*64;
    __shared__ __align__(16) float As[16][68];
    __shared__ __align__(16) float Bs[16][68];
    __shared__ __align__(16) float T[64][68];
    int tx = threadIdx.x, ty = threadIdx.y;
    int t = ty*16 + tx;
    float acc[4][4] = {};
    for (int k0 = 0; k0 < K; k0 += 16) {
        #pragma unroll
        for (int r = 0; r < 4; ++r) {
            int e = t + 256*r; int kk = e & 15, mm = e >> 4;
            As[kk][mm] = x[(size_t)(row0+mm)*K + k0+kk];
            Bs[kk][mm] = x[(size_t)(col0+mm)*K + k0+kk];
        }
        __syncthreads();
        #pragma unroll
        for (int kk = 0; kk < 16; ++kk) {
            float4 a4 = *(const float4*)&As[kk][ty*4];
            float4 b4 = *(const float4*)&Bs[kk][tx*4];
            acc[0][0] += a4.x*b4.x; acc[0][1] += a4.x*b4.y; acc[0][2] += a4.x*b4.z; acc[0][3] += a4.x*b4.w;
            acc[1][0] += a4.y*b4.x; acc[1][1] += a4.y*b4.y; acc[1][2] += a4.y*b4.z; acc[1][3] += a4.y*b4.w;
            acc[2][0] += a4.z*b4.x; acc[2][1] += a4.z*b4.y; acc[2][2] += a4.z*b4.z; acc[2][3] += a4.z*b4.w;
            acc[3][0] += a4.w*b4.x; acc[3][1] += a4.w*b4.y; acc[3][2] += a4.w*b4.z; acc[3][3] += a4.w*b4.w;
        }
        __syncthreads();
    }
    bool mirror = (row0 != col0);
    #pragma unroll
    for (int i2 = 0; i2 < 4; ++i2) {
        int row = row0 + ty*4 + i2;
        float sr = sq[row];
        float4 o;
        o.x = sr + sq[col0+tx*4+0] - 2.f*acc[i2][0];
        o.y = sr + sq[col0+tx*4+1] - 2.f*acc[i2][1];
        o.z = sr + sq[col0+tx*4+2] - 2.f*acc[i2][2];
        o.w = sr + sq[col0+tx*4+3] - 2.f*acc[i2][3];
        *(float4*)&dist[(size_t)row*n + col0 + tx*4] = o;
        if (mirror) {
            T[tx*4+0][ty*4+i2] = o.x;
            T[tx*4+1][ty*4+i2] = o.y;
            T[tx*4+2][ty*4+i2] = o.z;
            T[tx*4+3][ty*4+i2] = o.w;
        }
    }
    if (mirror) {
        __syncthreads();
        #pragma unroll
        for (int i2 = 0; i2 < 4; ++i2) {
            int orow = col0 + ty*4 + i2;
            float4 o = *(const float4*)&T[ty*4+i2][tx*4];
            *(float4*)&dist[(size_t)orow*n + row0 + tx*4] = o;
        }
    }
}

__global__ __launch_bounds__(256) void dist64tri_kernel(const float* __restrict__ x,
                                                        const float* __restrict__ sq,
                                                        float* __restrict__ dist, int n, int K) {
    disttri_body(x, sq, dist, n, K);
}

__global__ __launch_bounds__(256) void distpairtri_kernel(const float* __restrict__ xA,
                                                          const float* __restrict__ sqA,
                                                          float* __restrict__ dA,
                                                          const float* __restrict__ xB,
                                                          const float* __restrict__ sqB,
                                                          float* __restrict__ dB, int n, int K) {
    const float* x  = blockIdx.z ? xB : xA;
    const float* sq = blockIdx.z ? sqB : sqA;
    float* dist     = blockIdx.z ? dB : dA;
    disttri_body(x, sq, dist, n, K);
}

// ---------------- shared 64x64 GEMM tile body: C = A @ (Bw - BwB) + bias -----------
__device__ __forceinline__ void gemm_body(const float* __restrict__ A, const float* __restrict__ Bw,
                                          const float* __restrict__ BwB, const float* __restrict__ bias,
                                          float* __restrict__ C, int m, int K) {
    __shared__ __align__(16) float As[16][68];
    __shared__ __align__(16) float Bs[16][68];
    int tx = threadIdx.x, ty = threadIdx.y;
    int t = ty*16 + tx;
    int row0 = blockIdx.y*64, col0 = blockIdx.x*64;
    float acc[4][4] = {};
    for (int k0 = 0; k0 < K; k0 += 16) {
        #pragma unroll
        for (int r = 0; r < 4; ++r) {
            int e = t + 256*r; int kk = e & 15, mm = e >> 4;
            As[kk][mm] = (k0 + kk < K) ? A[(size_t)(row0+mm)*K + k0+kk] : 0.f;
        }
        #pragma unroll
        for (int r = 0; r < 4; ++r) {
            int e = t + 256*r; int nn = e & 63, kk = e >> 6;
            int col = col0 + nn, k = k0 + kk;
            float bv = 0.f;
            if (k < K && col < m) {
                bv = Bw[(size_t)k*m + col];
                if (BwB) bv -= BwB[(size_t)k*m + col];
            }
            Bs[kk][nn] = bv;
        }
        __syncthreads();
        #pragma unroll
        for (int kk = 0; kk < 16; ++kk) {
            float4 a4 = *(const float4*)&As[kk][ty*4];
            float4 b4 = *(const float4*)&Bs[kk][tx*4];
            acc[0][0] += a4.x*b4.x; acc[0][1] += a4.x*b4.y; acc[0][2] += a4.x*b4.z; acc[0][3] += a4.x*b4.w;
            acc[1][0] += a4.y*b4.x; acc[1][1] += a4.y*b4.y; acc[1][2] += a4.y*b4.z; acc[1][3] += a4.y*b4.w;
            acc[2][0] += a4.z*b4.x; acc[2][1] += a4.z*b4.y; acc[2][2] += a4.z*b4.z; acc[2][3] += a4.z*b4.w;
            acc[3][0] += a4.w*b4.x; acc[3][1] += a4.w*b4.y; acc[3][2] += a4.w*b4.z; acc[3][3] += a4.w*b4.w;
        }
        __syncthreads();
    }
    #pragma unroll
    for (int i2 = 0; i2 < 4; ++i2) {
        int row = row0 + ty*4 + i2;
        #pragma unroll
        for (int j2 = 0; j2 < 4; ++j2) {
            int col = col0 + tx*4 + j2;
            if (col < m) C[(size_t)row*m + col] = acc[i2][j2] + (bias ? bias[col] : 0.f);
        }
    }
}

__global__ __launch_bounds__(256) void gemmquad_kernel(
    const float* A0, const float* Bw0, const float* BwB0, const float* bias0, float* C0,
    const float* A1, const float* Bw1, const float* BwB1, const float* bias1, float* C1,
    const float* A2, const float* Bw2, const float* BwB2, const float* bias2, float* C2,
    const float* A3, const float* Bw3, const float* BwB3, const float* bias3, float* C3,
    int m, int K) {
    int z = blockIdx.z;
    const float* A    = (z==0)?A0 :(z==1)?A1 :(z==2)?A2 :A3;
    const float* Bw   = (z==0)?Bw0:(z==1)?Bw1:(z==2)?Bw2:Bw3;
    const float* BwB  = (z==0)?BwB0:(z==1)?BwB1:(z==2)?BwB2:BwB3;
    const float* bias = (z==0)?bias0:(z==1)?bias1:(z==2)?bias2:bias3;
    float* C          = (z==0)?C0 :(z==1)?C1 :(z==2)?C2 :C3;
    gemm_body(A, Bw, BwB, bias, C, m, K);
}

// ---------------- EdgeConv layer-2 gather-GEMM, max fused IN REGISTERS -------------
// Row (i*EPT+e): e<EREAL real edge (SELF: e==0 self), else duplicate self (max-inert).
// Tile layout: thread (tx,ty) owns rows ty*4+i2; lane=(ty&3)*16+tx, wave=ty>>2.
// EPT=16: point rows span one wave -> local fmax + shfl_xor(16,32).
// EPT=8:  pair ty with ty^1 -> local fmax + shfl_xor(16).
// EPT=4:  one thread's 4 rows = one point -> local fmax only.
template<int EPT, int SELF, int EREAL, int IDXS, int YT>
__device__ __forceinline__ void edge_fused_body(const float* __restrict__ u, const float* __restrict__ v,
                                                const int* __restrict__ idx,
                                                const float* __restrict__ Bw, const float* __restrict__ bias,
                                                float* __restrict__ hout, int m, int K, int npts) {
    if ((int)blockIdx.y >= YT) return;
    constexpr int LOG2EPT = (EPT == 16) ? 4 : (EPT == 8) ? 3 : 2;
    __shared__ __align__(16) float As[16][68];
    __shared__ __align__(16) float Bs[16][68];
    int tx = threadIdx.x, ty = threadIdx.y;
    int t = ty*16 + tx;
    int row0 = blockIdx.y*64, col0 = blockIdx.x*64;
    float acc[4][4] = {};
    for (int k0 = 0; k0 < K; k0 += 16) {
        #pragma unroll
        for (int r = 0; r < 4; ++r) {
            int e_ = t + 256*r; int kk = e_ & 15, mm = e_ >> 4;
            int row = row0 + mm, k = k0 + kk;
            int i = row >> LOG2EPT;
            int e = row - (i << LOG2EPT);
            int j;
            if (SELF && e == 0) j = i;
            else if (e < EREAL) j = idx[i*IDXS + (e - SELF)];
            else j = i;
            j = ((unsigned)j < (unsigned)npts) ? j : i;
            As[kk][mm] = frelu(u[(size_t)i*K + k] + v[(size_t)j*K + k]);
        }
        #pragma unroll
        for (int r = 0; r < 4; ++r) {
            int e_ = t + 256*r; int nn = e_ & 63, kk = e_ >> 6;
            int col = col0 + nn;
            Bs[kk][nn] = (col < m) ? Bw[(size_t)(k0+kk)*m + col] : 0.f;
        }
        __syncthreads();
        #pragma unroll
        for (int kk = 0; kk < 16; ++kk) {
            float4 a4 = *(const float4*)&As[kk][ty*4];
            float4 b4 = *(const float4*)&Bs[kk][tx*4];
            acc[0][0] += a4.x*b4.x; acc[0][1] += a4.x*b4.y; acc[0][2] += a4.x*b4.z; acc[0][3] += a4.x*b4.w;
            acc[1][0] += a4.y*b4.x; acc[1][1] += a4.y*b4.y; acc[1][2] += a4.y*b4.z; acc[1][3] += a4.y*b4.w;
            acc[2][0] += a4.z*b4.x; acc[2][1] += a4.z*b4.y; acc[2][2] += a4.z*b4.z; acc[2][3] += a4.z*b4.w;
            acc[3][0] += a4.w*b4.x; acc[3][1] += a4.w*b4.y; acc[3][2] += a4.w*b4.z; acc[3][3] += a4.w*b4.w;
        }
        __syncthreads();
    }
    float bestv[4];
    #pragma unroll
    for (int j2 = 0; j2 < 4; ++j2)
        bestv[j2] = fmaxf(fmaxf(acc[0][j2], acc[1][j2]), fmaxf(acc[2][j2], acc[3][j2]));
    if (EPT >= 8) {
        #pragma unroll
        for (int j2 = 0; j2 < 4; ++j2) bestv[j2] = fmaxf(bestv[j2], __shfl_xor(bestv[j2], 16));
    }
    if (EPT == 16) {
        #pragma unroll
        for (int j2 = 0; j2 < 4; ++j2) bestv[j2] = fmaxf(bestv[j2], __shfl_xor(bestv[j2], 32));
    }
    bool writer; int p;
    if (EPT == 16) { writer = (ty & 3) == 0; p = (row0 >> 4) + (ty >> 2); }
    else if (EPT == 8) { writer = (ty & 1) == 0; p = (row0 >> 3) + (ty >> 1); }
    else { writer = true; p = (row0 >> 2) + ty; }
    if (writer) {
        #pragma unroll
        for (int j2 = 0; j2 < 4; ++j2) {
            int col = col0 + tx*4 + j2;
            if (col < m) hout[(size_t)p*m + col] = bestv[j2] + bias[col];
        }
    }
}

__global__ __launch_bounds__(256) void edge_fused1_kernel(const float* u1, const float* v1,
                                                          const int* cidx1,
                                                          const float* Bw, const float* bias,
                                                          float* h_ctx, float* h_tgt, int npts) {
    if (blockIdx.z == 0) edge_fused_body<16,0,16,16,512>(u1, v1, cidx1, Bw, bias, h_ctx, H1C, H1C, npts);
    else                 edge_fused_body<8,1,5,16,256>(u1, v1, cidx1, Bw, bias, h_tgt, H1C, H1C, npts);
}

__global__ __launch_bounds__(256) void edge_fused2_kernel(const float* u2c, const float* v2c,
                                                          const float* u2t, const float* v2t,
                                                          const int* cidx2, const int* tidx2,
                                                          const float* Bw, const float* bias,
                                                          float* cfeat, float* tfeat, int npts) {
    if (blockIdx.z == 0) edge_fused_body<8,0,8,8,256>(u2c, v2c, cidx2, Bw, bias, cfeat, H2C, H2C, npts);
    else                 edge_fused_body<4,1,3,2,128>(u2t, v2t, tidx2, Bw, bias, tfeat, H2C, H2C, npts);
}

// ---------------- ctx deform head: out = xyz + 0.05 * mlp2(cfeat) ------------------
__global__ __launch_bounds__(128) void cdef_kernel(const float* __restrict__ cfeat,
                                                   const float* __restrict__ cdw1, const float* __restrict__ cdb1,
                                                   const float* __restrict__ cdw2, const float* __restrict__ cdb2,
                                                   const float* __restrict__ ctx_xyz,
                                                   float* __restrict__ out_ctx) {
    int i = blockIdx.x, tid = threadIdx.x, wave = tid >> 6, lane = tid & 63;
    __shared__ float sf_[96], st2_[96];
    if (tid < 96) sf_[tid] = cfeat[(size_t)i*H2C + tid];
    __syncthreads();
    if (tid < 96) {
        float a = cdb1[tid];
        for (int k = 0; k < 96; ++k) a += sf_[k]*cdw1[k*96 + tid];
        st2_[tid] = frelu(a);
    }
    __syncthreads();
    if (wave == 0) {
        float s0 = st2_[lane];
        float p0 = s0*cdw2[lane*3+0], p1 = s0*cdw2[lane*3+1], p2 = s0*cdw2[lane*3+2];
        if (lane < 32) {
            float s1 = st2_[lane+64];
            p0 += s1*cdw2[(lane+64)*3+0];
            p1 += s1*cdw2[(lane+64)*3+1];
            p2 += s1*cdw2[(lane+64)*3+2];
        }
        #pragma unroll
        for (int s = 1; s < 64; s <<= 1) {
            p0 += __shfl_xor(p0, s); p1 += __shfl_xor(p1, s); p2 += __shfl_xor(p2, s);
        }
        if (lane == 0) {
            out_ctx[i*3+0] = ctx_xyz[i*3+0] + 0.05f*(cdb2[0] + p0);
            out_ctx[i*3+1] = ctx_xyz[i*3+1] + 0.05f*(cdb2[1] + p1);
            out_ctx[i*3+2] = ctx_xyz[i*3+2] + 0.05f*(cdb2[2] + p2);
        }
    }
}

// refiner gather-GEMM pair: A row gathered from [featd(96) | xyzg(3)], K = 99
__global__ __launch_bounds__(256) void gatherpair_kernel(
    const float* __restrict__ featd, const float* __restrict__ xyzg,
    const float* Bw0, const float* BwB0, const float* bias0, float* C0,
    const float* Bw1, const float* BwB1, const float* bias1, float* C1,
    int m, int K) {
    int z = blockIdx.z;
    const float* Bw   = z ? Bw1 : Bw0;
    const float* BwB  = z ? BwB1 : BwB0;
    const float* bias = z ? bias1 : bias0;
    float* C          = z ? C1 : C0;
    __shared__ __align__(16) float As[16][68];
    __shared__ __align__(16) float Bs[16][68];
    int tx = threadIdx.x, ty = threadIdx.y;
    int t = ty*16 + tx;
    int row0 = blockIdx.y*64, col0 = blockIdx.x*64;
    float acc[4][4] = {};
    for (int k0 = 0; k0 < K; k0 += 16) {
        #pragma unroll
        for (int r = 0; r < 4; ++r) {
            int e = t + 256*r; int kk = e & 15, mm = e >> 4;
            int k = k0 + kk, grow = row0 + mm;
            float av = 0.f;
            if (k < K) {
                if (k < 96) { int b = grow >> 11, p = (grow & 2047) >> 2;
                              av = featd[(size_t)(b*PDIM + p)*H2C + k]; }
                else av = xyzg[(size_t)grow*3 + (k - 96)];
            }
            As[kk][mm] = av;
        }
        #pragma unroll
        for (int r = 0; r < 4; ++r) {
            int e = t + 256*r; int nn = e & 63, kk = e >> 6;
            int col = col0 + nn, k = k0 + kk;
            float bv = 0.f;
            if (k < K && col < m) {
                bv = Bw[(size_t)k*m + col];
                if (BwB) bv -= BwB[(size_t)k*m + col];
            }
            Bs[kk][nn] = bv;
        }
        __syncthreads();
        #pragma unroll
        for (int kk = 0; kk < 16; ++kk) {
            float4 a4 = *(const float4*)&As[kk][ty*4];
            float4 b4 = *(const float4*)&Bs[kk][tx*4];
            acc[0][0] += a4.x*b4.x; acc[0][1] += a4.x*b4.y; acc[0][2] += a4.x*b4.z; acc[0][3] += a4.x*b4.w;
            acc[1][0] += a4.y*b4.x; acc[1][1] += a4.y*b4.y; acc[1][2] += a4.y*b4.z; acc[1][3] += a4.y*b4.w;
            acc[2][0] += a4.z*b4.x; acc[2][1] += a4.z*b4.y; acc[2][2] += a4.z*b4.z; acc[2][3] += a4.z*b4.w;
            acc[3][0] += a4.w*b4.x; acc[3][1] += a4.w*b4.y; acc[3][2] += a4.w*b4.z; acc[3][3] += a4.w*b4.w;
        }
        __syncthreads();
    }
    #pragma unroll
    for (int i2 = 0; i2 < 4; ++i2) {
        int row = row0 + ty*4 + i2;
        #pragma unroll
        for (int j2 = 0; j2 < 4; ++j2) {
            int col = col0 + tx*4 + j2;
            if (col < m) C[(size_t)row*m + col] = acc[i2][j2] + (bias ? bias[col] : 0.f);
        }
    }
}

// ---------------- knn from dist rows (4 rows/block, bitonic select) ----------------
__global__ __launch_bounds__(256) void knn_dist_rt_kernel(const float* __restrict__ dA,
                                                          const float* __restrict__ dB, int n,
                                                          int* __restrict__ outA, int* __restrict__ outB,
                                                          int kA, int kB, int nblkA) {
    int wave = threadIdx.x >> 6, lane = threadIdx.x & 63;
    bool useB = (int)blockIdx.x >= nblkA;
    const float* dist = useB ? dB : dA;
    int* out = useB ? outB : outA;
    int ksel = useB ? kB : kA;
    int bx = useB ? (int)blockIdx.x - nblkA : (int)blockIdx.x;
    int row = bx*4 + wave;
    __shared__ float bufd[4][XCAP];
    __shared__ int   bufi[4][XCAP];
    __shared__ int   lcnt[4];
    const float4* drow = (const float4*)(dist + (size_t)row*n);
    int nq = n >> 2;
    float mv = INFF;
    for (int i = lane; i < nq; i += 64) {
        float4 d4 = drow[i]; int base = i*4;
        float a = (base+0 == row) ? INFF : d4.x;
        float b = (base+1 == row) ? INFF : d4.y;
        float c = (base+2 == row) ? INFF : d4.z;
        float d = (base+3 == row) ? INFF : d4.w;
        mv = fminf(mv, fminf(fminf(a,b), fminf(c,d)));
    }
    float sd = mv;
    bitonic64_val(sd, lane);
    float Tv = __shfl(sd, ksel - 1);
    if (lane == 0) lcnt[wave] = 0;
    for (int i = lane; i < nq; i += 64) {
        float4 d4 = drow[i]; int base = i*4;
        float dv4[4] = {d4.x, d4.y, d4.z, d4.w};
        #pragma unroll
        for (int q = 0; q < 4; ++q) {
            int col = base + q;
            if (col != row && dv4[q] <= Tv) {
                int pos = atomicAdd(&lcnt[wave], 1);
                if (pos < XCAP) { bufd[wave][pos] = dv4[q]; bufi[wave][pos] = col; }
            }
        }
    }
    int cnt = lcnt[wave]; if (cnt > XCAP) cnt = XCAP;
    if (cnt <= 64) {
        float d = (lane < cnt) ? bufd[wave][lane] : INFF;
        int   c = (lane < cnt) ? bufi[wave][lane] : 0x7fffffff;
        bitonic64_pair(d, c, lane);
        if (lane < ksel) {
            int safe = ((unsigned)c < (unsigned)n) ? c : ((row + 1) & (n - 1));
            out[row*ksel + lane] = safe;
        }
    } else {
        select_slow(bufd[wave], bufi[wave], cnt, ksel, row, n, out, lane);
    }
}

// ---------------- knn over packed xyz: 16 rows/block, 4 rows/wave ------------------
__global__ __launch_bounds__(256) void knn_xyz16_kernel(const float4* __restrict__ pts, int n,
                                                        int* __restrict__ out_idx) {
    int tid = threadIdx.x, wave = tid >> 6, lane = tid & 63;
    int rbase = blockIdx.x*16 + wave*4;
    __shared__ __align__(16) float4 tile[XTILE];
    __shared__ float bufd[16][XCAP];
    __shared__ int   bufi[16][XCAP];
    __shared__ int   lcnt[16];
    float4 P0 = pts[rbase], P1 = pts[rbase+1], P2 = pts[rbase+2], P3 = pts[rbase+3];
    float mv0 = INFF, mv1 = INFF, mv2 = INFF, mv3 = INFF;
    for (int t0 = 0; t0 < n; t0 += XTILE) {
        __syncthreads();
        #pragma unroll
        for (int k = 0; k < XTILE/256; ++k) tile[tid + 256*k] = pts[t0 + tid + 256*k];
        __syncthreads();
        for (int c = lane; c < XTILE; c += 64) {
            float4 q = tile[c];
            int col = t0 + c;
            float d0 = P0.w + q.w - 2.f*(P0.x*q.x + P0.y*q.y + P0.z*q.z);
            float d1 = P1.w + q.w - 2.f*(P1.x*q.x + P1.y*q.y + P1.z*q.z);
            float d2 = P2.w + q.w - 2.f*(P2.x*q.x + P2.y*q.y + P2.z*q.z);
            float d3 = P3.w + q.w - 2.f*(P3.x*q.x + P3.y*q.y + P3.z*q.z);
            d0 = (col == rbase)   ? INFF : d0;
            d1 = (col == rbase+1) ? INFF : d1;
            d2 = (col == rbase+2) ? INFF : d2;
            d3 = (col == rbase+3) ? INFF : d3;
            mv0 = fminf(mv0, d0); mv1 = fminf(mv1, d1);
            mv2 = fminf(mv2, d2); mv3 = fminf(mv3, d3);
        }
    }
    bitonic64_val(mv0, lane); bitonic64_val(mv1, lane);
    bitonic64_val(mv2, lane); bitonic64_val(mv3, lane);
    float Tv0 = __shfl(mv0, 15), Tv1 = __shfl(mv1, 15);
    float Tv2 = __shfl(mv2, 15), Tv3 = __shfl(mv3, 15);
    if (lane < 4) lcnt[wave*4 + lane] = 0;
    for (int t0 = 0; t0 < n; t0 += XTILE) {
        __syncthreads();
        #pragma unroll
        for (int k = 0; k < XTILE/256; ++k) tile[tid + 256*k] = pts[t0 + tid + 256*k];
        __syncthreads();
        for (int c = lane; c < XTILE; c += 64) {
            float4 q = tile[c];
            int col = t0 + c;
            float d0 = P0.w + q.w - 2.f*(P0.x*q.x + P0.y*q.y + P0.z*q.z);
            float d1 = P1.w + q.w - 2.f*(P1.x*q.x + P1.y*q.y + P1.z*q.z);
            float d2 = P2.w + q.w - 2.f*(P2.x*q.x + P2.y*q.y + P2.z*q.z);
            float d3 = P3.w + q.w - 2.f*(P3.x*q.x + P3.y*q.y + P3.z*q.z);
            if (col != rbase && d0 <= Tv0) {
                int pos = atomicAdd(&lcnt[wave*4+0], 1);
                if (pos < XCAP) { bufd[wave*4+0][pos] = d0; bufi[wave*4+0][pos] = col; }
            }
            if (col != rbase+1 && d1 <= Tv1) {
                int pos = atomicAdd(&lcnt[wave*4+1], 1);
                if (pos < XCAP) { bufd[wave*4+1][pos] = d1; bufi[wave*4+1][pos] = col; }
            }
            if (col != rbase+2 && d2 <= Tv2) {
                int pos = atomicAdd(&lcnt[wave*4+2], 1);
                if (pos < XCAP) { bufd[wave*4+2][pos] = d2; bufi[wave*4+2][pos] = col; }
            }
            if (col != rbase+3 && d3 <= Tv3) {
                int pos = atomicAdd(&lcnt[wave*4+3], 1);
                if (pos < XCAP) { bufd[wave*4+3][pos] = d3; bufi[wave*4+3][pos] = col; }
            }
        }
    }
    for (int jj = 0; jj < 4; ++jj) {
        int brow = wave*4 + jj, row = rbase + jj;
        int cnt = lcnt[brow]; if (cnt > XCAP) cnt = XCAP;
        if (cnt <= 64) {
            float d = (lane < cnt) ? bufd[brow][lane] : INFF;
            int   c = (lane < cnt) ? bufi[brow][lane] : 0x7fffffff;
            bitonic64_pair(d, c, lane);
            if (lane < 16) {
                int safe = ((unsigned)c < (unsigned)n) ? c : ((row + 1) & (n - 1));
                out_idx[row*16 + lane] = safe;
            }
        } else {
            select_slow(bufd[brow], bufi[brow], cnt, 16, row, n, out_idx, lane);
        }
    }
}

// ---------------- refiner EdgeConv (H1=384, H2=3), wave per point ------------------
__global__ __launch_bounds__(256) void edge_ref_kernel(const float* __restrict__ ur,
                                                       const float* __restrict__ vr,
                                                       const float* __restrict__ w2,
                                                       const float* __restrict__ b2,
                                                       const int* __restrict__ idx,
                                                       const float* __restrict__ xyz_in,
                                                       float* __restrict__ out, int n) {
    int wave = threadIdx.x >> 6, lane = threadIdx.x & 63;
    int i = blockIdx.x*4 + wave;
    if (i >= n) return;
    float m0 = -INFF, m1 = -INFF, m2 = -INFF;
    float uh[6];
    #pragma unroll
    for (int t = 0; t < 6; ++t) uh[t] = ur[(size_t)i*384 + lane + 64*t];
    for (int e = 0; e < KRR; ++e) {
        int j = idx[i*KRR + e];
        j = ((unsigned)j < (unsigned)n) ? j : i;
        float a0 = 0.f, a1 = 0.f, a2 = 0.f;
        #pragma unroll
        for (int t = 0; t < 6; ++t) {
            int h = lane + 64*t;
            float tv = frelu(uh[t] + vr[(size_t)j*384 + h]);
            a0 += tv*w2[h*3+0]; a1 += tv*w2[h*3+1]; a2 += tv*w2[h*3+2];
        }
        #pragma unroll
        for (int s = 32; s > 0; s >>= 1) {
            a0 += __shfl_xor(a0, s); a1 += __shfl_xor(a1, s); a2 += __shfl_xor(a2, s);
        }
        m0 = fmaxf(m0, a0 + b2[0]); m1 = fmaxf(m1, a1 + b2[1]); m2 = fmaxf(m2, a2 + b2[2]);
    }
    if (lane == 0) {
        out[i*3+0] = xyz_in[i*3+0] + m0;
        out[i*3+1] = xyz_in[i*3+1] + m1;
        out[i*3+2] = xyz_in[i*3+2] + m2;
    }
}

// ---------------- folding MLP, fused upsample+noise in, xyz1 + packed pts out ------
__global__ __launch_bounds__(256) void fold_kernel(const float* __restrict__ pred_xyz,
                                                   const float* __restrict__ noise,
                                                   const float* __restrict__ featd,
                                                   const float* __restrict__ w1, const float* __restrict__ b1,
                                                   const float* __restrict__ w2, const float* __restrict__ b2,
                                                   const float* __restrict__ w3, const float* __restrict__ b3,
                                                   float* __restrict__ xyz1, float4* __restrict__ pts_out) {
    const int PTS = 16;
    int base = blockIdx.x * PTS;
    int tid = threadIdx.x;
    __shared__ __align__(16) float xin[PTS][100];
    __shared__ __align__(16) float h1[PTS][FOLDH];
    __shared__ __align__(16) float h2s[PTS][FOLDH];
    __shared__ float oxyz[PTS][3];
    for (int t = tid; t < PTS*100; t += 256) {
        int pt = t/100, k = t - pt*100;
        int gi = base + pt;
        float vv = 0.f;
        if (k < 3) {
            int b = gi >> 11, p = (gi & 2047) >> 2;
            vv = pred_xyz[(size_t)(b*PDIM + p)*3 + k] + 0.02f*noise[(size_t)gi*3 + k];
        } else if (k < 99) {
            int b = gi >> 11, p = (gi & 2047) >> 2;
            vv = featd[(size_t)(b*PDIM + p)*H2C + (k - 3)];
        }
        xin[pt][k] = vv;
    }
    __syncthreads();
    int c = tid;
    float acc[PTS];
    #pragma unroll
    for (int pt = 0; pt < PTS; ++pt) acc[pt] = b1[c];
    for (int k0 = 0; k0 < 96; k0 += 4) {
        float wa = w1[(k0+0)*FOLDH + c], wb = w1[(k0+1)*FOLDH + c];
        float wc = w1[(k0+2)*FOLDH + c], wd = w1[(k0+3)*FOLDH + c];
        #pragma unroll
        for (int pt = 0; pt < PTS; ++pt) {
            float4 xv = *(const float4*)&xin[pt][k0];
            acc[pt] += xv.x*wa + xv.y*wb + xv.z*wc + xv.w*wd;
        }
    }
    {
        float wa = w1[96*FOLDH + c], wb = w1[97*FOLDH + c], wc = w1[98*FOLDH + c];
        #pragma unroll
        for (int pt = 0; pt < PTS; ++pt) {
            float4 xv = *(const float4*)&xin[pt][96];
            acc[pt] += xv.x*wa + xv.y*wb + xv.z*wc;
        }
    }
    #pragma unroll
    for (int pt = 0; pt < PTS; ++pt) h1[pt][c] = frelu(acc[pt]);
    __syncthreads();
    #pragma unroll
    for (int pt = 0; pt < PTS; ++pt) acc[pt] = b2[c];
    for (int k0 = 0; k0 < FOLDH; k0 += 4) {
        float wa = w2[(k0+0)*FOLDH + c], wb = w2[(k0+1)*FOLDH + c];
        float wc = w2[(k0+2)*FOLDH + c], wd = w2[(k0+3)*FOLDH + c];
        #pragma unroll
        for (int pt = 0; pt < PTS; ++pt) {
            float4 hv = *(const float4*)&h1[pt][k0];
            acc[pt] += hv.x*wa + hv.y*wb + hv.z*wc + hv.w*wd;
        }
    }
    #pragma unroll
    for (int pt = 0; pt < PTS; ++pt) h2s[pt][c] = frelu(acc[pt]);
    __syncthreads();
    if (tid < PTS*3) {
        int pt = tid/3, cc = tid - pt*3;
        float a = b3[cc];
        for (int k0 = 0; k0 < FOLDH; k0 += 4) {
            float4 hv = *(const float4*)&h2s[pt][k0];
            a += hv.x*w3[(k0+0)*3+cc] + hv.y*w3[(k0+1)*3+cc] + hv.z*w3[(k0+2)*3+cc] + hv.w*w3[(k0+3)*3+cc];
        }
        int gi = base + pt;
        float res = xin[pt][cc] + a;
        xyz1[(size_t)gi*3 + cc] = res;
        oxyz[pt][cc] = res;
    }
    __syncthreads();
    if (tid < PTS) {
        float x = oxyz[tid][0], y = oxyz[tid][1], z = oxyz[tid][2];
        pts_out[base + tid] = make_float4(x, y, z, x*x + y*y + z*z);
    }
}

extern "C" void kernel_launch(void* const* d_in, const int* in_sizes, int n_in,
                              void* d_out, int out_size, void* d_ws, size_t ws_size,
                              hipStream_t stream) {
    const float* ctx_xyz    = (const float*)d_in[0];
    const float* ctx_tokens = (const float*)d_in[1];
    const float* pred_xyz   = (const float*)d_in[2];
    const float* noise      = (const float*)d_in[4];
    const float* c1w1 = (const float*)d_in[5];
    const float* c1b1 = (const float*)d_in[6];
    const float* c1w2 = (const float*)d_in[7];
    const float* c1b2 = (const float*)d_in[8];
    const float* c2w1 = (const float*)d_in[9];
    const float* c2b1 = (const float*)d_in[10];
    const float* c2w2 = (const float*)d_in[11];
    const float* c2b2 = (const float*)d_in[12];
    const float* cdw1 = (const float*)d_in[13];
    const float* cdb1 = (const float*)d_in[14];
    const float* cdw2 = (const float*)d_in[15];
    const float* cdb2 = (const float*)d_in[16];
    const float* fw1  = (const float*)d_in[17];
    const float* fb1  = (const float*)d_in[18];
    const float* fw2  = (const float*)d_in[19];
    const float* fb2  = (const float*)d_in[20];
    const float* fw3  = (const float*)d_in[21];
    const float* fb3  = (const float*)d_in[22];
    const float* rw1  = (const float*)d_in[23];
    const float* rb1  = (const float*)d_in[24];
    const float* rw2  = (const float*)d_in[25];
    const float* rb2  = (const float*)d_in[26];

    float* W = (float*)d_ws;
    // Zone A (staged aliasing): dist/distB (S1/S3) -> cfeat (S4) -> ur/vr (S8)
    float* dist  = W;                   // 2048*2048
    float* distB = W + 4194304;
    float* cfeat = W;                   // 2048*96 (after dist dead)
    float* ur    = W;                   // 8192*384 (after cfeat dead)
    float* vr    = W + 3145728;
    // Persistent zone:
    float* h_ctx = W + 8388608;         // 393,216
    float* h_tgt = h_ctx + 393216;
    float* UV    = h_tgt + 393216;      // [u1|v1] then [u2c|v2c|u2t|v2t]
    float* u1  = UV;            float* v1  = UV + 393216;
    float* u2c = UV;            float* v2c = UV + 196608;
    float* u2t = UV + 393216;   float* v2t = UV + 589824;
    float* tfeat = UV + 786432;         // 196,608
    float* xyz1  = tfeat + 196608;      // 24,576
    float4* pts  = (float4*)(xyz1 + 24576);
    float* sqb     = (float*)pts + 32768;
    float* sq_hctx = sqb + N2;
    float* sq_htgt = sq_hctx + N2;
    int* cidx1 = (int*)(sq_htgt + N2);
    int* cidx2 = cidx1 + N2*16;
    int* tidx2 = cidx2 + N2*8;
    int* ridx  = tidx2 + N2*2;

    float* out_ctx = (float*)d_out;
    float* out_tgt = out_ctx + N2*3;

    dim3 b16(16, 16);
    const int NTRI = 32*33/2;
    const float* NUL = nullptr;

    // --- S1: rowsq, dist(tokens), knn16 (tgt conv1 uses first 4 of cidx1)
    rowsq_kernel<<<N2/4, 256, 0, stream>>>(ctx_tokens, sqb, CDIM);
    dist64tri_kernel<<<NTRI, b16, 0, stream>>>(ctx_tokens, sqb, dist, N2, CDIM);
    knn_dist_rt_kernel<<<N2/4, 256, 0, stream>>>(dist, dist, N2, cidx1, cidx1, 16, 16, N2/4);

    // --- S2: u1/v1 GEMMs; conv1 fused gather-GEMM+reg-max; row-sq of h
    gemmquad_kernel<<<dim3(3, 32, 2), b16, 0, stream>>>(
        ctx_tokens, c1w1, c1w1 + 384*192, c1b1, u1,
        ctx_tokens, c1w1 + 384*192, NUL, NUL, v1,
        ctx_tokens, c1w1, NUL, NUL, u1,   // unused (z<2)
        ctx_tokens, c1w1, NUL, NUL, v1,
        H1C, CDIM);
    edge_fused1_kernel<<<dim3(3, 512, 2), b16, 0, stream>>>(u1, v1, cidx1, c1w2, c1b2,
                                                            h_ctx, h_tgt, N2);
    rowsqpair_kernel<<<dim3(N2/4, 2), 256, 0, stream>>>(h_ctx, sq_hctx, h_tgt, sq_htgt, H1C);

    // --- S3: dist(h_ctx)+dist(h_tgt), paired knn, u2/v2 quad
    distpairtri_kernel<<<dim3(NTRI, 1, 2), b16, 0, stream>>>(h_ctx, sq_hctx, dist,
                                                             h_tgt, sq_htgt, distB, N2, H1C);
    knn_dist_rt_kernel<<<2*(N2/4), 256, 0, stream>>>(dist, distB, N2, cidx2, tidx2, 8, 2, N2/4);
    gemmquad_kernel<<<dim3(2, 32, 4), b16, 0, stream>>>(
        h_ctx, c2w1, c2w1 + 192*96, c2b1, u2c,
        h_ctx, c2w1 + 192*96, NUL, NUL, v2c,
        h_tgt, c2w1, c2w1 + 192*96, c2b1, u2t,
        h_tgt, c2w1 + 192*96, NUL, NUL, v2t,
        H2C, H1C);

    // --- S4: conv2 fused gather-GEMM+reg-max; cdef head
    edge_fused2_kernel<<<dim3(2, 256, 2), b16, 0, stream>>>(u2c, v2c, u2t, v2t, cidx2, tidx2,
                                                            c2w2, c2b2, cfeat, tfeat, N2);
    cdef_kernel<<<N2, 128, 0, stream>>>(cfeat, cdw1, cdb1, cdw2, cdb2, ctx_xyz, out_ctx);

    // --- S6: folding MLP (fused upsample+noise; emits xyz1 + packed pts)
    fold_kernel<<<N8/16, 256, 0, stream>>>(pred_xyz, noise, tfeat, fw1, fb1, fw2, fb2, fw3, fb3, xyz1, pts);

    // --- S7: refiner knn (4 rows/wave)
    knn_xyz16_kernel<<<N8/16, 256, 0, stream>>>(pts, N8, ridx);

    // --- S8: refiner u/v gather-GEMMs, residual EdgeConv to output
    gatherpair_kernel<<<dim3(6, N8/64, 2), b16, 0, stream>>>(
        tfeat, xyz1,
        rw1, rw1 + 99*384, rb1, ur,
        rw1 + 99*384, NUL, NUL, vr,
        384, 99);
    edge_ref_kernel<<<N8/4, 256, 0, stream>>>(ur, vr, rw2, rb2, ridx, xyz1, out_tgt, N8);
}

// Round 13
// 447.612 us; speedup vs baseline: 1.0658x; 1.0407x over previous
//
#include <hip/hip_runtime.h>

#define N2 2048      // B*P
#define N8 8192      // B*P*UP
#define CDIM 384
#define H1C 192      // C/2
#define H2C 96       // C/4
#define PDIM 512
#define KRR 16
#define FOLDH 256
#define XCAP 256
#define XCAPX 128
#define XTILE 1024
#define INFF 3.0e38f

__device__ __forceinline__ float frelu(float x) { return x > 0.f ? x : 0.f; }

// ---------------- 64-lane bitonic sorts (ascending) --------------------------------
__device__ __forceinline__ void bitonic64_val(float& d, int lane) {
    #pragma unroll
    for (int k = 2; k <= 64; k <<= 1) {
        #pragma unroll
        for (int j = k >> 1; j > 0; j >>= 1) {
            float od = __shfl_xor(d, j);
            bool lower = (lane & j) == 0;
            bool olt = od < d;
            bool take = lower ? olt : !olt;
            if (lane & k) take = !take;
            if (take) d = od;
        }
    }
}

__device__ __forceinline__ void bitonic64_pair(float& d, int& c, int lane) {
    #pragma unroll
    for (int k = 2; k <= 64; k <<= 1) {
        #pragma unroll
        for (int j = k >> 1; j > 0; j >>= 1) {
            float od = __shfl_xor(d, j);
            int   oc = __shfl_xor(c, j);
            bool lower = (lane & j) == 0;
            bool olt = (od < d) || (od == d && oc < c);
            bool take = lower ? olt : !olt;
            if (lane & k) take = !take;
            if (take) { d = od; c = oc; }
        }
    }
}

// ---------------- slow exact select fallback (cnt > 64, rare) ----------------------
__device__ __forceinline__ void select_slow(const float* bd, const int* bi, int cnt,
                                            int ksel, int row, int n, int* out, int lane) {
    float cd[4]; int cix[4];
    #pragma unroll
    for (int s = 0; s < 4; ++s) {
        int c = lane + 64*s;
        bool v = c < cnt;
        cd[s]  = v ? bd[c] : INFF;
        cix[s] = v ? bi[c] : 0x7fffffff;
    }
    for (int r = 0; r < ksel; ++r) {
        float lv = cd[0]; int li = cix[0];
        #pragma unroll
        for (int s = 1; s < 4; ++s) {
            if (cd[s] < lv || (cd[s] == lv && cix[s] < li)) { lv = cd[s]; li = cix[s]; }
        }
        float wv = lv; int wi = li;
        #pragma unroll
        for (int s = 1; s < 64; s <<= 1) {
            float ov = __shfl_xor(wv, s); int oi = __shfl_xor(wi, s);
            if (ov < wv || (ov == wv && oi < wi)) { wv = ov; wi = oi; }
        }
        if (lane == 0) {
            int safe = ((unsigned)wi < (unsigned)n) ? wi : ((row + 1) & (n - 1));
            out[row*ksel + r] = safe;
        }
        #pragma unroll
        for (int s = 0; s < 4; ++s) {
            if (cd[s] == wv && cix[s] == wi) { cd[s] = INFF; cix[s] = 0x7fffffff; }
        }
    }
}

// ---------------- row squared norms (wave per row; single + paired) ----------------
__global__ __launch_bounds__(256) void rowsq_kernel(const float* __restrict__ x,
                                                    float* __restrict__ sq, int d) {
    int wave = threadIdx.x >> 6, lane = threadIdx.x & 63;
    int row = blockIdx.x*4 + wave;
    float acc = 0.f;
    for (int k = lane; k < d; k += 64) { float v = x[(size_t)row*d + k]; acc += v*v; }
    #pragma unroll
    for (int s = 1; s < 64; s <<= 1) acc += __shfl_xor(acc, s);
    if (lane == 0) sq[row] = acc;
}

__global__ __launch_bounds__(256) void rowsqpair_kernel(const float* __restrict__ xA,
                                                        float* __restrict__ sqA,
                                                        const float* __restrict__ xB,
                                                        float* __restrict__ sqB, int d) {
    const float* x = blockIdx.y ? xB : xA;
    float* sq = blockIdx.y ? sqB : sqA;
    int wave = threadIdx.x >> 6, lane = threadIdx.x & 63;
    int row = blockIdx.x*4 + wave;
    float acc = 0.f;
    for (int k = lane; k < d; k += 64) { float v = x[(size_t)row*d + k]; acc += v*v; }
    #pragma unroll
    for (int s = 1; s < 64; s <<= 1) acc += __shfl_xor(acc, s);
    if (lane == 0) sq[row] = acc;
}

// ---------------- triangular symmetric dist: direct + mirrored tile ----------------
__device__ __forceinline__ void disttri_body(const float* __restrict__ x, const float* __restrict__ sq,
                                             float* __restrict__ dist, int n, int K) {
    int l = blockIdx.x;
    int by = (int)((sqrtf(8.f*(float)l + 1.f) - 1.f)*0.5f);
    while ((by+1)*(by+2)/2 <= l) ++by;
    while (by*(by+1)/2 > l) --by;
    int bx = l - by*(by+1)/2;
    int row0 = by*64, col0 = bx*64;
    __shared__ __align__(16) float As[16][68];
    __shared__ __align__(16) float Bs[16][68];
    __shared__ __align__(16) float T[64][68];
    int tx = threadIdx.x, ty = threadIdx.y;
    int t = ty*16 + tx;
    float acc[4][4] = {};
    for (int k0 = 0; k0 < K; k0 += 16) {
        #pragma unroll
        for (int r = 0; r < 4; ++r) {
            int e = t + 256*r; int kk = e & 15, mm = e >> 4;
            As[kk][mm] = x[(size_t)(row0+mm)*K + k0+kk];
            Bs[kk][mm] = x[(size_t)(col0+mm)*K + k0+kk];
        }
        __syncthreads();
        #pragma unroll
        for (int kk = 0; kk < 16; ++kk) {
            float4 a4 = *(const float4*)&As[kk][ty*4];
            float4 b4 = *(const float4*)&Bs[kk][tx*4];
            acc[0][0] += a4.x*b4.x; acc[0][1] += a4.x*b4.y; acc[0][2] += a4.x*b4.z; acc[0][3] += a4.x*b4.w;
            acc[1][0] += a4.y*b4.x; acc[1][1] += a4.y*b4.y; acc[1][2] += a4.y*b4.z; acc[1][3] += a4.y*b4.w;
            acc[2][0] += a4.z*b4.x; acc[2][1] += a4.z*b4.y; acc[2][2] += a4.z*b4.z; acc[2][3] += a4.z*b4.w;
            acc[3][0] += a4.w*b4.x; acc[3][1] += a4.w*b4.y; acc[3][2] += a4.w*b4.z; acc[3][3] += a4.w*b4.w;
        }
        __syncthreads();
    }
    bool mirror = (row0 != col0);
    #pragma unroll
    for (int i2 = 0; i2 < 4; ++i2) {
        int row = row0 + ty*4 + i2;
        float sr = sq[row];
        float4 o;
        o.x = sr + sq[col0+tx*4+0] - 2.f*acc[i2][0];
        o.y = sr + sq[col0+tx*4+1] - 2.f*acc[i2][1];
        o.z = sr + sq[col0+tx*4+2] - 2.f*acc[i2][2];
        o.w = sr + sq[col0+tx*4+3] - 2.f*acc[i2][3];
        *(float4*)&dist[(size_t)row*n + col0 + tx*4] = o;
        if (mirror) {
            T[tx*4+0][ty*4+i2] = o.x;
            T[tx*4+1][ty*4+i2] = o.y;
            T[tx*4+2][ty*4+i2] = o.z;
            T[tx*4+3][ty*4+i2] = o.w;
        }
    }
    if (mirror) {
        __syncthreads();
        #pragma unroll
        for (int i2 = 0; i2 < 4; ++i2) {
            int orow = col0 + ty*4 + i2;
            float4 o = *(const float4*)&T[ty*4+i2][tx*4];
            *(float4*)&dist[(size_t)orow*n + row0 + tx*4] = o;
        }
    }
}

__global__ __launch_bounds__(256) void dist64tri_kernel(const float* __restrict__ x,
                                                        const float* __restrict__ sq,
                                                        float* __restrict__ dist, int n, int K) {
    disttri_body(x, sq, dist, n, K);
}

__global__ __launch_bounds__(256) void distpairtri_kernel(const float* __restrict__ xA,
                                                          const float* __restrict__ sqA,
                                                          float* __restrict__ dA,
                                                          const float* __restrict__ xB,
                                                          const float* __restrict__ sqB,
                                                          float* __restrict__ dB, int n, int K) {
    const float* x  = blockIdx.z ? xB : xA;
    const float* sq = blockIdx.z ? sqB : sqA;
    float* dist     = blockIdx.z ? dB : dA;
    disttri_body(x, sq, dist, n, K);
}

// ---------------- shared 64x64 GEMM tile body: C = A @ (Bw - BwB) + bias -----------
__device__ __forceinline__ void gemm_body(const float* __restrict__ A, const float* __restrict__ Bw,
                                          const float* __restrict__ BwB, const float* __restrict__ bias,
                                          float* __restrict__ C, int m, int K) {
    __shared__ __align__(16) float As[16][68];
    __shared__ __align__(16) float Bs[16][68];
    int tx = threadIdx.x, ty = threadIdx.y;
    int t = ty*16 + tx;
    int row0 = blockIdx.y*64, col0 = blockIdx.x*64;
    float acc[4][4] = {};
    for (int k0 = 0; k0 < K; k0 += 16) {
        #pragma unroll
        for (int r = 0; r < 4; ++r) {
            int e = t + 256*r; int kk = e & 15, mm = e >> 4;
            As[kk][mm] = (k0 + kk < K) ? A[(size_t)(row0+mm)*K + k0+kk] : 0.f;
        }
        #pragma unroll
        for (int r = 0; r < 4; ++r) {
            int e = t + 256*r; int nn = e & 63, kk = e >> 6;
            int col = col0 + nn, k = k0 + kk;
            float bv = 0.f;
            if (k < K && col < m) {
                bv = Bw[(size_t)k*m + col];
                if (BwB) bv -= BwB[(size_t)k*m + col];
            }
            Bs[kk][nn] = bv;
        }
        __syncthreads();
        #pragma unroll
        for (int kk = 0; kk < 16; ++kk) {
            float4 a4 = *(const float4*)&As[kk][ty*4];
            float4 b4 = *(const float4*)&Bs[kk][tx*4];
            acc[0][0] += a4.x*b4.x; acc[0][1] += a4.x*b4.y; acc[0][2] += a4.x*b4.z; acc[0][3] += a4.x*b4.w;
            acc[1][0] += a4.y*b4.x; acc[1][1] += a4.y*b4.y; acc[1][2] += a4.y*b4.z; acc[1][3] += a4.y*b4.w;
            acc[2][0] += a4.z*b4.x; acc[2][1] += a4.z*b4.y; acc[2][2] += a4.z*b4.z; acc[2][3] += a4.z*b4.w;
            acc[3][0] += a4.w*b4.x; acc[3][1] += a4.w*b4.y; acc[3][2] += a4.w*b4.z; acc[3][3] += a4.w*b4.w;
        }
        __syncthreads();
    }
    #pragma unroll
    for (int i2 = 0; i2 < 4; ++i2) {
        int row = row0 + ty*4 + i2;
        #pragma unroll
        for (int j2 = 0; j2 < 4; ++j2) {
            int col = col0 + tx*4 + j2;
            if (col < m) C[(size_t)row*m + col] = acc[i2][j2] + (bias ? bias[col] : 0.f);
        }
    }
}

__global__ __launch_bounds__(256) void gemmquad_kernel(
    const float* A0, const float* Bw0, const float* BwB0, const float* bias0, float* C0,
    const float* A1, const float* Bw1, const float* BwB1, const float* bias1, float* C1,
    const float* A2, const float* Bw2, const float* BwB2, const float* bias2, float* C2,
    const float* A3, const float* Bw3, const float* BwB3, const float* bias3, float* C3,
    int m, int K) {
    int z = blockIdx.z;
    const float* A    = (z==0)?A0 :(z==1)?A1 :(z==2)?A2 :A3;
    const float* Bw   = (z==0)?Bw0:(z==1)?Bw1:(z==2)?Bw2:Bw3;
    const float* BwB  = (z==0)?BwB0:(z==1)?BwB1:(z==2)?BwB2:BwB3;
    const float* bias = (z==0)?bias0:(z==1)?bias1:(z==2)?bias2:bias3;
    float* C          = (z==0)?C0 :(z==1)?C1 :(z==2)?C2 :C3;
    gemm_body(A, Bw, BwB, bias, C, m, K);
}

// ---------------- EdgeConv layer-2 gather-GEMM, reg-max, coalesced fill ------------
// Thread t owns A-row mmA=t>>2, k-slab kqA=(t&3)*4 -> i/j/idx hoisted out of k-loop;
// u/v read as aligned float4. B read as float4. Same cells/values as before.
template<int EPT, int SELF, int EREAL, int IDXS, int YT>
__device__ __forceinline__ void edge_fused_body(const float* __restrict__ u, const float* __restrict__ v,
                                                const int* __restrict__ idx,
                                                const float* __restrict__ Bw, const float* __restrict__ bias,
                                                float* __restrict__ hout, int m, int K, int npts) {
    if ((int)blockIdx.y >= YT) return;
    constexpr int LOG2EPT = (EPT == 16) ? 4 : (EPT == 8) ? 3 : 2;
    __shared__ __align__(16) float As[16][68];
    __shared__ __align__(16) float Bs[16][68];
    int tx = threadIdx.x, ty = threadIdx.y;
    int t = ty*16 + tx;
    int row0 = blockIdx.y*64, col0 = blockIdx.x*64;
    // hoisted per-thread A-fill assignment
    int mmA = t >> 2;
    int kqA = (t & 3) * 4;
    int rowA = row0 + mmA;
    int iA = rowA >> LOG2EPT;
    int eA = rowA - (iA << LOG2EPT);
    int jA;
    if (SELF && eA == 0) jA = iA;
    else if (eA < EREAL) jA = idx[iA*IDXS + (eA - SELF)];
    else jA = iA;
    jA = ((unsigned)jA < (unsigned)npts) ? jA : iA;
    const float* uRow = u + (size_t)iA*K + kqA;
    const float* vRow = v + (size_t)jA*K + kqA;
    int nnB = (t & 15) * 4, kkB = t >> 4;
    float acc[4][4] = {};
    for (int k0 = 0; k0 < K; k0 += 16) {
        float4 u4 = *(const float4*)(uRow + k0);
        float4 v4 = *(const float4*)(vRow + k0);
        As[kqA+0][mmA] = frelu(u4.x + v4.x);
        As[kqA+1][mmA] = frelu(u4.y + v4.y);
        As[kqA+2][mmA] = frelu(u4.z + v4.z);
        As[kqA+3][mmA] = frelu(u4.w + v4.w);
        int colB = col0 + nnB;
        if (colB + 3 < m) {
            *(float4*)&Bs[kkB][nnB] = *(const float4*)&Bw[(size_t)(k0+kkB)*m + colB];
        } else {
            #pragma unroll
            for (int q = 0; q < 4; ++q) {
                int col = colB + q;
                Bs[kkB][nnB+q] = (col < m) ? Bw[(size_t)(k0+kkB)*m + col] : 0.f;
            }
        }
        __syncthreads();
        #pragma unroll
        for (int kk = 0; kk < 16; ++kk) {
            float4 a4 = *(const float4*)&As[kk][ty*4];
            float4 b4 = *(const float4*)&Bs[kk][tx*4];
            acc[0][0] += a4.x*b4.x; acc[0][1] += a4.x*b4.y; acc[0][2] += a4.x*b4.z; acc[0][3] += a4.x*b4.w;
            acc[1][0] += a4.y*b4.x; acc[1][1] += a4.y*b4.y; acc[1][2] += a4.y*b4.z; acc[1][3] += a4.y*b4.w;
            acc[2][0] += a4.z*b4.x; acc[2][1] += a4.z*b4.y; acc[2][2] += a4.z*b4.z; acc[2][3] += a4.z*b4.w;
            acc[3][0] += a4.w*b4.x; acc[3][1] += a4.w*b4.y; acc[3][2] += a4.w*b4.z; acc[3][3] += a4.w*b4.w;
        }
        __syncthreads();
    }
    float bestv[4];
    #pragma unroll
    for (int j2 = 0; j2 < 4; ++j2)
        bestv[j2] = fmaxf(fmaxf(acc[0][j2], acc[1][j2]), fmaxf(acc[2][j2], acc[3][j2]));
    if (EPT >= 8) {
        #pragma unroll
        for (int j2 = 0; j2 < 4; ++j2) bestv[j2] = fmaxf(bestv[j2], __shfl_xor(bestv[j2], 16));
    }
    if (EPT == 16) {
        #pragma unroll
        for (int j2 = 0; j2 < 4; ++j2) bestv[j2] = fmaxf(bestv[j2], __shfl_xor(bestv[j2], 32));
    }
    bool writer; int p;
    if (EPT == 16) { writer = (ty & 3) == 0; p = (row0 >> 4) + (ty >> 2); }
    else if (EPT == 8) { writer = (ty & 1) == 0; p = (row0 >> 3) + (ty >> 1); }
    else { writer = true; p = (row0 >> 2) + ty; }
    if (writer) {
        #pragma unroll
        for (int j2 = 0; j2 < 4; ++j2) {
            int col = col0 + tx*4 + j2;
            if (col < m) hout[(size_t)p*m + col] = bestv[j2] + bias[col];
        }
    }
}

__global__ __launch_bounds__(256) void edge_fused1_kernel(const float* u1, const float* v1,
                                                          const int* cidx1,
                                                          const float* Bw, const float* bias,
                                                          float* h_ctx, float* h_tgt, int npts) {
    if (blockIdx.z == 0) edge_fused_body<16,0,16,16,512>(u1, v1, cidx1, Bw, bias, h_ctx, H1C, H1C, npts);
    else                 edge_fused_body<8,1,5,16,256>(u1, v1, cidx1, Bw, bias, h_tgt, H1C, H1C, npts);
}

__global__ __launch_bounds__(256) void edge_fused2_kernel(const float* u2c, const float* v2c,
                                                          const float* u2t, const float* v2t,
                                                          const int* cidx2, const int* tidx2,
                                                          const float* Bw, const float* bias,
                                                          float* cfeat, float* tfeat, int npts) {
    if (blockIdx.z == 0) edge_fused_body<8,0,8,8,256>(u2c, v2c, cidx2, Bw, bias, cfeat, H2C, H2C, npts);
    else                 edge_fused_body<4,1,3,2,128>(u2t, v2t, tidx2, Bw, bias, tfeat, H2C, H2C, npts);
}

// ---------------- ctx deform head: out = xyz + 0.05 * mlp2(cfeat) ------------------
__global__ __launch_bounds__(128) void cdef_kernel(const float* __restrict__ cfeat,
                                                   const float* __restrict__ cdw1, const float* __restrict__ cdb1,
                                                   const float* __restrict__ cdw2, const float* __restrict__ cdb2,
                                                   const float* __restrict__ ctx_xyz,
                                                   float* __restrict__ out_ctx) {
    int i = blockIdx.x, tid = threadIdx.x, wave = tid >> 6, lane = tid & 63;
    __shared__ float sf_[96], st2_[96];
    if (tid < 96) sf_[tid] = cfeat[(size_t)i*H2C + tid];
    __syncthreads();
    if (tid < 96) {
        float a = cdb1[tid];
        for (int k = 0; k < 96; ++k) a += sf_[k]*cdw1[k*96 + tid];
        st2_[tid] = frelu(a);
    }
    __syncthreads();
    if (wave == 0) {
        float s0 = st2_[lane];
        float p0 = s0*cdw2[lane*3+0], p1 = s0*cdw2[lane*3+1], p2 = s0*cdw2[lane*3+2];
        if (lane < 32) {
            float s1 = st2_[lane+64];
            p0 += s1*cdw2[(lane+64)*3+0];
            p1 += s1*cdw2[(lane+64)*3+1];
            p2 += s1*cdw2[(lane+64)*3+2];
        }
        #pragma unroll
        for (int s = 1; s < 64; s <<= 1) {
            p0 += __shfl_xor(p0, s); p1 += __shfl_xor(p1, s); p2 += __shfl_xor(p2, s);
        }
        if (lane == 0) {
            out_ctx[i*3+0] = ctx_xyz[i*3+0] + 0.05f*(cdb2[0] + p0);
            out_ctx[i*3+1] = ctx_xyz[i*3+1] + 0.05f*(cdb2[1] + p1);
            out_ctx[i*3+2] = ctx_xyz[i*3+2] + 0.05f*(cdb2[2] + p2);
        }
    }
}

// refiner gather-GEMM pair: A row gathered from [featd(96) | xyzg(3)], K = 99
__global__ __launch_bounds__(256) void gatherpair_kernel(
    const float* __restrict__ featd, const float* __restrict__ xyzg,
    const float* Bw0, const float* BwB0, const float* bias0, float* C0,
    const float* Bw1, const float* BwB1, const float* bias1, float* C1,
    int m, int K) {
    int z = blockIdx.z;
    const float* Bw   = z ? Bw1 : Bw0;
    const float* BwB  = z ? BwB1 : BwB0;
    const float* bias = z ? bias1 : bias0;
    float* C          = z ? C1 : C0;
    __shared__ __align__(16) float As[16][68];
    __shared__ __align__(16) float Bs[16][68];
    int tx = threadIdx.x, ty = threadIdx.y;
    int t = ty*16 + tx;
    int row0 = blockIdx.y*64, col0 = blockIdx.x*64;
    float acc[4][4] = {};
    for (int k0 = 0; k0 < K; k0 += 16) {
        #pragma unroll
        for (int r = 0; r < 4; ++r) {
            int e = t + 256*r; int kk = e & 15, mm = e >> 4;
            int k = k0 + kk, grow = row0 + mm;
            float av = 0.f;
            if (k < K) {
                if (k < 96) { int b = grow >> 11, p = (grow & 2047) >> 2;
                              av = featd[(size_t)(b*PDIM + p)*H2C + k]; }
                else av = xyzg[(size_t)grow*3 + (k - 96)];
            }
            As[kk][mm] = av;
        }
        #pragma unroll
        for (int r = 0; r < 4; ++r) {
            int e = t + 256*r; int nn = e & 63, kk = e >> 6;
            int col = col0 + nn, k = k0 + kk;
            float bv = 0.f;
            if (k < K && col < m) {
                bv = Bw[(size_t)k*m + col];
                if (BwB) bv -= BwB[(size_t)k*m + col];
            }
            Bs[kk][nn] = bv;
        }
        __syncthreads();
        #pragma unroll
        for (int kk = 0; kk < 16; ++kk) {
            float4 a4 = *(const float4*)&As[kk][ty*4];
            float4 b4 = *(const float4*)&Bs[kk][tx*4];
            acc[0][0] += a4.x*b4.x; acc[0][1] += a4.x*b4.y; acc[0][2] += a4.x*b4.z; acc[0][3] += a4.x*b4.w;
            acc[1][0] += a4.y*b4.x; acc[1][1] += a4.y*b4.y; acc[1][2] += a4.y*b4.z; acc[1][3] += a4.y*b4.w;
            acc[2][0] += a4.z*b4.x; acc[2][1] += a4.z*b4.y; acc[2][2] += a4.z*b4.z; acc[2][3] += a4.z*b4.w;
            acc[3][0] += a4.w*b4.x; acc[3][1] += a4.w*b4.y; acc[3][2] += a4.w*b4.z; acc[3][3] += a4.w*b4.w;
        }
        __syncthreads();
    }
    #pragma unroll
    for (int i2 = 0; i2 < 4; ++i2) {
        int row = row0 + ty*4 + i2;
        #pragma unroll
        for (int j2 = 0; j2 < 4; ++j2) {
            int col = col0 + tx*4 + j2;
            if (col < m) C[(size_t)row*m + col] = acc[i2][j2] + (bias ? bias[col] : 0.f);
        }
    }
}

// ---------------- knn from dist rows (4 rows/block, bitonic select) ----------------
__global__ __launch_bounds__(256) void knn_dist_rt_kernel(const float* __restrict__ dA,
                                                          const float* __restrict__ dB, int n,
                                                          int* __restrict__ outA, int* __restrict__ outB,
                                                          int kA, int kB, int nblkA) {
    int wave = threadIdx.x >> 6, lane = threadIdx.x & 63;
    bool useB = (int)blockIdx.x >= nblkA;
    const float* dist = useB ? dB : dA;
    int* out = useB ? outB : outA;
    int ksel = useB ? kB : kA;
    int bx = useB ? (int)blockIdx.x - nblkA : (int)blockIdx.x;
    int row = bx*4 + wave;
    __shared__ float bufd[4][XCAP];
    __shared__ int   bufi[4][XCAP];
    __shared__ int   lcnt[4];
    const float4* drow = (const float4*)(dist + (size_t)row*n);
    int nq = n >> 2;
    float mv = INFF;
    for (int i = lane; i < nq; i += 64) {
        float4 d4 = drow[i]; int base = i*4;
        float a = (base+0 == row) ? INFF : d4.x;
        float b = (base+1 == row) ? INFF : d4.y;
        float c = (base+2 == row) ? INFF : d4.z;
        float d = (base+3 == row) ? INFF : d4.w;
        mv = fminf(mv, fminf(fminf(a,b), fminf(c,d)));
    }
    float sd = mv;
    bitonic64_val(sd, lane);
    float Tv = __shfl(sd, ksel - 1);
    if (lane == 0) lcnt[wave] = 0;
    for (int i = lane; i < nq; i += 64) {
        float4 d4 = drow[i]; int base = i*4;
        float dv4[4] = {d4.x, d4.y, d4.z, d4.w};
        #pragma unroll
        for (int q = 0; q < 4; ++q) {
            int col = base + q;
            if (col != row && dv4[q] <= Tv) {
                int pos = atomicAdd(&lcnt[wave], 1);
                if (pos < XCAP) { bufd[wave][pos] = dv4[q]; bufi[wave][pos] = col; }
            }
        }
    }
    int cnt = lcnt[wave]; if (cnt > XCAP) cnt = XCAP;
    if (cnt <= 64) {
        float d = (lane < cnt) ? bufd[wave][lane] : INFF;
        int   c = (lane < cnt) ? bufi[wave][lane] : 0x7fffffff;
        bitonic64_pair(d, c, lane);
        if (lane < ksel) {
            int safe = ((unsigned)c < (unsigned)n) ? c : ((row + 1) & (n - 1));
            out[row*ksel + lane] = safe;
        }
    } else {
        select_slow(bufd[wave], bufi[wave], cnt, ksel, row, n, out, lane);
    }
}

// ---------------- knn over packed xyz: 16 rows/block, 4 rows/wave, XCAPX bufs ------
__global__ __launch_bounds__(256) void knn_xyz16_kernel(const float4* __restrict__ pts, int n,
                                                        int* __restrict__ out_idx) {
    int tid = threadIdx.x, wave = tid >> 6, lane = tid & 63;
    int rbase = blockIdx.x*16 + wave*4;
    __shared__ __align__(16) float4 tile[XTILE];
    __shared__ float bufd[16][XCAPX];
    __shared__ int   bufi[16][XCAPX];
    __shared__ int   lcnt[16];
    float4 P0 = pts[rbase], P1 = pts[rbase+1], P2 = pts[rbase+2], P3 = pts[rbase+3];
    float mv0 = INFF, mv1 = INFF, mv2 = INFF, mv3 = INFF;
    for (int t0 = 0; t0 < n; t0 += XTILE) {
        __syncthreads();
        #pragma unroll
        for (int k = 0; k < XTILE/256; ++k) tile[tid + 256*k] = pts[t0 + tid + 256*k];
        __syncthreads();
        for (int c = lane; c < XTILE; c += 64) {
            float4 q = tile[c];
            int col = t0 + c;
            float d0 = P0.w + q.w - 2.f*(P0.x*q.x + P0.y*q.y + P0.z*q.z);
            float d1 = P1.w + q.w - 2.f*(P1.x*q.x + P1.y*q.y + P1.z*q.z);
            float d2 = P2.w + q.w - 2.f*(P2.x*q.x + P2.y*q.y + P2.z*q.z);
            float d3 = P3.w + q.w - 2.f*(P3.x*q.x + P3.y*q.y + P3.z*q.z);
            d0 = (col == rbase)   ? INFF : d0;
            d1 = (col == rbase+1) ? INFF : d1;
            d2 = (col == rbase+2) ? INFF : d2;
            d3 = (col == rbase+3) ? INFF : d3;
            mv0 = fminf(mv0, d0); mv1 = fminf(mv1, d1);
            mv2 = fminf(mv2, d2); mv3 = fminf(mv3, d3);
        }
    }
    bitonic64_val(mv0, lane); bitonic64_val(mv1, lane);
    bitonic64_val(mv2, lane); bitonic64_val(mv3, lane);
    float Tv0 = __shfl(mv0, 15), Tv1 = __shfl(mv1, 15);
    float Tv2 = __shfl(mv2, 15), Tv3 = __shfl(mv3, 15);
    if (lane < 4) lcnt[wave*4 + lane] = 0;
    for (int t0 = 0; t0 < n; t0 += XTILE) {
        __syncthreads();
        #pragma unroll
        for (int k = 0; k < XTILE/256; ++k) tile[tid + 256*k] = pts[t0 + tid + 256*k];
        __syncthreads();
        for (int c = lane; c < XTILE; c += 64) {
            float4 q = tile[c];
            int col = t0 + c;
            float d0 = P0.w + q.w - 2.f*(P0.x*q.x + P0.y*q.y + P0.z*q.z);
            float d1 = P1.w + q.w - 2.f*(P1.x*q.x + P1.y*q.y + P1.z*q.z);
            float d2 = P2.w + q.w - 2.f*(P2.x*q.x + P2.y*q.y + P2.z*q.z);
            float d3 = P3.w + q.w - 2.f*(P3.x*q.x + P3.y*q.y + P3.z*q.z);
            if (col != rbase && d0 <= Tv0) {
                int pos = atomicAdd(&lcnt[wave*4+0], 1);
                if (pos < XCAPX) { bufd[wave*4+0][pos] = d0; bufi[wave*4+0][pos] = col; }
            }
            if (col != rbase+1 && d1 <= Tv1) {
                int pos = atomicAdd(&lcnt[wave*4+1], 1);
                if (pos < XCAPX) { bufd[wave*4+1][pos] = d1; bufi[wave*4+1][pos] = col; }
            }
            if (col != rbase+2 && d2 <= Tv2) {
                int pos = atomicAdd(&lcnt[wave*4+2], 1);
                if (pos < XCAPX) { bufd[wave*4+2][pos] = d2; bufi[wave*4+2][pos] = col; }
            }
            if (col != rbase+3 && d3 <= Tv3) {
                int pos = atomicAdd(&lcnt[wave*4+3], 1);
                if (pos < XCAPX) { bufd[wave*4+3][pos] = d3; bufi[wave*4+3][pos] = col; }
            }
        }
    }
    for (int jj = 0; jj < 4; ++jj) {
        int brow = wave*4 + jj, row = rbase + jj;
        int cnt = lcnt[brow]; if (cnt > XCAPX) cnt = XCAPX;
        if (cnt <= 64) {
            float d = (lane < cnt) ? bufd[brow][lane] : INFF;
            int   c = (lane < cnt) ? bufi[brow][lane] : 0x7fffffff;
            bitonic64_pair(d, c, lane);
            if (lane < 16) {
                int safe = ((unsigned)c < (unsigned)n) ? c : ((row + 1) & (n - 1));
                out_idx[row*16 + lane] = safe;
            }
        } else {
            float cd[2]; int cix[2];
            #pragma unroll
            for (int s = 0; s < 2; ++s) {
                int c = lane + 64*s;
                bool v = c < cnt;
                cd[s]  = v ? bufd[brow][c] : INFF;
                cix[s] = v ? bufi[brow][c] : 0x7fffffff;
            }
            for (int r = 0; r < 16; ++r) {
                float lv = cd[0]; int li = cix[0];
                if (cd[1] < lv || (cd[1] == lv && cix[1] < li)) { lv = cd[1]; li = cix[1]; }
                float wv = lv; int wi = li;
                #pragma unroll
                for (int s = 1; s < 64; s <<= 1) {
                    float ov = __shfl_xor(wv, s); int oi = __shfl_xor(wi, s);
                    if (ov < wv || (ov == wv && oi < wi)) { wv = ov; wi = oi; }
                }
                if (lane == 0) {
                    int safe = ((unsigned)wi < (unsigned)n) ? wi : ((row + 1) & (n - 1));
                    out_idx[row*16 + r] = safe;
                }
                #pragma unroll
                for (int s = 0; s < 2; ++s) {
                    if (cd[s] == wv && cix[s] == wi) { cd[s] = INFF; cix[s] = 0x7fffffff; }
                }
            }
        }
    }
}

// ---------------- refiner EdgeConv (H1=384, H2=3), wave per point ------------------
__global__ __launch_bounds__(256) void edge_ref_kernel(const float* __restrict__ ur,
                                                       const float* __restrict__ vr,
                                                       const float* __restrict__ w2,
                                                       const float* __restrict__ b2,
                                                       const int* __restrict__ idx,
                                                       const float* __restrict__ xyz_in,
                                                       float* __restrict__ out, int n) {
    int wave = threadIdx.x >> 6, lane = threadIdx.x & 63;
    int i = blockIdx.x*4 + wave;
    if (i >= n) return;
    float m0 = -INFF, m1 = -INFF, m2 = -INFF;
    float uh[6];
    #pragma unroll
    for (int t = 0; t < 6; ++t) uh[t] = ur[(size_t)i*384 + lane + 64*t];
    for (int e = 0; e < KRR; ++e) {
        int j = idx[i*KRR + e];
        j = ((unsigned)j < (unsigned)n) ? j : i;
        float a0 = 0.f, a1 = 0.f, a2 = 0.f;
        #pragma unroll
        for (int t = 0; t < 6; ++t) {
            int h = lane + 64*t;
            float tv = frelu(uh[t] + vr[(size_t)j*384 + h]);
            a0 += tv*w2[h*3+0]; a1 += tv*w2[h*3+1]; a2 += tv*w2[h*3+2];
        }
        #pragma unroll
        for (int s = 32; s > 0; s >>= 1) {
            a0 += __shfl_xor(a0, s); a1 += __shfl_xor(a1, s); a2 += __shfl_xor(a2, s);
        }
        m0 = fmaxf(m0, a0 + b2[0]); m1 = fmaxf(m1, a1 + b2[1]); m2 = fmaxf(m2, a2 + b2[2]);
    }
    if (lane == 0) {
        out[i*3+0] = xyz_in[i*3+0] + m0;
        out[i*3+1] = xyz_in[i*3+1] + m1;
        out[i*3+2] = xyz_in[i*3+2] + m2;
    }
}

// ---------------- folding MLP, fused upsample+noise in, xyz1 + packed pts out ------
__global__ __launch_bounds__(256) void fold_kernel(const float* __restrict__ pred_xyz,
                                                   const float* __restrict__ noise,
                                                   const float* __restrict__ featd,
                                                   const float* __restrict__ w1, const float* __restrict__ b1,
                                                   const float* __restrict__ w2, const float* __restrict__ b2,
                                                   const float* __restrict__ w3, const float* __restrict__ b3,
                                                   float* __restrict__ xyz1, float4* __restrict__ pts_out) {
    const int PTS = 16;
    int base = blockIdx.x * PTS;
    int tid = threadIdx.x;
    __shared__ __align__(16) float xin[PTS][100];
    __shared__ __align__(16) float h1[PTS][FOLDH];
    __shared__ __align__(16) float h2s[PTS][FOLDH];
    __shared__ float oxyz[PTS][3];
    for (int t = tid; t < PTS*100; t += 256) {
        int pt = t/100, k = t - pt*100;
        int gi = base + pt;
        float vv = 0.f;
        if (k < 3) {
            int b = gi >> 11, p = (gi & 2047) >> 2;
            vv = pred_xyz[(size_t)(b*PDIM + p)*3 + k] + 0.02f*noise[(size_t)gi*3 + k];
        } else if (k < 99) {
            int b = gi >> 11, p = (gi & 2047) >> 2;
            vv = featd[(size_t)(b*PDIM + p)*H2C + (k - 3)];
        }
        xin[pt][k] = vv;
    }
    __syncthreads();
    int c = tid;
    float acc[PTS];
    #pragma unroll
    for (int pt = 0; pt < PTS; ++pt) acc[pt] = b1[c];
    for (int k0 = 0; k0 < 96; k0 += 4) {
        float wa = w1[(k0+0)*FOLDH + c], wb = w1[(k0+1)*FOLDH + c];
        float wc = w1[(k0+2)*FOLDH + c], wd = w1[(k0+3)*FOLDH + c];
        #pragma unroll
        for (int pt = 0; pt < PTS; ++pt) {
            float4 xv = *(const float4*)&xin[pt][k0];
            acc[pt] += xv.x*wa + xv.y*wb + xv.z*wc + xv.w*wd;
        }
    }
    {
        float wa = w1[96*FOLDH + c], wb = w1[97*FOLDH + c], wc = w1[98*FOLDH + c];
        #pragma unroll
        for (int pt = 0; pt < PTS; ++pt) {
            float4 xv = *(const float4*)&xin[pt][96];
            acc[pt] += xv.x*wa + xv.y*wb + xv.z*wc;
        }
    }
    #pragma unroll
    for (int pt = 0; pt < PTS; ++pt) h1[pt][c] = frelu(acc[pt]);
    __syncthreads();
    #pragma unroll
    for (int pt = 0; pt < PTS; ++pt) acc[pt] = b2[c];
    for (int k0 = 0; k0 < FOLDH; k0 += 4) {
        float wa = w2[(k0+0)*FOLDH + c], wb = w2[(k0+1)*FOLDH + c];
        float wc = w2[(k0+2)*FOLDH + c], wd = w2[(k0+3)*FOLDH + c];
        #pragma unroll
        for (int pt = 0; pt < PTS; ++pt) {
            float4 hv = *(const float4*)&h1[pt][k0];
            acc[pt] += hv.x*wa + hv.y*wb + hv.z*wc + hv.w*wd;
        }
    }
    #pragma unroll
    for (int pt = 0; pt < PTS; ++pt) h2s[pt][c] = frelu(acc[pt]);
    __syncthreads();
    if (tid < PTS*3) {
        int pt = tid/3, cc = tid - pt*3;
        float a = b3[cc];
        for (int k0 = 0; k0 < FOLDH; k0 += 4) {
            float4 hv = *(const float4*)&h2s[pt][k0];
            a += hv.x*w3[(k0+0)*3+cc] + hv.y*w3[(k0+1)*3+cc] + hv.z*w3[(k0+2)*3+cc] + hv.w*w3[(k0+3)*3+cc];
        }
        int gi = base + pt;
        float res = xin[pt][cc] + a;
        xyz1[(size_t)gi*3 + cc] = res;
        oxyz[pt][cc] = res;
    }
    __syncthreads();
    if (tid < PTS) {
        float x = oxyz[tid][0], y = oxyz[tid][1], z = oxyz[tid][2];
        pts_out[base + tid] = make_float4(x, y, z, x*x + y*y + z*z);
    }
}

extern "C" void kernel_launch(void* const* d_in, const int* in_sizes, int n_in,
                              void* d_out, int out_size, void* d_ws, size_t ws_size,
                              hipStream_t stream) {
    const float* ctx_xyz    = (const float*)d_in[0];
    const float* ctx_tokens = (const float*)d_in[1];
    const float* pred_xyz   = (const float*)d_in[2];
    const float* noise      = (const float*)d_in[4];
    const float* c1w1 = (const float*)d_in[5];
    const float* c1b1 = (const float*)d_in[6];
    const float* c1w2 = (const float*)d_in[7];
    const float* c1b2 = (const float*)d_in[8];
    const float* c2w1 = (const float*)d_in[9];
    const float* c2b1 = (const float*)d_in[10];
    const float* c2w2 = (const float*)d_in[11];
    const float* c2b2 = (const float*)d_in[12];
    const float* cdw1 = (const float*)d_in[13];
    const float* cdb1 = (const float*)d_in[14];
    const float* cdw2 = (const float*)d_in[15];
    const float* cdb2 = (const float*)d_in[16];
    const float* fw1  = (const float*)d_in[17];
    const float* fb1  = (const float*)d_in[18];
    const float* fw2  = (const float*)d_in[19];
    const float* fb2  = (const float*)d_in[20];
    const float* fw3  = (const float*)d_in[21];
    const float* fb3  = (const float*)d_in[22];
    const float* rw1  = (const float*)d_in[23];
    const float* rb1  = (const float*)d_in[24];
    const float* rw2  = (const float*)d_in[25];
    const float* rb2  = (const float*)d_in[26];

    float* W = (float*)d_ws;
    // Zone A (staged aliasing): dist/distB (S1/S3) -> cfeat (S4) -> ur/vr (S8)
    float* dist  = W;                   // 2048*2048
    float* distB = W + 4194304;
    float* cfeat = W;                   // 2048*96 (after dist dead)
    float* ur    = W;                   // 8192*384 (after cfeat dead)
    float* vr    = W + 3145728;
    // Persistent zone:
    float* h_ctx = W + 8388608;         // 393,216
    float* h_tgt = h_ctx + 393216;
    float* UV    = h_tgt + 393216;      // [u1|v1] then [u2c|v2c|u2t|v2t]
    float* u1  = UV;            float* v1  = UV + 393216;
    float* u2c = UV;            float* v2c = UV + 196608;
    float* u2t = UV + 393216;   float* v2t = UV + 589824;
    float* tfeat = UV + 786432;         // 196,608
    float* xyz1  = tfeat + 196608;      // 24,576
    float4* pts  = (float4*)(xyz1 + 24576);
    float* sqb     = (float*)pts + 32768;
    float* sq_hctx = sqb + N2;
    float* sq_htgt = sq_hctx + N2;
    int* cidx1 = (int*)(sq_htgt + N2);
    int* cidx2 = cidx1 + N2*16;
    int* tidx2 = cidx2 + N2*8;
    int* ridx  = tidx2 + N2*2;

    float* out_ctx = (float*)d_out;
    float* out_tgt = out_ctx + N2*3;

    dim3 b16(16, 16);
    const int NTRI = 32*33/2;
    const float* NUL = nullptr;

    // --- S1: rowsq, dist(tokens), knn16 (tgt conv1 uses first 4 of cidx1)
    rowsq_kernel<<<N2/4, 256, 0, stream>>>(ctx_tokens, sqb, CDIM);
    dist64tri_kernel<<<NTRI, b16, 0, stream>>>(ctx_tokens, sqb, dist, N2, CDIM);
    knn_dist_rt_kernel<<<N2/4, 256, 0, stream>>>(dist, dist, N2, cidx1, cidx1, 16, 16, N2/4);

    // --- S2: u1/v1 GEMMs; conv1 fused gather-GEMM+reg-max (coalesced fill); row-sq
    gemmquad_kernel<<<dim3(3, 32, 2), b16, 0, stream>>>(
        ctx_tokens, c1w1, c1w1 + 384*192, c1b1, u1,
        ctx_tokens, c1w1 + 384*192, NUL, NUL, v1,
        ctx_tokens, c1w1, NUL, NUL, u1,   // unused (z<2)
        ctx_tokens, c1w1, NUL, NUL, v1,
        H1C, CDIM);
    edge_fused1_kernel<<<dim3(3, 512, 2), b16, 0, stream>>>(u1, v1, cidx1, c1w2, c1b2,
                                                            h_ctx, h_tgt, N2);
    rowsqpair_kernel<<<dim3(N2/4, 2), 256, 0, stream>>>(h_ctx, sq_hctx, h_tgt, sq_htgt, H1C);

    // --- S3: dist(h_ctx)+dist(h_tgt), paired knn, u2/v2 quad
    distpairtri_kernel<<<dim3(NTRI, 1, 2), b16, 0, stream>>>(h_ctx, sq_hctx, dist,
                                                             h_tgt, sq_htgt, distB, N2, H1C);
    knn_dist_rt_kernel<<<2*(N2/4), 256, 0, stream>>>(dist, distB, N2, cidx2, tidx2, 8, 2, N2/4);
    gemmquad_kernel<<<dim3(2, 32, 4), b16, 0, stream>>>(
        h_ctx, c2w1, c2w1 + 192*96, c2b1, u2c,
        h_ctx, c2w1 + 192*96, NUL, NUL, v2c,
        h_tgt, c2w1, c2w1 + 192*96, c2b1, u2t,
        h_tgt, c2w1 + 192*96, NUL, NUL, v2t,
        H2C, H1C);

    // --- S4: conv2 fused gather-GEMM+reg-max; cdef head
    edge_fused2_kernel<<<dim3(2, 256, 2), b16, 0, stream>>>(u2c, v2c, u2t, v2t, cidx2, tidx2,
                                                            c2w2, c2b2, cfeat, tfeat, N2);
    cdef_kernel<<<N2, 128, 0, stream>>>(cfeat, cdw1, cdb1, cdw2, cdb2, ctx_xyz, out_ctx);

    // --- S6: folding MLP (fused upsample+noise; emits xyz1 + packed pts)
    fold_kernel<<<N8/16, 256, 0, stream>>>(pred_xyz, noise, tfeat, fw1, fb1, fw2, fb2, fw3, fb3, xyz1, pts);

    // --- S7: refiner knn (4 rows/wave, compact bufs)
    knn_xyz16_kernel<<<N8/16, 256, 0, stream>>>(pts, N8, ridx);

    // --- S8: refiner u/v gather-GEMMs, residual EdgeConv to output
    gatherpair_kernel<<<dim3(6, N8/64, 2), b16, 0, stream>>>(
        tfeat, xyz1,
        rw1, rw1 + 99*384, rb1, ur,
        rw1 + 99*384, NUL, NUL, vr,
        384, 99);
    edge_ref_kernel<<<N8/4, 256, 0, stream>>>(ur, vr, rw2, rb2, ridx, xyz1, out_tgt, N8);
}

// Round 14
// 439.046 us; speedup vs baseline: 1.0866x; 1.0195x over previous
//
#include <hip/hip_runtime.h>

#define N2 2048      // B*P
#define N8 8192      // B*P*UP
#define CDIM 384
#define H1C 192      // C/2
#define H2C 96       // C/4
#define PDIM 512
#define KRR 16
#define FOLDH 256
#define XCAP 256
#define XCAPX 128
#define XTILE 1024
#define INFF 3.0e38f

__device__ __forceinline__ float frelu(float x) { return x > 0.f ? x : 0.f; }

// ---------------- 64-lane bitonic sorts (ascending) --------------------------------
__device__ __forceinline__ void bitonic64_val(float& d, int lane) {
    #pragma unroll
    for (int k = 2; k <= 64; k <<= 1) {
        #pragma unroll
        for (int j = k >> 1; j > 0; j >>= 1) {
            float od = __shfl_xor(d, j);
            bool lower = (lane & j) == 0;
            bool olt = od < d;
            bool take = lower ? olt : !olt;
            if (lane & k) take = !take;
            if (take) d = od;
        }
    }
}

__device__ __forceinline__ void bitonic64_pair(float& d, int& c, int lane) {
    #pragma unroll
    for (int k = 2; k <= 64; k <<= 1) {
        #pragma unroll
        for (int j = k >> 1; j > 0; j >>= 1) {
            float od = __shfl_xor(d, j);
            int   oc = __shfl_xor(c, j);
            bool lower = (lane & j) == 0;
            bool olt = (od < d) || (od == d && oc < c);
            bool take = lower ? olt : !olt;
            if (lane & k) take = !take;
            if (take) { d = od; c = oc; }
        }
    }
}

// ---------------- slow exact select fallback (cnt > 64, rare) ----------------------
__device__ __forceinline__ void select_slow(const float* bd, const int* bi, int cnt,
                                            int ksel, int row, int n, int* out, int lane) {
    float cd[4]; int cix[4];
    #pragma unroll
    for (int s = 0; s < 4; ++s) {
        int c = lane + 64*s;
        bool v = c < cnt;
        cd[s]  = v ? bd[c] : INFF;
        cix[s] = v ? bi[c] : 0x7fffffff;
    }
    for (int r = 0; r < ksel; ++r) {
        float lv = cd[0]; int li = cix[0];
        #pragma unroll
        for (int s = 1; s < 4; ++s) {
            if (cd[s] < lv || (cd[s] == lv && cix[s] < li)) { lv = cd[s]; li = cix[s]; }
        }
        float wv = lv; int wi = li;
        #pragma unroll
        for (int s = 1; s < 64; s <<= 1) {
            float ov = __shfl_xor(wv, s); int oi = __shfl_xor(wi, s);
            if (ov < wv || (ov == wv && oi < wi)) { wv = ov; wi = oi; }
        }
        if (lane == 0) {
            int safe = ((unsigned)wi < (unsigned)n) ? wi : ((row + 1) & (n - 1));
            out[row*ksel + r] = safe;
        }
        #pragma unroll
        for (int s = 0; s < 4; ++s) {
            if (cd[s] == wv && cix[s] == wi) { cd[s] = INFF; cix[s] = 0x7fffffff; }
        }
    }
}

// ---------------- row squared norms (wave per row; single + paired) ----------------
__global__ __launch_bounds__(256) void rowsq_kernel(const float* __restrict__ x,
                                                    float* __restrict__ sq, int d) {
    int wave = threadIdx.x >> 6, lane = threadIdx.x & 63;
    int row = blockIdx.x*4 + wave;
    float acc = 0.f;
    for (int k = lane; k < d; k += 64) { float v = x[(size_t)row*d + k]; acc += v*v; }
    #pragma unroll
    for (int s = 1; s < 64; s <<= 1) acc += __shfl_xor(acc, s);
    if (lane == 0) sq[row] = acc;
}

__global__ __launch_bounds__(256) void rowsqpair_kernel(const float* __restrict__ xA,
                                                        float* __restrict__ sqA,
                                                        const float* __restrict__ xB,
                                                        float* __restrict__ sqB, int d) {
    const float* x = blockIdx.y ? xB : xA;
    float* sq = blockIdx.y ? sqB : sqA;
    int wave = threadIdx.x >> 6, lane = threadIdx.x & 63;
    int row = blockIdx.x*4 + wave;
    float acc = 0.f;
    for (int k = lane; k < d; k += 64) { float v = x[(size_t)row*d + k]; acc += v*v; }
    #pragma unroll
    for (int s = 1; s < 64; s <<= 1) acc += __shfl_xor(acc, s);
    if (lane == 0) sq[row] = acc;
}

// ---------------- triangular symmetric dist: direct + mirrored tile ----------------
__device__ __forceinline__ void disttri_body(const float* __restrict__ x, const float* __restrict__ sq,
                                             float* __restrict__ dist, int n, int K) {
    int l = blockIdx.x;
    int by = (int)((sqrtf(8.f*(float)l + 1.f) - 1.f)*0.5f);
    while ((by+1)*(by+2)/2 <= l) ++by;
    while (by*(by+1)/2 > l) --by;
    int bx = l - by*(by+1)/2;
    int row0 = by*64, col0 = bx*64;
    __shared__ __align__(16) float As[16][68];
    __shared__ __align__(16) float Bs[16][68];
    __shared__ __align__(16) float T[64][68];
    int tx = threadIdx.x, ty = threadIdx.y;
    int t = ty*16 + tx;
    float acc[4][4] = {};
    for (int k0 = 0; k0 < K; k0 += 16) {
        #pragma unroll
        for (int r = 0; r < 4; ++r) {
            int e = t + 256*r; int kk = e & 15, mm = e >> 4;
            As[kk][mm] = x[(size_t)(row0+mm)*K + k0+kk];
            Bs[kk][mm] = x[(size_t)(col0+mm)*K + k0+kk];
        }
        __syncthreads();
        #pragma unroll
        for (int kk = 0; kk < 16; ++kk) {
            float4 a4 = *(const float4*)&As[kk][ty*4];
            float4 b4 = *(const float4*)&Bs[kk][tx*4];
            acc[0][0] += a4.x*b4.x; acc[0][1] += a4.x*b4.y; acc[0][2] += a4.x*b4.z; acc[0][3] += a4.x*b4.w;
            acc[1][0] += a4.y*b4.x; acc[1][1] += a4.y*b4.y; acc[1][2] += a4.y*b4.z; acc[1][3] += a4.y*b4.w;
            acc[2][0] += a4.z*b4.x; acc[2][1] += a4.z*b4.y; acc[2][2] += a4.z*b4.z; acc[2][3] += a4.z*b4.w;
            acc[3][0] += a4.w*b4.x; acc[3][1] += a4.w*b4.y; acc[3][2] += a4.w*b4.z; acc[3][3] += a4.w*b4.w;
        }
        __syncthreads();
    }
    bool mirror = (row0 != col0);
    #pragma unroll
    for (int i2 = 0; i2 < 4; ++i2) {
        int row = row0 + ty*4 + i2;
        float sr = sq[row];
        float4 o;
        o.x = sr + sq[col0+tx*4+0] - 2.f*acc[i2][0];
        o.y = sr + sq[col0+tx*4+1] - 2.f*acc[i2][1];
        o.z = sr + sq[col0+tx*4+2] - 2.f*acc[i2][2];
        o.w = sr + sq[col0+tx*4+3] - 2.f*acc[i2][3];
        *(float4*)&dist[(size_t)row*n + col0 + tx*4] = o;
        if (mirror) {
            T[tx*4+0][ty*4+i2] = o.x;
            T[tx*4+1][ty*4+i2] = o.y;
            T[tx*4+2][ty*4+i2] = o.z;
            T[tx*4+3][ty*4+i2] = o.w;
        }
    }
    if (mirror) {
        __syncthreads();
        #pragma unroll
        for (int i2 = 0; i2 < 4; ++i2) {
            int orow = col0 + ty*4 + i2;
            float4 o = *(const float4*)&T[ty*4+i2][tx*4];
            *(float4*)&dist[(size_t)orow*n + row0 + tx*4] = o;
        }
    }
}

__global__ __launch_bounds__(256) void dist64tri_kernel(const float* __restrict__ x,
                                                        const float* __restrict__ sq,
                                                        float* __restrict__ dist, int n, int K) {
    disttri_body(x, sq, dist, n, K);
}

__global__ __launch_bounds__(256) void distpairtri_kernel(const float* __restrict__ xA,
                                                          const float* __restrict__ sqA,
                                                          float* __restrict__ dA,
                                                          const float* __restrict__ xB,
                                                          const float* __restrict__ sqB,
                                                          float* __restrict__ dB, int n, int K) {
    const float* x  = blockIdx.z ? xB : xA;
    const float* sq = blockIdx.z ? sqB : sqA;
    float* dist     = blockIdx.z ? dB : dA;
    disttri_body(x, sq, dist, n, K);
}

// ---------------- shared 64x64 GEMM tile body: C = A @ (Bw - BwB) + bias -----------
__device__ __forceinline__ void gemm_body(const float* __restrict__ A, const float* __restrict__ Bw,
                                          const float* __restrict__ BwB, const float* __restrict__ bias,
                                          float* __restrict__ C, int m, int K) {
    __shared__ __align__(16) float As[16][68];
    __shared__ __align__(16) float Bs[16][68];
    int tx = threadIdx.x, ty = threadIdx.y;
    int t = ty*16 + tx;
    int row0 = blockIdx.y*64, col0 = blockIdx.x*64;
    float acc[4][4] = {};
    for (int k0 = 0; k0 < K; k0 += 16) {
        #pragma unroll
        for (int r = 0; r < 4; ++r) {
            int e = t + 256*r; int kk = e & 15, mm = e >> 4;
            As[kk][mm] = (k0 + kk < K) ? A[(size_t)(row0+mm)*K + k0+kk] : 0.f;
        }
        #pragma unroll
        for (int r = 0; r < 4; ++r) {
            int e = t + 256*r; int nn = e & 63, kk = e >> 6;
            int col = col0 + nn, k = k0 + kk;
            float bv = 0.f;
            if (k < K && col < m) {
                bv = Bw[(size_t)k*m + col];
                if (BwB) bv -= BwB[(size_t)k*m + col];
            }
            Bs[kk][nn] = bv;
        }
        __syncthreads();
        #pragma unroll
        for (int kk = 0; kk < 16; ++kk) {
            float4 a4 = *(const float4*)&As[kk][ty*4];
            float4 b4 = *(const float4*)&Bs[kk][tx*4];
            acc[0][0] += a4.x*b4.x; acc[0][1] += a4.x*b4.y; acc[0][2] += a4.x*b4.z; acc[0][3] += a4.x*b4.w;
            acc[1][0] += a4.y*b4.x; acc[1][1] += a4.y*b4.y; acc[1][2] += a4.y*b4.z; acc[1][3] += a4.y*b4.w;
            acc[2][0] += a4.z*b4.x; acc[2][1] += a4.z*b4.y; acc[2][2] += a4.z*b4.z; acc[2][3] += a4.z*b4.w;
            acc[3][0] += a4.w*b4.x; acc[3][1] += a4.w*b4.y; acc[3][2] += a4.w*b4.z; acc[3][3] += a4.w*b4.w;
        }
        __syncthreads();
    }
    #pragma unroll
    for (int i2 = 0; i2 < 4; ++i2) {
        int row = row0 + ty*4 + i2;
        #pragma unroll
        for (int j2 = 0; j2 < 4; ++j2) {
            int col = col0 + tx*4 + j2;
            if (col < m) C[(size_t)row*m + col] = acc[i2][j2] + (bias ? bias[col] : 0.f);
        }
    }
}

__global__ __launch_bounds__(256) void gemmquad_kernel(
    const float* A0, const float* Bw0, const float* BwB0, const float* bias0, float* C0,
    const float* A1, const float* Bw1, const float* BwB1, const float* bias1, float* C1,
    const float* A2, const float* Bw2, const float* BwB2, const float* bias2, float* C2,
    const float* A3, const float* Bw3, const float* BwB3, const float* bias3, float* C3,
    int m, int K) {
    int z = blockIdx.z;
    const float* A    = (z==0)?A0 :(z==1)?A1 :(z==2)?A2 :A3;
    const float* Bw   = (z==0)?Bw0:(z==1)?Bw1:(z==2)?Bw2:Bw3;
    const float* BwB  = (z==0)?BwB0:(z==1)?BwB1:(z==2)?BwB2:BwB3;
    const float* bias = (z==0)?bias0:(z==1)?bias1:(z==2)?bias2:bias3;
    float* C          = (z==0)?C0 :(z==1)?C1 :(z==2)?C2 :C3;
    gemm_body(A, Bw, BwB, bias, C, m, K);
}

// ---------------- EdgeConv layer-2 gather-GEMM, reg-max, coalesced fill ------------
template<int EPT, int SELF, int EREAL, int IDXS, int YT>
__device__ __forceinline__ void edge_fused_body(const float* __restrict__ u, const float* __restrict__ v,
                                                const int* __restrict__ idx,
                                                const float* __restrict__ Bw, const float* __restrict__ bias,
                                                float* __restrict__ hout, int m, int K, int npts) {
    if ((int)blockIdx.y >= YT) return;
    constexpr int LOG2EPT = (EPT == 16) ? 4 : (EPT == 8) ? 3 : 2;
    __shared__ __align__(16) float As[16][68];
    __shared__ __align__(16) float Bs[16][68];
    int tx = threadIdx.x, ty = threadIdx.y;
    int t = ty*16 + tx;
    int row0 = blockIdx.y*64, col0 = blockIdx.x*64;
    int mmA = t >> 2;
    int kqA = (t & 3) * 4;
    int rowA = row0 + mmA;
    int iA = rowA >> LOG2EPT;
    int eA = rowA - (iA << LOG2EPT);
    int jA;
    if (SELF && eA == 0) jA = iA;
    else if (eA < EREAL) jA = idx[iA*IDXS + (eA - SELF)];
    else jA = iA;
    jA = ((unsigned)jA < (unsigned)npts) ? jA : iA;
    const float* uRow = u + (size_t)iA*K + kqA;
    const float* vRow = v + (size_t)jA*K + kqA;
    int nnB = (t & 15) * 4, kkB = t >> 4;
    float acc[4][4] = {};
    for (int k0 = 0; k0 < K; k0 += 16) {
        float4 u4 = *(const float4*)(uRow + k0);
        float4 v4 = *(const float4*)(vRow + k0);
        As[kqA+0][mmA] = frelu(u4.x + v4.x);
        As[kqA+1][mmA] = frelu(u4.y + v4.y);
        As[kqA+2][mmA] = frelu(u4.z + v4.z);
        As[kqA+3][mmA] = frelu(u4.w + v4.w);
        int colB = col0 + nnB;
        if (colB + 3 < m) {
            *(float4*)&Bs[kkB][nnB] = *(const float4*)&Bw[(size_t)(k0+kkB)*m + colB];
        } else {
            #pragma unroll
            for (int q = 0; q < 4; ++q) {
                int col = colB + q;
                Bs[kkB][nnB+q] = (col < m) ? Bw[(size_t)(k0+kkB)*m + col] : 0.f;
            }
        }
        __syncthreads();
        #pragma unroll
        for (int kk = 0; kk < 16; ++kk) {
            float4 a4 = *(const float4*)&As[kk][ty*4];
            float4 b4 = *(const float4*)&Bs[kk][tx*4];
            acc[0][0] += a4.x*b4.x; acc[0][1] += a4.x*b4.y; acc[0][2] += a4.x*b4.z; acc[0][3] += a4.x*b4.w;
            acc[1][0] += a4.y*b4.x; acc[1][1] += a4.y*b4.y; acc[1][2] += a4.y*b4.z; acc[1][3] += a4.y*b4.w;
            acc[2][0] += a4.z*b4.x; acc[2][1] += a4.z*b4.y; acc[2][2] += a4.z*b4.z; acc[2][3] += a4.z*b4.w;
            acc[3][0] += a4.w*b4.x; acc[3][1] += a4.w*b4.y; acc[3][2] += a4.w*b4.z; acc[3][3] += a4.w*b4.w;
        }
        __syncthreads();
    }
    float bestv[4];
    #pragma unroll
    for (int j2 = 0; j2 < 4; ++j2)
        bestv[j2] = fmaxf(fmaxf(acc[0][j2], acc[1][j2]), fmaxf(acc[2][j2], acc[3][j2]));
    if (EPT >= 8) {
        #pragma unroll
        for (int j2 = 0; j2 < 4; ++j2) bestv[j2] = fmaxf(bestv[j2], __shfl_xor(bestv[j2], 16));
    }
    if (EPT == 16) {
        #pragma unroll
        for (int j2 = 0; j2 < 4; ++j2) bestv[j2] = fmaxf(bestv[j2], __shfl_xor(bestv[j2], 32));
    }
    bool writer; int p;
    if (EPT == 16) { writer = (ty & 3) == 0; p = (row0 >> 4) + (ty >> 2); }
    else if (EPT == 8) { writer = (ty & 1) == 0; p = (row0 >> 3) + (ty >> 1); }
    else { writer = true; p = (row0 >> 2) + ty; }
    if (writer) {
        #pragma unroll
        for (int j2 = 0; j2 < 4; ++j2) {
            int col = col0 + tx*4 + j2;
            if (col < m) hout[(size_t)p*m + col] = bestv[j2] + bias[col];
        }
    }
}

__global__ __launch_bounds__(256) void edge_fused1_kernel(const float* u1, const float* v1,
                                                          const int* cidx1,
                                                          const float* Bw, const float* bias,
                                                          float* h_ctx, float* h_tgt, int npts) {
    if (blockIdx.z == 0) edge_fused_body<16,0,16,16,512>(u1, v1, cidx1, Bw, bias, h_ctx, H1C, H1C, npts);
    else                 edge_fused_body<8,1,5,16,256>(u1, v1, cidx1, Bw, bias, h_tgt, H1C, H1C, npts);
}

__global__ __launch_bounds__(256) void edge_fused2_kernel(const float* u2c, const float* v2c,
                                                          const float* u2t, const float* v2t,
                                                          const int* cidx2, const int* tidx2,
                                                          const float* Bw, const float* bias,
                                                          float* cfeat, float* tfeat, int npts) {
    if (blockIdx.z == 0) edge_fused_body<8,0,8,8,256>(u2c, v2c, cidx2, Bw, bias, cfeat, H2C, H2C, npts);
    else                 edge_fused_body<4,1,3,2,128>(u2t, v2t, tidx2, Bw, bias, tfeat, H2C, H2C, npts);
}

// ---------------- ctx deform head: out = xyz + 0.05 * mlp2(cfeat) ------------------
__global__ __launch_bounds__(128) void cdef_kernel(const float* __restrict__ cfeat,
                                                   const float* __restrict__ cdw1, const float* __restrict__ cdb1,
                                                   const float* __restrict__ cdw2, const float* __restrict__ cdb2,
                                                   const float* __restrict__ ctx_xyz,
                                                   float* __restrict__ out_ctx) {
    int i = blockIdx.x, tid = threadIdx.x, wave = tid >> 6, lane = tid & 63;
    __shared__ float sf_[96], st2_[96];
    if (tid < 96) sf_[tid] = cfeat[(size_t)i*H2C + tid];
    __syncthreads();
    if (tid < 96) {
        float a = cdb1[tid];
        for (int k = 0; k < 96; ++k) a += sf_[k]*cdw1[k*96 + tid];
        st2_[tid] = frelu(a);
    }
    __syncthreads();
    if (wave == 0) {
        float s0 = st2_[lane];
        float p0 = s0*cdw2[lane*3+0], p1 = s0*cdw2[lane*3+1], p2 = s0*cdw2[lane*3+2];
        if (lane < 32) {
            float s1 = st2_[lane+64];
            p0 += s1*cdw2[(lane+64)*3+0];
            p1 += s1*cdw2[(lane+64)*3+1];
            p2 += s1*cdw2[(lane+64)*3+2];
        }
        #pragma unroll
        for (int s = 1; s < 64; s <<= 1) {
            p0 += __shfl_xor(p0, s); p1 += __shfl_xor(p1, s); p2 += __shfl_xor(p2, s);
        }
        if (lane == 0) {
            out_ctx[i*3+0] = ctx_xyz[i*3+0] + 0.05f*(cdb2[0] + p0);
            out_ctx[i*3+1] = ctx_xyz[i*3+1] + 0.05f*(cdb2[1] + p1);
            out_ctx[i*3+2] = ctx_xyz[i*3+2] + 0.05f*(cdb2[2] + p2);
        }
    }
}

// refiner gather-GEMM pair: A row gathered from [featd(96) | xyzg(3)], K = 99
__global__ __launch_bounds__(256) void gatherpair_kernel(
    const float* __restrict__ featd, const float* __restrict__ xyzg,
    const float* Bw0, const float* BwB0, const float* bias0, float* C0,
    const float* Bw1, const float* BwB1, const float* bias1, float* C1,
    int m, int K) {
    int z = blockIdx.z;
    const float* Bw   = z ? Bw1 : Bw0;
    const float* BwB  = z ? BwB1 : BwB0;
    const float* bias = z ? bias1 : bias0;
    float* C          = z ? C1 : C0;
    __shared__ __align__(16) float As[16][68];
    __shared__ __align__(16) float Bs[16][68];
    int tx = threadIdx.x, ty = threadIdx.y;
    int t = ty*16 + tx;
    int row0 = blockIdx.y*64, col0 = blockIdx.x*64;
    float acc[4][4] = {};
    for (int k0 = 0; k0 < K; k0 += 16) {
        #pragma unroll
        for (int r = 0; r < 4; ++r) {
            int e = t + 256*r; int kk = e & 15, mm = e >> 4;
            int k = k0 + kk, grow = row0 + mm;
            float av = 0.f;
            if (k < K) {
                if (k < 96) { int b = grow >> 11, p = (grow & 2047) >> 2;
                              av = featd[(size_t)(b*PDIM + p)*H2C + k]; }
                else av = xyzg[(size_t)grow*3 + (k - 96)];
            }
            As[kk][mm] = av;
        }
        #pragma unroll
        for (int r = 0; r < 4; ++r) {
            int e = t + 256*r; int nn = e & 63, kk = e >> 6;
            int col = col0 + nn, k = k0 + kk;
            float bv = 0.f;
            if (k < K && col < m) {
                bv = Bw[(size_t)k*m + col];
                if (BwB) bv -= BwB[(size_t)k*m + col];
            }
            Bs[kk][nn] = bv;
        }
        __syncthreads();
        #pragma unroll
        for (int kk = 0; kk < 16; ++kk) {
            float4 a4 = *(const float4*)&As[kk][ty*4];
            float4 b4 = *(const float4*)&Bs[kk][tx*4];
            acc[0][0] += a4.x*b4.x; acc[0][1] += a4.x*b4.y; acc[0][2] += a4.x*b4.z; acc[0][3] += a4.x*b4.w;
            acc[1][0] += a4.y*b4.x; acc[1][1] += a4.y*b4.y; acc[1][2] += a4.y*b4.z; acc[1][3] += a4.y*b4.w;
            acc[2][0] += a4.z*b4.x; acc[2][1] += a4.z*b4.y; acc[2][2] += a4.z*b4.z; acc[2][3] += a4.z*b4.w;
            acc[3][0] += a4.w*b4.x; acc[3][1] += a4.w*b4.y; acc[3][2] += a4.w*b4.z; acc[3][3] += a4.w*b4.w;
        }
        __syncthreads();
    }
    #pragma unroll
    for (int i2 = 0; i2 < 4; ++i2) {
        int row = row0 + ty*4 + i2;
        #pragma unroll
        for (int j2 = 0; j2 < 4; ++j2) {
            int col = col0 + tx*4 + j2;
            if (col < m) C[(size_t)row*m + col] = acc[i2][j2] + (bias ? bias[col] : 0.f);
        }
    }
}

// ---------------- knn from dist rows (4 rows/block, bitonic select) ----------------
__global__ __launch_bounds__(256) void knn_dist_rt_kernel(const float* __restrict__ dA,
                                                          const float* __restrict__ dB, int n,
                                                          int* __restrict__ outA, int* __restrict__ outB,
                                                          int kA, int kB, int nblkA) {
    int wave = threadIdx.x >> 6, lane = threadIdx.x & 63;
    bool useB = (int)blockIdx.x >= nblkA;
    const float* dist = useB ? dB : dA;
    int* out = useB ? outB : outA;
    int ksel = useB ? kB : kA;
    int bx = useB ? (int)blockIdx.x - nblkA : (int)blockIdx.x;
    int row = bx*4 + wave;
    __shared__ float bufd[4][XCAP];
    __shared__ int   bufi[4][XCAP];
    __shared__ int   lcnt[4];
    const float4* drow = (const float4*)(dist + (size_t)row*n);
    int nq = n >> 2;
    float mv = INFF;
    for (int i = lane; i < nq; i += 64) {
        float4 d4 = drow[i]; int base = i*4;
        float a = (base+0 == row) ? INFF : d4.x;
        float b = (base+1 == row) ? INFF : d4.y;
        float c = (base+2 == row) ? INFF : d4.z;
        float d = (base+3 == row) ? INFF : d4.w;
        mv = fminf(mv, fminf(fminf(a,b), fminf(c,d)));
    }
    float sd = mv;
    bitonic64_val(sd, lane);
    float Tv = __shfl(sd, ksel - 1);
    if (lane == 0) lcnt[wave] = 0;
    for (int i = lane; i < nq; i += 64) {
        float4 d4 = drow[i]; int base = i*4;
        float dv4[4] = {d4.x, d4.y, d4.z, d4.w};
        #pragma unroll
        for (int q = 0; q < 4; ++q) {
            int col = base + q;
            if (col != row && dv4[q] <= Tv) {
                int pos = atomicAdd(&lcnt[wave], 1);
                if (pos < XCAP) { bufd[wave][pos] = dv4[q]; bufi[wave][pos] = col; }
            }
        }
    }
    int cnt = lcnt[wave]; if (cnt > XCAP) cnt = XCAP;
    if (cnt <= 64) {
        float d = (lane < cnt) ? bufd[wave][lane] : INFF;
        int   c = (lane < cnt) ? bufi[wave][lane] : 0x7fffffff;
        bitonic64_pair(d, c, lane);
        if (lane < ksel) {
            int safe = ((unsigned)c < (unsigned)n) ? c : ((row + 1) & (n - 1));
            out[row*ksel + lane] = safe;
        }
    } else {
        select_slow(bufd[wave], bufi[wave], cnt, ksel, row, n, out, lane);
    }
}

// ---------------- knn over packed xyz: 16 rows/block, 512 thr, 2 rows/wave ---------
__global__ __launch_bounds__(512) void knn_xyz512_kernel(const float4* __restrict__ pts, int n,
                                                         int* __restrict__ out_idx) {
    int tid = threadIdx.x, wave = tid >> 6, lane = tid & 63;
    int rbase = blockIdx.x*16 + wave*2;
    __shared__ __align__(16) float4 tile[XTILE];
    __shared__ float bufd[16][XCAPX];
    __shared__ int   bufi[16][XCAPX];
    __shared__ int   lcnt[16];
    float4 P0 = pts[rbase], P1 = pts[rbase+1];
    float mv0 = INFF, mv1 = INFF;
    for (int t0 = 0; t0 < n; t0 += XTILE) {
        __syncthreads();
        #pragma unroll
        for (int k = 0; k < XTILE/512; ++k) tile[tid + 512*k] = pts[t0 + tid + 512*k];
        __syncthreads();
        for (int c = lane; c < XTILE; c += 64) {
            float4 q = tile[c];
            int col = t0 + c;
            float d0 = P0.w + q.w - 2.f*(P0.x*q.x + P0.y*q.y + P0.z*q.z);
            float d1 = P1.w + q.w - 2.f*(P1.x*q.x + P1.y*q.y + P1.z*q.z);
            d0 = (col == rbase)   ? INFF : d0;
            d1 = (col == rbase+1) ? INFF : d1;
            mv0 = fminf(mv0, d0);
            mv1 = fminf(mv1, d1);
        }
    }
    bitonic64_val(mv0, lane);
    bitonic64_val(mv1, lane);
    float Tv0 = __shfl(mv0, 15), Tv1 = __shfl(mv1, 15);
    if (lane < 2) lcnt[wave*2 + lane] = 0;
    for (int t0 = 0; t0 < n; t0 += XTILE) {
        __syncthreads();
        #pragma unroll
        for (int k = 0; k < XTILE/512; ++k) tile[tid + 512*k] = pts[t0 + tid + 512*k];
        __syncthreads();
        for (int c = lane; c < XTILE; c += 64) {
            float4 q = tile[c];
            int col = t0 + c;
            float d0 = P0.w + q.w - 2.f*(P0.x*q.x + P0.y*q.y + P0.z*q.z);
            float d1 = P1.w + q.w - 2.f*(P1.x*q.x + P1.y*q.y + P1.z*q.z);
            if (col != rbase && d0 <= Tv0) {
                int pos = atomicAdd(&lcnt[wave*2+0], 1);
                if (pos < XCAPX) { bufd[wave*2+0][pos] = d0; bufi[wave*2+0][pos] = col; }
            }
            if (col != rbase+1 && d1 <= Tv1) {
                int pos = atomicAdd(&lcnt[wave*2+1], 1);
                if (pos < XCAPX) { bufd[wave*2+1][pos] = d1; bufi[wave*2+1][pos] = col; }
            }
        }
    }
    for (int jj = 0; jj < 2; ++jj) {
        int brow = wave*2 + jj, row = rbase + jj;
        int cnt = lcnt[brow]; if (cnt > XCAPX) cnt = XCAPX;
        if (cnt <= 64) {
            float d = (lane < cnt) ? bufd[brow][lane] : INFF;
            int   c = (lane < cnt) ? bufi[brow][lane] : 0x7fffffff;
            bitonic64_pair(d, c, lane);
            if (lane < 16) {
                int safe = ((unsigned)c < (unsigned)n) ? c : ((row + 1) & (n - 1));
                out_idx[row*16 + lane] = safe;
            }
        } else {
            float cd[2]; int cix[2];
            #pragma unroll
            for (int s = 0; s < 2; ++s) {
                int c = lane + 64*s;
                bool v = c < cnt;
                cd[s]  = v ? bufd[brow][c] : INFF;
                cix[s] = v ? bufi[brow][c] : 0x7fffffff;
            }
            for (int r = 0; r < 16; ++r) {
                float lv = cd[0]; int li = cix[0];
                if (cd[1] < lv || (cd[1] == lv && cix[1] < li)) { lv = cd[1]; li = cix[1]; }
                float wv = lv; int wi = li;
                #pragma unroll
                for (int s = 1; s < 64; s <<= 1) {
                    float ov = __shfl_xor(wv, s); int oi = __shfl_xor(wi, s);
                    if (ov < wv || (ov == wv && oi < wi)) { wv = ov; wi = oi; }
                }
                if (lane == 0) {
                    int safe = ((unsigned)wi < (unsigned)n) ? wi : ((row + 1) & (n - 1));
                    out_idx[row*16 + r] = safe;
                }
                #pragma unroll
                for (int s = 0; s < 2; ++s) {
                    if (cd[s] == wv && cix[s] == wi) { cd[s] = INFF; cix[s] = 0x7fffffff; }
                }
            }
        }
    }
}

// ---------------- refiner EdgeConv (H1=384, H2=3), wave per point ------------------
__global__ __launch_bounds__(256) void edge_ref_kernel(const float* __restrict__ ur,
                                                       const float* __restrict__ vr,
                                                       const float* __restrict__ w2,
                                                       const float* __restrict__ b2,
                                                       const int* __restrict__ idx,
                                                       const float* __restrict__ xyz_in,
                                                       float* __restrict__ out, int n) {
    int wave = threadIdx.x >> 6, lane = threadIdx.x & 63;
    int i = blockIdx.x*4 + wave;
    if (i >= n) return;
    float m0 = -INFF, m1 = -INFF, m2 = -INFF;
    float uh[6];
    #pragma unroll
    for (int t = 0; t < 6; ++t) uh[t] = ur[(size_t)i*384 + lane + 64*t];
    for (int e = 0; e < KRR; ++e) {
        int j = idx[i*KRR + e];
        j = ((unsigned)j < (unsigned)n) ? j : i;
        float a0 = 0.f, a1 = 0.f, a2 = 0.f;
        #pragma unroll
        for (int t = 0; t < 6; ++t) {
            int h = lane + 64*t;
            float tv = frelu(uh[t] + vr[(size_t)j*384 + h]);
            a0 += tv*w2[h*3+0]; a1 += tv*w2[h*3+1]; a2 += tv*w2[h*3+2];
        }
        #pragma unroll
        for (int s = 32; s > 0; s >>= 1) {
            a0 += __shfl_xor(a0, s); a1 += __shfl_xor(a1, s); a2 += __shfl_xor(a2, s);
        }
        m0 = fmaxf(m0, a0 + b2[0]); m1 = fmaxf(m1, a1 + b2[1]); m2 = fmaxf(m2, a2 + b2[2]);
    }
    if (lane == 0) {
        out[i*3+0] = xyz_in[i*3+0] + m0;
        out[i*3+1] = xyz_in[i*3+1] + m1;
        out[i*3+2] = xyz_in[i*3+2] + m2;
    }
}

// ---------------- folding MLP, fused upsample+noise in, xyz1 + packed pts out ------
__global__ __launch_bounds__(256) void fold_kernel(const float* __restrict__ pred_xyz,
                                                   const float* __restrict__ noise,
                                                   const float* __restrict__ featd,
                                                   const float* __restrict__ w1, const float* __restrict__ b1,
                                                   const float* __restrict__ w2, const float* __restrict__ b2,
                                                   const float* __restrict__ w3, const float* __restrict__ b3,
                                                   float* __restrict__ xyz1, float4* __restrict__ pts_out) {
    const int PTS = 16;
    int base = blockIdx.x * PTS;
    int tid = threadIdx.x;
    __shared__ __align__(16) float xin[PTS][100];
    __shared__ __align__(16) float h1[PTS][FOLDH];
    __shared__ __align__(16) float h2s[PTS][FOLDH];
    __shared__ float oxyz[PTS][3];
    for (int t = tid; t < PTS*100; t += 256) {
        int pt = t/100, k = t - pt*100;
        int gi = base + pt;
        float vv = 0.f;
        if (k < 3) {
            int b = gi >> 11, p = (gi & 2047) >> 2;
            vv = pred_xyz[(size_t)(b*PDIM + p)*3 + k] + 0.02f*noise[(size_t)gi*3 + k];
        } else if (k < 99) {
            int b = gi >> 11, p = (gi & 2047) >> 2;
            vv = featd[(size_t)(b*PDIM + p)*H2C + (k - 3)];
        }
        xin[pt][k] = vv;
    }
    __syncthreads();
    int c = tid;
    float acc[PTS];
    #pragma unroll
    for (int pt = 0; pt < PTS; ++pt) acc[pt] = b1[c];
    for (int k0 = 0; k0 < 96; k0 += 4) {
        float wa = w1[(k0+0)*FOLDH + c], wb = w1[(k0+1)*FOLDH + c];
        float wc = w1[(k0+2)*FOLDH + c], wd = w1[(k0+3)*FOLDH + c];
        #pragma unroll
        for (int pt = 0; pt < PTS; ++pt) {
            float4 xv = *(const float4*)&xin[pt][k0];
            acc[pt] += xv.x*wa + xv.y*wb + xv.z*wc + xv.w*wd;
        }
    }
    {
        float wa = w1[96*FOLDH + c], wb = w1[97*FOLDH + c], wc = w1[98*FOLDH + c];
        #pragma unroll
        for (int pt = 0; pt < PTS; ++pt) {
            float4 xv = *(const float4*)&xin[pt][96];
            acc[pt] += xv.x*wa + xv.y*wb + xv.z*wc;
        }
    }
    #pragma unroll
    for (int pt = 0; pt < PTS; ++pt) h1[pt][c] = frelu(acc[pt]);
    __syncthreads();
    #pragma unroll
    for (int pt = 0; pt < PTS; ++pt) acc[pt] = b2[c];
    for (int k0 = 0; k0 < FOLDH; k0 += 4) {
        float wa = w2[(k0+0)*FOLDH + c], wb = w2[(k0+1)*FOLDH + c];
        float wc = w2[(k0+2)*FOLDH + c], wd = w2[(k0+3)*FOLDH + c];
        #pragma unroll
        for (int pt = 0; pt < PTS; ++pt) {
            float4 hv = *(const float4*)&h1[pt][k0];
            acc[pt] += hv.x*wa + hv.y*wb + hv.z*wc + hv.w*wd;
        }
    }
    #pragma unroll
    for (int pt = 0; pt < PTS; ++pt) h2s[pt][c] = frelu(acc[pt]);
    __syncthreads();
    if (tid < PTS*3) {
        int pt = tid/3, cc = tid - pt*3;
        float a = b3[cc];
        for (int k0 = 0; k0 < FOLDH; k0 += 4) {
            float4 hv = *(const float4*)&h2s[pt][k0];
            a += hv.x*w3[(k0+0)*3+cc] + hv.y*w3[(k0+1)*3+cc] + hv.z*w3[(k0+2)*3+cc] + hv.w*w3[(k0+3)*3+cc];
        }
        int gi = base + pt;
        float res = xin[pt][cc] + a;
        xyz1[(size_t)gi*3 + cc] = res;
        oxyz[pt][cc] = res;
    }
    __syncthreads();
    if (tid < PTS) {
        float x = oxyz[tid][0], y = oxyz[tid][1], z = oxyz[tid][2];
        pts_out[base + tid] = make_float4(x, y, z, x*x + y*y + z*z);
    }
}

extern "C" void kernel_launch(void* const* d_in, const int* in_sizes, int n_in,
                              void* d_out, int out_size, void* d_ws, size_t ws_size,
                              hipStream_t stream) {
    const float* ctx_xyz    = (const float*)d_in[0];
    const float* ctx_tokens = (const float*)d_in[1];
    const float* pred_xyz   = (const float*)d_in[2];
    const float* noise      = (const float*)d_in[4];
    const float* c1w1 = (const float*)d_in[5];
    const float* c1b1 = (const float*)d_in[6];
    const float* c1w2 = (const float*)d_in[7];
    const float* c1b2 = (const float*)d_in[8];
    const float* c2w1 = (const float*)d_in[9];
    const float* c2b1 = (const float*)d_in[10];
    const float* c2w2 = (const float*)d_in[11];
    const float* c2b2 = (const float*)d_in[12];
    const float* cdw1 = (const float*)d_in[13];
    const float* cdb1 = (const float*)d_in[14];
    const float* cdw2 = (const float*)d_in[15];
    const float* cdb2 = (const float*)d_in[16];
    const float* fw1  = (const float*)d_in[17];
    const float* fb1  = (const float*)d_in[18];
    const float* fw2  = (const float*)d_in[19];
    const float* fb2  = (const float*)d_in[20];
    const float* fw3  = (const float*)d_in[21];
    const float* fb3  = (const float*)d_in[22];
    const float* rw1  = (const float*)d_in[23];
    const float* rb1  = (const float*)d_in[24];
    const float* rw2  = (const float*)d_in[25];
    const float* rb2  = (const float*)d_in[26];

    float* W = (float*)d_ws;
    // Zone A (staged aliasing): dist/distB (S1/S3) -> cfeat (S4) -> ur/vr (S8)
    float* dist  = W;                   // 2048*2048
    float* distB = W + 4194304;
    float* cfeat = W;                   // 2048*96 (after dist dead)
    float* ur    = W;                   // 8192*384 (after cfeat dead)
    float* vr    = W + 3145728;
    // Persistent zone:
    float* h_ctx = W + 8388608;         // 393,216
    float* h_tgt = h_ctx + 393216;
    float* UV    = h_tgt + 393216;      // [u1|v1] then [u2c|v2c|u2t|v2t]
    float* u1  = UV;            float* v1  = UV + 393216;
    float* u2c = UV;            float* v2c = UV + 196608;
    float* u2t = UV + 393216;   float* v2t = UV + 589824;
    float* tfeat = UV + 786432;         // 196,608
    float* xyz1  = tfeat + 196608;      // 24,576
    float4* pts  = (float4*)(xyz1 + 24576);
    float* sqb     = (float*)pts + 32768;
    float* sq_hctx = sqb + N2;
    float* sq_htgt = sq_hctx + N2;
    int* cidx1 = (int*)(sq_htgt + N2);
    int* cidx2 = cidx1 + N2*16;
    int* tidx2 = cidx2 + N2*8;
    int* ridx  = tidx2 + N2*2;

    float* out_ctx = (float*)d_out;
    float* out_tgt = out_ctx + N2*3;

    dim3 b16(16, 16);
    const int NTRI = 32*33/2;
    const float* NUL = nullptr;

    // --- S1: rowsq, dist(tokens), knn16 (tgt conv1 uses first 4 of cidx1)
    rowsq_kernel<<<N2/4, 256, 0, stream>>>(ctx_tokens, sqb, CDIM);
    dist64tri_kernel<<<NTRI, b16, 0, stream>>>(ctx_tokens, sqb, dist, N2, CDIM);
    knn_dist_rt_kernel<<<N2/4, 256, 0, stream>>>(dist, dist, N2, cidx1, cidx1, 16, 16, N2/4);

    // --- S2: u1/v1 GEMMs; conv1 fused gather-GEMM+reg-max (coalesced fill); row-sq
    gemmquad_kernel<<<dim3(3, 32, 2), b16, 0, stream>>>(
        ctx_tokens, c1w1, c1w1 + 384*192, c1b1, u1,
        ctx_tokens, c1w1 + 384*192, NUL, NUL, v1,
        ctx_tokens, c1w1, NUL, NUL, u1,   // unused (z<2)
        ctx_tokens, c1w1, NUL, NUL, v1,
        H1C, CDIM);
    edge_fused1_kernel<<<dim3(3, 512, 2), b16, 0, stream>>>(u1, v1, cidx1, c1w2, c1b2,
                                                            h_ctx, h_tgt, N2);
    rowsqpair_kernel<<<dim3(N2/4, 2), 256, 0, stream>>>(h_ctx, sq_hctx, h_tgt, sq_htgt, H1C);

    // --- S3: dist(h_ctx)+dist(h_tgt), paired knn, u2/v2 quad
    distpairtri_kernel<<<dim3(NTRI, 1, 2), b16, 0, stream>>>(h_ctx, sq_hctx, dist,
                                                             h_tgt, sq_htgt, distB, N2, H1C);
    knn_dist_rt_kernel<<<2*(N2/4), 256, 0, stream>>>(dist, distB, N2, cidx2, tidx2, 8, 2, N2/4);
    gemmquad_kernel<<<dim3(2, 32, 4), b16, 0, stream>>>(
        h_ctx, c2w1, c2w1 + 192*96, c2b1, u2c,
        h_ctx, c2w1 + 192*96, NUL, NUL, v2c,
        h_tgt, c2w1, c2w1 + 192*96, c2b1, u2t,
        h_tgt, c2w1 + 192*96, NUL, NUL, v2t,
        H2C, H1C);

    // --- S4: conv2 fused gather-GEMM+reg-max; cdef head
    edge_fused2_kernel<<<dim3(2, 256, 2), b16, 0, stream>>>(u2c, v2c, u2t, v2t, cidx2, tidx2,
                                                            c2w2, c2b2, cfeat, tfeat, N2);
    cdef_kernel<<<N2, 128, 0, stream>>>(cfeat, cdw1, cdb1, cdw2, cdb2, ctx_xyz, out_ctx);

    // --- S6: folding MLP (fused upsample+noise; emits xyz1 + packed pts)
    fold_kernel<<<N8/16, 256, 0, stream>>>(pred_xyz, noise, tfeat, fw1, fb1, fw2, fb2, fw3, fb3, xyz1, pts);

    // --- S7: refiner knn (512 thr, 2 rows/wave, 16 rows/block)
    knn_xyz512_kernel<<<N8/16, 512, 0, stream>>>(pts, N8, ridx);

    // --- S8: refiner u/v gather-GEMMs, residual EdgeConv to output
    gatherpair_kernel<<<dim3(6, N8/64, 2), b16, 0, stream>>>(
        tfeat, xyz1,
        rw1, rw1 + 99*384, rb1, ur,
        rw1 + 99*384, NUL, NUL, vr,
        384, 99);
    edge_ref_kernel<<<N8/4, 256, 0, stream>>>(ur, vr, rw2, rb2, ridx, xyz1, out_tgt, N8);
}

// Round 15
// 437.733 us; speedup vs baseline: 1.0899x; 1.0030x over previous
//
#include <hip/hip_runtime.h>

#define N2 2048      // B*P
#define N8 8192      // B*P*UP
#define CDIM 384
#define H1C 192      // C/2
#define H2C 96       // C/4
#define PDIM 512
#define KRR 16
#define FOLDH 256
#define XCAP 256
#define XCAPX 128
#define XTILE 1024
#define INFF 3.0e38f

__device__ __forceinline__ float frelu(float x) { return x > 0.f ? x : 0.f; }

// ---------------- 64-lane bitonic sorts (ascending) --------------------------------
__device__ __forceinline__ void bitonic64_val(float& d, int lane) {
    #pragma unroll
    for (int k = 2; k <= 64; k <<= 1) {
        #pragma unroll
        for (int j = k >> 1; j > 0; j >>= 1) {
            float od = __shfl_xor(d, j);
            bool lower = (lane & j) == 0;
            bool olt = od < d;
            bool take = lower ? olt : !olt;
            if (lane & k) take = !take;
            if (take) d = od;
        }
    }
}

__device__ __forceinline__ void bitonic64_pair(float& d, int& c, int lane) {
    #pragma unroll
    for (int k = 2; k <= 64; k <<= 1) {
        #pragma unroll
        for (int j = k >> 1; j > 0; j >>= 1) {
            float od = __shfl_xor(d, j);
            int   oc = __shfl_xor(c, j);
            bool lower = (lane & j) == 0;
            bool olt = (od < d) || (od == d && oc < c);
            bool take = lower ? olt : !olt;
            if (lane & k) take = !take;
            if (take) { d = od; c = oc; }
        }
    }
}

// ---------------- slow exact select fallback (cnt > 64, rare) ----------------------
__device__ __forceinline__ void select_slow(const float* bd, const int* bi, int cnt,
                                            int ksel, int row, int n, int* out, int lane) {
    float cd[4]; int cix[4];
    #pragma unroll
    for (int s = 0; s < 4; ++s) {
        int c = lane + 64*s;
        bool v = c < cnt;
        cd[s]  = v ? bd[c] : INFF;
        cix[s] = v ? bi[c] : 0x7fffffff;
    }
    for (int r = 0; r < ksel; ++r) {
        float lv = cd[0]; int li = cix[0];
        #pragma unroll
        for (int s = 1; s < 4; ++s) {
            if (cd[s] < lv || (cd[s] == lv && cix[s] < li)) { lv = cd[s]; li = cix[s]; }
        }
        float wv = lv; int wi = li;
        #pragma unroll
        for (int s = 1; s < 64; s <<= 1) {
            float ov = __shfl_xor(wv, s); int oi = __shfl_xor(wi, s);
            if (ov < wv || (ov == wv && oi < wi)) { wv = ov; wi = oi; }
        }
        if (lane == 0) {
            int safe = ((unsigned)wi < (unsigned)n) ? wi : ((row + 1) & (n - 1));
            out[row*ksel + r] = safe;
        }
        #pragma unroll
        for (int s = 0; s < 4; ++s) {
            if (cd[s] == wv && cix[s] == wi) { cd[s] = INFF; cix[s] = 0x7fffffff; }
        }
    }
}

// ---------------- row squared norms (wave per row; single + paired) ----------------
__global__ __launch_bounds__(256) void rowsq_kernel(const float* __restrict__ x,
                                                    float* __restrict__ sq, int d) {
    int wave = threadIdx.x >> 6, lane = threadIdx.x & 63;
    int row = blockIdx.x*4 + wave;
    float acc = 0.f;
    for (int k = lane; k < d; k += 64) { float v = x[(size_t)row*d + k]; acc += v*v; }
    #pragma unroll
    for (int s = 1; s < 64; s <<= 1) acc += __shfl_xor(acc, s);
    if (lane == 0) sq[row] = acc;
}

__global__ __launch_bounds__(256) void rowsqpair_kernel(const float* __restrict__ xA,
                                                        float* __restrict__ sqA,
                                                        const float* __restrict__ xB,
                                                        float* __restrict__ sqB, int d) {
    const float* x = blockIdx.y ? xB : xA;
    float* sq = blockIdx.y ? sqB : sqA;
    int wave = threadIdx.x >> 6, lane = threadIdx.x & 63;
    int row = blockIdx.x*4 + wave;
    float acc = 0.f;
    for (int k = lane; k < d; k += 64) { float v = x[(size_t)row*d + k]; acc += v*v; }
    #pragma unroll
    for (int s = 1; s < 64; s <<= 1) acc += __shfl_xor(acc, s);
    if (lane == 0) sq[row] = acc;
}

// ---------------- triangular symmetric dist: direct + mirrored tile ----------------
__device__ __forceinline__ void disttri_body(const float* __restrict__ x, const float* __restrict__ sq,
                                             float* __restrict__ dist, int n, int K) {
    int l = blockIdx.x;
    int by = (int)((sqrtf(8.f*(float)l + 1.f) - 1.f)*0.5f);
    while ((by+1)*(by+2)/2 <= l) ++by;
    while (by*(by+1)/2 > l) --by;
    int bx = l - by*(by+1)/2;
    int row0 = by*64, col0 = bx*64;
    __shared__ __align__(16) float As[16][68];
    __shared__ __align__(16) float Bs[16][68];
    __shared__ __align__(16) float T[64][68];
    int tx = threadIdx.x, ty = threadIdx.y;
    int t = ty*16 + tx;
    float acc[4][4] = {};
    for (int k0 = 0; k0 < K; k0 += 16) {
        #pragma unroll
        for (int r = 0; r < 4; ++r) {
            int e = t + 256*r; int kk = e & 15, mm = e >> 4;
            As[kk][mm] = x[(size_t)(row0+mm)*K + k0+kk];
            Bs[kk][mm] = x[(size_t)(col0+mm)*K + k0+kk];
        }
        __syncthreads();
        #pragma unroll
        for (int kk = 0; kk < 16; ++kk) {
            float4 a4 = *(const float4*)&As[kk][ty*4];
            float4 b4 = *(const float4*)&Bs[kk][tx*4];
            acc[0][0] += a4.x*b4.x; acc[0][1] += a4.x*b4.y; acc[0][2] += a4.x*b4.z; acc[0][3] += a4.x*b4.w;
            acc[1][0] += a4.y*b4.x; acc[1][1] += a4.y*b4.y; acc[1][2] += a4.y*b4.z; acc[1][3] += a4.y*b4.w;
            acc[2][0] += a4.z*b4.x; acc[2][1] += a4.z*b4.y; acc[2][2] += a4.z*b4.z; acc[2][3] += a4.z*b4.w;
            acc[3][0] += a4.w*b4.x; acc[3][1] += a4.w*b4.y; acc[3][2] += a4.w*b4.z; acc[3][3] += a4.w*b4.w;
        }
        __syncthreads();
    }
    bool mirror = (row0 != col0);
    #pragma unroll
    for (int i2 = 0; i2 < 4; ++i2) {
        int row = row0 + ty*4 + i2;
        float sr = sq[row];
        float4 o;
        o.x = sr + sq[col0+tx*4+0] - 2.f*acc[i2][0];
        o.y = sr + sq[col0+tx*4+1] - 2.f*acc[i2][1];
        o.z = sr + sq[col0+tx*4+2] - 2.f*acc[i2][2];
        o.w = sr + sq[col0+tx*4+3] - 2.f*acc[i2][3];
        *(float4*)&dist[(size_t)row*n + col0 + tx*4] = o;
        if (mirror) {
            T[tx*4+0][ty*4+i2] = o.x;
            T[tx*4+1][ty*4+i2] = o.y;
            T[tx*4+2][ty*4+i2] = o.z;
            T[tx*4+3][ty*4+i2] = o.w;
        }
    }
    if (mirror) {
        __syncthreads();
        #pragma unroll
        for (int i2 = 0; i2 < 4; ++i2) {
            int orow = col0 + ty*4 + i2;
            float4 o = *(const float4*)&T[ty*4+i2][tx*4];
            *(float4*)&dist[(size_t)orow*n + row0 + tx*4] = o;
        }
    }
}

__global__ __launch_bounds__(256) void dist64tri_kernel(const float* __restrict__ x,
                                                        const float* __restrict__ sq,
                                                        float* __restrict__ dist, int n, int K) {
    disttri_body(x, sq, dist, n, K);
}

__global__ __launch_bounds__(256) void distpairtri_kernel(const float* __restrict__ xA,
                                                          const float* __restrict__ sqA,
                                                          float* __restrict__ dA,
                                                          const float* __restrict__ xB,
                                                          const float* __restrict__ sqB,
                                                          float* __restrict__ dB, int n, int K) {
    const float* x  = blockIdx.z ? xB : xA;
    const float* sq = blockIdx.z ? sqB : sqA;
    float* dist     = blockIdx.z ? dB : dA;
    disttri_body(x, sq, dist, n, K);
}

// ---------------- 16x64 GEMM tile (high block count for small GEMMs) ---------------
// Thread (tx,ty): row = row0+ty, cols col0+tx*4..+3. Same k-order per output as the
// 64x64 tile (k0 asc, kk asc) -> bit-identical results.
__device__ __forceinline__ void gemm16_body(const float* __restrict__ A, const float* __restrict__ Bw,
                                            const float* __restrict__ BwB, const float* __restrict__ bias,
                                            float* __restrict__ C, int m, int K) {
    __shared__ __align__(16) float As[16][17];
    __shared__ __align__(16) float Bs[16][68];
    int tx = threadIdx.x, ty = threadIdx.y;
    int t = ty*16 + tx;
    int row0 = blockIdx.y*16, col0 = blockIdx.x*64;
    float acc[4] = {};
    for (int k0 = 0; k0 < K; k0 += 16) {
        {
            int kk = t & 15, mm = t >> 4;
            As[kk][mm] = (k0 + kk < K) ? A[(size_t)(row0+mm)*K + k0+kk] : 0.f;
        }
        #pragma unroll
        for (int r = 0; r < 4; ++r) {
            int e = t + 256*r; int nn = e & 63, kk = e >> 6;
            int col = col0 + nn, k = k0 + kk;
            float bv = 0.f;
            if (k < K && col < m) {
                bv = Bw[(size_t)k*m + col];
                if (BwB) bv -= BwB[(size_t)k*m + col];
            }
            Bs[kk][nn] = bv;
        }
        __syncthreads();
        #pragma unroll
        for (int kk = 0; kk < 16; ++kk) {
            float a = As[kk][ty];
            float4 b4 = *(const float4*)&Bs[kk][tx*4];
            acc[0] += a*b4.x; acc[1] += a*b4.y; acc[2] += a*b4.z; acc[3] += a*b4.w;
        }
        __syncthreads();
    }
    int row = row0 + ty;
    #pragma unroll
    for (int j2 = 0; j2 < 4; ++j2) {
        int col = col0 + tx*4 + j2;
        if (col < m) C[(size_t)row*m + col] = acc[j2] + (bias ? bias[col] : 0.f);
    }
}

__global__ __launch_bounds__(256) void gemm16quad_kernel(
    const float* A0, const float* Bw0, const float* BwB0, const float* bias0, float* C0,
    const float* A1, const float* Bw1, const float* BwB1, const float* bias1, float* C1,
    const float* A2, const float* Bw2, const float* BwB2, const float* bias2, float* C2,
    const float* A3, const float* Bw3, const float* BwB3, const float* bias3, float* C3,
    int m, int K) {
    int z = blockIdx.z;
    const float* A    = (z==0)?A0 :(z==1)?A1 :(z==2)?A2 :A3;
    const float* Bw   = (z==0)?Bw0:(z==1)?Bw1:(z==2)?Bw2:Bw3;
    const float* BwB  = (z==0)?BwB0:(z==1)?BwB1:(z==2)?BwB2:BwB3;
    const float* bias = (z==0)?bias0:(z==1)?bias1:(z==2)?bias2:bias3;
    float* C          = (z==0)?C0 :(z==1)?C1 :(z==2)?C2 :C3;
    gemm16_body(A, Bw, BwB, bias, C, m, K);
}

// ---------------- EdgeConv layer-2 gather-GEMM, reg-max, coalesced fill ------------
template<int EPT, int SELF, int EREAL, int IDXS, int YT>
__device__ __forceinline__ void edge_fused_body(const float* __restrict__ u, const float* __restrict__ v,
                                                const int* __restrict__ idx,
                                                const float* __restrict__ Bw, const float* __restrict__ bias,
                                                float* __restrict__ hout, int m, int K, int npts) {
    if ((int)blockIdx.y >= YT) return;
    constexpr int LOG2EPT = (EPT == 16) ? 4 : (EPT == 8) ? 3 : 2;
    __shared__ __align__(16) float As[16][68];
    __shared__ __align__(16) float Bs[16][68];
    int tx = threadIdx.x, ty = threadIdx.y;
    int t = ty*16 + tx;
    int row0 = blockIdx.y*64, col0 = blockIdx.x*64;
    int mmA = t >> 2;
    int kqA = (t & 3) * 4;
    int rowA = row0 + mmA;
    int iA = rowA >> LOG2EPT;
    int eA = rowA - (iA << LOG2EPT);
    int jA;
    if (SELF && eA == 0) jA = iA;
    else if (eA < EREAL) jA = idx[iA*IDXS + (eA - SELF)];
    else jA = iA;
    jA = ((unsigned)jA < (unsigned)npts) ? jA : iA;
    const float* uRow = u + (size_t)iA*K + kqA;
    const float* vRow = v + (size_t)jA*K + kqA;
    int nnB = (t & 15) * 4, kkB = t >> 4;
    float acc[4][4] = {};
    for (int k0 = 0; k0 < K; k0 += 16) {
        float4 u4 = *(const float4*)(uRow + k0);
        float4 v4 = *(const float4*)(vRow + k0);
        As[kqA+0][mmA] = frelu(u4.x + v4.x);
        As[kqA+1][mmA] = frelu(u4.y + v4.y);
        As[kqA+2][mmA] = frelu(u4.z + v4.z);
        As[kqA+3][mmA] = frelu(u4.w + v4.w);
        int colB = col0 + nnB;
        if (colB + 3 < m) {
            *(float4*)&Bs[kkB][nnB] = *(const float4*)&Bw[(size_t)(k0+kkB)*m + colB];
        } else {
            #pragma unroll
            for (int q = 0; q < 4; ++q) {
                int col = colB + q;
                Bs[kkB][nnB+q] = (col < m) ? Bw[(size_t)(k0+kkB)*m + col] : 0.f;
            }
        }
        __syncthreads();
        #pragma unroll
        for (int kk = 0; kk < 16; ++kk) {
            float4 a4 = *(const float4*)&As[kk][ty*4];
            float4 b4 = *(const float4*)&Bs[kk][tx*4];
            acc[0][0] += a4.x*b4.x; acc[0][1] += a4.x*b4.y; acc[0][2] += a4.x*b4.z; acc[0][3] += a4.x*b4.w;
            acc[1][0] += a4.y*b4.x; acc[1][1] += a4.y*b4.y; acc[1][2] += a4.y*b4.z; acc[1][3] += a4.y*b4.w;
            acc[2][0] += a4.z*b4.x; acc[2][1] += a4.z*b4.y; acc[2][2] += a4.z*b4.z; acc[2][3] += a4.z*b4.w;
            acc[3][0] += a4.w*b4.x; acc[3][1] += a4.w*b4.y; acc[3][2] += a4.w*b4.z; acc[3][3] += a4.w*b4.w;
        }
        __syncthreads();
    }
    float bestv[4];
    #pragma unroll
    for (int j2 = 0; j2 < 4; ++j2)
        bestv[j2] = fmaxf(fmaxf(acc[0][j2], acc[1][j2]), fmaxf(acc[2][j2], acc[3][j2]));
    if (EPT >= 8) {
        #pragma unroll
        for (int j2 = 0; j2 < 4; ++j2) bestv[j2] = fmaxf(bestv[j2], __shfl_xor(bestv[j2], 16));
    }
    if (EPT == 16) {
        #pragma unroll
        for (int j2 = 0; j2 < 4; ++j2) bestv[j2] = fmaxf(bestv[j2], __shfl_xor(bestv[j2], 32));
    }
    bool writer; int p;
    if (EPT == 16) { writer = (ty & 3) == 0; p = (row0 >> 4) + (ty >> 2); }
    else if (EPT == 8) { writer = (ty & 1) == 0; p = (row0 >> 3) + (ty >> 1); }
    else { writer = true; p = (row0 >> 2) + ty; }
    if (writer) {
        #pragma unroll
        for (int j2 = 0; j2 < 4; ++j2) {
            int col = col0 + tx*4 + j2;
            if (col < m) hout[(size_t)p*m + col] = bestv[j2] + bias[col];
        }
    }
}

__global__ __launch_bounds__(256) void edge_fused1_kernel(const float* u1, const float* v1,
                                                          const int* cidx1,
                                                          const float* Bw, const float* bias,
                                                          float* h_ctx, float* h_tgt, int npts) {
    if (blockIdx.z == 0) edge_fused_body<16,0,16,16,512>(u1, v1, cidx1, Bw, bias, h_ctx, H1C, H1C, npts);
    else                 edge_fused_body<8,1,5,16,256>(u1, v1, cidx1, Bw, bias, h_tgt, H1C, H1C, npts);
}

__global__ __launch_bounds__(256) void edge_fused2_kernel(const float* u2c, const float* v2c,
                                                          const float* u2t, const float* v2t,
                                                          const int* cidx2, const int* tidx2,
                                                          const float* Bw, const float* bias,
                                                          float* cfeat, float* tfeat, int npts) {
    if (blockIdx.z == 0) edge_fused_body<8,0,8,8,256>(u2c, v2c, cidx2, Bw, bias, cfeat, H2C, H2C, npts);
    else                 edge_fused_body<4,1,3,2,128>(u2t, v2t, tidx2, Bw, bias, tfeat, H2C, H2C, npts);
}

// ---------------- ctx deform head: out = xyz + 0.05 * mlp2(cfeat) ------------------
__global__ __launch_bounds__(128) void cdef_kernel(const float* __restrict__ cfeat,
                                                   const float* __restrict__ cdw1, const float* __restrict__ cdb1,
                                                   const float* __restrict__ cdw2, const float* __restrict__ cdb2,
                                                   const float* __restrict__ ctx_xyz,
                                                   float* __restrict__ out_ctx) {
    int i = blockIdx.x, tid = threadIdx.x, wave = tid >> 6, lane = tid & 63;
    __shared__ float sf_[96], st2_[96];
    if (tid < 96) sf_[tid] = cfeat[(size_t)i*H2C + tid];
    __syncthreads();
    if (tid < 96) {
        float a = cdb1[tid];
        for (int k = 0; k < 96; ++k) a += sf_[k]*cdw1[k*96 + tid];
        st2_[tid] = frelu(a);
    }
    __syncthreads();
    if (wave == 0) {
        float s0 = st2_[lane];
        float p0 = s0*cdw2[lane*3+0], p1 = s0*cdw2[lane*3+1], p2 = s0*cdw2[lane*3+2];
        if (lane < 32) {
            float s1 = st2_[lane+64];
            p0 += s1*cdw2[(lane+64)*3+0];
            p1 += s1*cdw2[(lane+64)*3+1];
            p2 += s1*cdw2[(lane+64)*3+2];
        }
        #pragma unroll
        for (int s = 1; s < 64; s <<= 1) {
            p0 += __shfl_xor(p0, s); p1 += __shfl_xor(p1, s); p2 += __shfl_xor(p2, s);
        }
        if (lane == 0) {
            out_ctx[i*3+0] = ctx_xyz[i*3+0] + 0.05f*(cdb2[0] + p0);
            out_ctx[i*3+1] = ctx_xyz[i*3+1] + 0.05f*(cdb2[1] + p1);
            out_ctx[i*3+2] = ctx_xyz[i*3+2] + 0.05f*(cdb2[2] + p2);
        }
    }
}

// refiner gather-GEMM pair: A row gathered from [featd(96) | xyzg(3)], K = 99
__global__ __launch_bounds__(256) void gatherpair_kernel(
    const float* __restrict__ featd, const float* __restrict__ xyzg,
    const float* Bw0, const float* BwB0, const float* bias0, float* C0,
    const float* Bw1, const float* BwB1, const float* bias1, float* C1,
    int m, int K) {
    int z = blockIdx.z;
    const float* Bw   = z ? Bw1 : Bw0;
    const float* BwB  = z ? BwB1 : BwB0;
    const float* bias = z ? bias1 : bias0;
    float* C          = z ? C1 : C0;
    __shared__ __align__(16) float As[16][68];
    __shared__ __align__(16) float Bs[16][68];
    int tx = threadIdx.x, ty = threadIdx.y;
    int t = ty*16 + tx;
    int row0 = blockIdx.y*64, col0 = blockIdx.x*64;
    float acc[4][4] = {};
    for (int k0 = 0; k0 < K; k0 += 16) {
        #pragma unroll
        for (int r = 0; r < 4; ++r) {
            int e = t + 256*r; int kk = e & 15, mm = e >> 4;
            int k = k0 + kk, grow = row0 + mm;
            float av = 0.f;
            if (k < K) {
                if (k < 96) { int b = grow >> 11, p = (grow & 2047) >> 2;
                              av = featd[(size_t)(b*PDIM + p)*H2C + k]; }
                else av = xyzg[(size_t)grow*3 + (k - 96)];
            }
            As[kk][mm] = av;
        }
        #pragma unroll
        for (int r = 0; r < 4; ++r) {
            int e = t + 256*r; int nn = e & 63, kk = e >> 6;
            int col = col0 + nn, k = k0 + kk;
            float bv = 0.f;
            if (k < K && col < m) {
                bv = Bw[(size_t)k*m + col];
                if (BwB) bv -= BwB[(size_t)k*m + col];
            }
            Bs[kk][nn] = bv;
        }
        __syncthreads();
        #pragma unroll
        for (int kk = 0; kk < 16; ++kk) {
            float4 a4 = *(const float4*)&As[kk][ty*4];
            float4 b4 = *(const float4*)&Bs[kk][tx*4];
            acc[0][0] += a4.x*b4.x; acc[0][1] += a4.x*b4.y; acc[0][2] += a4.x*b4.z; acc[0][3] += a4.x*b4.w;
            acc[1][0] += a4.y*b4.x; acc[1][1] += a4.y*b4.y; acc[1][2] += a4.y*b4.z; acc[1][3] += a4.y*b4.w;
            acc[2][0] += a4.z*b4.x; acc[2][1] += a4.z*b4.y; acc[2][2] += a4.z*b4.z; acc[2][3] += a4.z*b4.w;
            acc[3][0] += a4.w*b4.x; acc[3][1] += a4.w*b4.y; acc[3][2] += a4.w*b4.z; acc[3][3] += a4.w*b4.w;
        }
        __syncthreads();
    }
    #pragma unroll
    for (int i2 = 0; i2 < 4; ++i2) {
        int row = row0 + ty*4 + i2;
        #pragma unroll
        for (int j2 = 0; j2 < 4; ++j2) {
            int col = col0 + tx*4 + j2;
            if (col < m) C[(size_t)row*m + col] = acc[i2][j2] + (bias ? bias[col] : 0.f);
        }
    }
}

// ---------------- knn from dist rows (4 rows/block, bitonic select) ----------------
__global__ __launch_bounds__(256) void knn_dist_rt_kernel(const float* __restrict__ dA,
                                                          const float* __restrict__ dB, int n,
                                                          int* __restrict__ outA, int* __restrict__ outB,
                                                          int kA, int kB, int nblkA) {
    int wave = threadIdx.x >> 6, lane = threadIdx.x & 63;
    bool useB = (int)blockIdx.x >= nblkA;
    const float* dist = useB ? dB : dA;
    int* out = useB ? outB : outA;
    int ksel = useB ? kB : kA;
    int bx = useB ? (int)blockIdx.x - nblkA : (int)blockIdx.x;
    int row = bx*4 + wave;
    __shared__ float bufd[4][XCAP];
    __shared__ int   bufi[4][XCAP];
    __shared__ int   lcnt[4];
    const float4* drow = (const float4*)(dist + (size_t)row*n);
    int nq = n >> 2;
    float mv = INFF;
    for (int i = lane; i < nq; i += 64) {
        float4 d4 = drow[i]; int base = i*4;
        float a = (base+0 == row) ? INFF : d4.x;
        float b = (base+1 == row) ? INFF : d4.y;
        float c = (base+2 == row) ? INFF : d4.z;
        float d = (base+3 == row) ? INFF : d4.w;
        mv = fminf(mv, fminf(fminf(a,b), fminf(c,d)));
    }
    float sd = mv;
    bitonic64_val(sd, lane);
    float Tv = __shfl(sd, ksel - 1);
    if (lane == 0) lcnt[wave] = 0;
    for (int i = lane; i < nq; i += 64) {
        float4 d4 = drow[i]; int base = i*4;
        float dv4[4] = {d4.x, d4.y, d4.z, d4.w};
        #pragma unroll
        for (int q = 0; q < 4; ++q) {
            int col = base + q;
            if (col != row && dv4[q] <= Tv) {
                int pos = atomicAdd(&lcnt[wave], 1);
                if (pos < XCAP) { bufd[wave][pos] = dv4[q]; bufi[wave][pos] = col; }
            }
        }
    }
    int cnt = lcnt[wave]; if (cnt > XCAP) cnt = XCAP;
    if (cnt <= 64) {
        float d = (lane < cnt) ? bufd[wave][lane] : INFF;
        int   c = (lane < cnt) ? bufi[wave][lane] : 0x7fffffff;
        bitonic64_pair(d, c, lane);
        if (lane < ksel) {
            int safe = ((unsigned)c < (unsigned)n) ? c : ((row + 1) & (n - 1));
            out[row*ksel + lane] = safe;
        }
    } else {
        select_slow(bufd[wave], bufi[wave], cnt, ksel, row, n, out, lane);
    }
}

// ---------------- knn over packed xyz: 16 rows/block, 512 thr, 2 rows/wave ---------
__global__ __launch_bounds__(512) void knn_xyz512_kernel(const float4* __restrict__ pts, int n,
                                                         int* __restrict__ out_idx) {
    int tid = threadIdx.x, wave = tid >> 6, lane = tid & 63;
    int rbase = blockIdx.x*16 + wave*2;
    __shared__ __align__(16) float4 tile[XTILE];
    __shared__ float bufd[16][XCAPX];
    __shared__ int   bufi[16][XCAPX];
    __shared__ int   lcnt[16];
    float4 P0 = pts[rbase], P1 = pts[rbase+1];
    float mv0 = INFF, mv1 = INFF;
    for (int t0 = 0; t0 < n; t0 += XTILE) {
        __syncthreads();
        #pragma unroll
        for (int k = 0; k < XTILE/512; ++k) tile[tid + 512*k] = pts[t0 + tid + 512*k];
        __syncthreads();
        for (int c = lane; c < XTILE; c += 64) {
            float4 q = tile[c];
            int col = t0 + c;
            float d0 = P0.w + q.w - 2.f*(P0.x*q.x + P0.y*q.y + P0.z*q.z);
            float d1 = P1.w + q.w - 2.f*(P1.x*q.x + P1.y*q.y + P1.z*q.z);
            d0 = (col == rbase)   ? INFF : d0;
            d1 = (col == rbase+1) ? INFF : d1;
            mv0 = fminf(mv0, d0);
            mv1 = fminf(mv1, d1);
        }
    }
    bitonic64_val(mv0, lane);
    bitonic64_val(mv1, lane);
    float Tv0 = __shfl(mv0, 15), Tv1 = __shfl(mv1, 15);
    if (lane < 2) lcnt[wave*2 + lane] = 0;
    for (int t0 = 0; t0 < n; t0 += XTILE) {
        __syncthreads();
        #pragma unroll
        for (int k = 0; k < XTILE/512; ++k) tile[tid + 512*k] = pts[t0 + tid + 512*k];
        __syncthreads();
        for (int c = lane; c < XTILE; c += 64) {
            float4 q = tile[c];
            int col = t0 + c;
            float d0 = P0.w + q.w - 2.f*(P0.x*q.x + P0.y*q.y + P0.z*q.z);
            float d1 = P1.w + q.w - 2.f*(P1.x*q.x + P1.y*q.y + P1.z*q.z);
            if (col != rbase && d0 <= Tv0) {
                int pos = atomicAdd(&lcnt[wave*2+0], 1);
                if (pos < XCAPX) { bufd[wave*2+0][pos] = d0; bufi[wave*2+0][pos] = col; }
            }
            if (col != rbase+1 && d1 <= Tv1) {
                int pos = atomicAdd(&lcnt[wave*2+1], 1);
                if (pos < XCAPX) { bufd[wave*2+1][pos] = d1; bufi[wave*2+1][pos] = col; }
            }
        }
    }
    for (int jj = 0; jj < 2; ++jj) {
        int brow = wave*2 + jj, row = rbase + jj;
        int cnt = lcnt[brow]; if (cnt > XCAPX) cnt = XCAPX;
        if (cnt <= 64) {
            float d = (lane < cnt) ? bufd[brow][lane] : INFF;
            int   c = (lane < cnt) ? bufi[brow][lane] : 0x7fffffff;
            bitonic64_pair(d, c, lane);
            if (lane < 16) {
                int safe = ((unsigned)c < (unsigned)n) ? c : ((row + 1) & (n - 1));
                out_idx[row*16 + lane] = safe;
            }
        } else {
            float cd[2]; int cix[2];
            #pragma unroll
            for (int s = 0; s < 2; ++s) {
                int c = lane + 64*s;
                bool v = c < cnt;
                cd[s]  = v ? bufd[brow][c] : INFF;
                cix[s] = v ? bufi[brow][c] : 0x7fffffff;
            }
            for (int r = 0; r < 16; ++r) {
                float lv = cd[0]; int li = cix[0];
                if (cd[1] < lv || (cd[1] == lv && cix[1] < li)) { lv = cd[1]; li = cix[1]; }
                float wv = lv; int wi = li;
                #pragma unroll
                for (int s = 1; s < 64; s <<= 1) {
                    float ov = __shfl_xor(wv, s); int oi = __shfl_xor(wi, s);
                    if (ov < wv || (ov == wv && oi < wi)) { wv = ov; wi = oi; }
                }
                if (lane == 0) {
                    int safe = ((unsigned)wi < (unsigned)n) ? wi : ((row + 1) & (n - 1));
                    out_idx[row*16 + r] = safe;
                }
                #pragma unroll
                for (int s = 0; s < 2; ++s) {
                    if (cd[s] == wv && cix[s] == wi) { cd[s] = INFF; cix[s] = 0x7fffffff; }
                }
            }
        }
    }
}

// ---------------- refiner EdgeConv (H1=384, H2=3), wave per point ------------------
__global__ __launch_bounds__(256) void edge_ref_kernel(const float* __restrict__ ur,
                                                       const float* __restrict__ vr,
                                                       const float* __restrict__ w2,
                                                       const float* __restrict__ b2,
                                                       const int* __restrict__ idx,
                                                       const float* __restrict__ xyz_in,
                                                       float* __restrict__ out, int n) {
    int wave = threadIdx.x >> 6, lane = threadIdx.x & 63;
    int i = blockIdx.x*4 + wave;
    if (i >= n) return;
    float m0 = -INFF, m1 = -INFF, m2 = -INFF;
    float uh[6];
    #pragma unroll
    for (int t = 0; t < 6; ++t) uh[t] = ur[(size_t)i*384 + lane + 64*t];
    for (int e = 0; e < KRR; ++e) {
        int j = idx[i*KRR + e];
        j = ((unsigned)j < (unsigned)n) ? j : i;
        float a0 = 0.f, a1 = 0.f, a2 = 0.f;
        #pragma unroll
        for (int t = 0; t < 6; ++t) {
            int h = lane + 64*t;
            float tv = frelu(uh[t] + vr[(size_t)j*384 + h]);
            a0 += tv*w2[h*3+0]; a1 += tv*w2[h*3+1]; a2 += tv*w2[h*3+2];
        }
        #pragma unroll
        for (int s = 32; s > 0; s >>= 1) {
            a0 += __shfl_xor(a0, s); a1 += __shfl_xor(a1, s); a2 += __shfl_xor(a2, s);
        }
        m0 = fmaxf(m0, a0 + b2[0]); m1 = fmaxf(m1, a1 + b2[1]); m2 = fmaxf(m2, a2 + b2[2]);
    }
    if (lane == 0) {
        out[i*3+0] = xyz_in[i*3+0] + m0;
        out[i*3+1] = xyz_in[i*3+1] + m1;
        out[i*3+2] = xyz_in[i*3+2] + m2;
    }
}

// ---------------- folding MLP, fused upsample+noise in, xyz1 + packed pts out ------
__global__ __launch_bounds__(256) void fold_kernel(const float* __restrict__ pred_xyz,
                                                   const float* __restrict__ noise,
                                                   const float* __restrict__ featd,
                                                   const float* __restrict__ w1, const float* __restrict__ b1,
                                                   const float* __restrict__ w2, const float* __restrict__ b2,
                                                   const float* __restrict__ w3, const float* __restrict__ b3,
                                                   float* __restrict__ xyz1, float4* __restrict__ pts_out) {
    const int PTS = 16;
    int base = blockIdx.x * PTS;
    int tid = threadIdx.x;
    __shared__ __align__(16) float xin[PTS][100];
    __shared__ __align__(16) float h1[PTS][FOLDH];
    __shared__ __align__(16) float h2s[PTS][FOLDH];
    __shared__ float oxyz[PTS][3];
    for (int t = tid; t < PTS*100; t += 256) {
        int pt = t/100, k = t - pt*100;
        int gi = base + pt;
        float vv = 0.f;
        if (k < 3) {
            int b = gi >> 11, p = (gi & 2047) >> 2;
            vv = pred_xyz[(size_t)(b*PDIM + p)*3 + k] + 0.02f*noise[(size_t)gi*3 + k];
        } else if (k < 99) {
            int b = gi >> 11, p = (gi & 2047) >> 2;
            vv = featd[(size_t)(b*PDIM + p)*H2C + (k - 3)];
        }
        xin[pt][k] = vv;
    }
    __syncthreads();
    int c = tid;
    float acc[PTS];
    #pragma unroll
    for (int pt = 0; pt < PTS; ++pt) acc[pt] = b1[c];
    for (int k0 = 0; k0 < 96; k0 += 4) {
        float wa = w1[(k0+0)*FOLDH + c], wb = w1[(k0+1)*FOLDH + c];
        float wc = w1[(k0+2)*FOLDH + c], wd = w1[(k0+3)*FOLDH + c];
        #pragma unroll
        for (int pt = 0; pt < PTS; ++pt) {
            float4 xv = *(const float4*)&xin[pt][k0];
            acc[pt] += xv.x*wa + xv.y*wb + xv.z*wc + xv.w*wd;
        }
    }
    {
        float wa = w1[96*FOLDH + c], wb = w1[97*FOLDH + c], wc = w1[98*FOLDH + c];
        #pragma unroll
        for (int pt = 0; pt < PTS; ++pt) {
            float4 xv = *(const float4*)&xin[pt][96];
            acc[pt] += xv.x*wa + xv.y*wb + xv.z*wc;
        }
    }
    #pragma unroll
    for (int pt = 0; pt < PTS; ++pt) h1[pt][c] = frelu(acc[pt]);
    __syncthreads();
    #pragma unroll
    for (int pt = 0; pt < PTS; ++pt) acc[pt] = b2[c];
    for (int k0 = 0; k0 < FOLDH; k0 += 4) {
        float wa = w2[(k0+0)*FOLDH + c], wb = w2[(k0+1)*FOLDH + c];
        float wc = w2[(k0+2)*FOLDH + c], wd = w2[(k0+3)*FOLDH + c];
        #pragma unroll
        for (int pt = 0; pt < PTS; ++pt) {
            float4 hv = *(const float4*)&h1[pt][k0];
            acc[pt] += hv.x*wa + hv.y*wb + hv.z*wc + hv.w*wd;
        }
    }
    #pragma unroll
    for (int pt = 0; pt < PTS; ++pt) h2s[pt][c] = frelu(acc[pt]);
    __syncthreads();
    if (tid < PTS*3) {
        int pt = tid/3, cc = tid - pt*3;
        float a = b3[cc];
        for (int k0 = 0; k0 < FOLDH; k0 += 4) {
            float4 hv = *(const float4*)&h2s[pt][k0];
            a += hv.x*w3[(k0+0)*3+cc] + hv.y*w3[(k0+1)*3+cc] + hv.z*w3[(k0+2)*3+cc] + hv.w*w3[(k0+3)*3+cc];
        }
        int gi = base + pt;
        float res = xin[pt][cc] + a;
        xyz1[(size_t)gi*3 + cc] = res;
        oxyz[pt][cc] = res;
    }
    __syncthreads();
    if (tid < PTS) {
        float x = oxyz[tid][0], y = oxyz[tid][1], z = oxyz[tid][2];
        pts_out[base + tid] = make_float4(x, y, z, x*x + y*y + z*z);
    }
}

extern "C" void kernel_launch(void* const* d_in, const int* in_sizes, int n_in,
                              void* d_out, int out_size, void* d_ws, size_t ws_size,
                              hipStream_t stream) {
    const float* ctx_xyz    = (const float*)d_in[0];
    const float* ctx_tokens = (const float*)d_in[1];
    const float* pred_xyz   = (const float*)d_in[2];
    const float* noise      = (const float*)d_in[4];
    const float* c1w1 = (const float*)d_in[5];
    const float* c1b1 = (const float*)d_in[6];
    const float* c1w2 = (const float*)d_in[7];
    const float* c1b2 = (const float*)d_in[8];
    const float* c2w1 = (const float*)d_in[9];
    const float* c2b1 = (const float*)d_in[10];
    const float* c2w2 = (const float*)d_in[11];
    const float* c2b2 = (const float*)d_in[12];
    const float* cdw1 = (const float*)d_in[13];
    const float* cdb1 = (const float*)d_in[14];
    const float* cdw2 = (const float*)d_in[15];
    const float* cdb2 = (const float*)d_in[16];
    const float* fw1  = (const float*)d_in[17];
    const float* fb1  = (const float*)d_in[18];
    const float* fw2  = (const float*)d_in[19];
    const float* fb2  = (const float*)d_in[20];
    const float* fw3  = (const float*)d_in[21];
    const float* fb3  = (const float*)d_in[22];
    const float* rw1  = (const float*)d_in[23];
    const float* rb1  = (const float*)d_in[24];
    const float* rw2  = (const float*)d_in[25];
    const float* rb2  = (const float*)d_in[26];

    float* W = (float*)d_ws;
    // Zone A (staged aliasing): dist/distB (S1/S3) -> cfeat (S4) -> ur/vr (S8)
    float* dist  = W;                   // 2048*2048
    float* distB = W + 4194304;
    float* cfeat = W;                   // 2048*96 (after dist dead)
    float* ur    = W;                   // 8192*384 (after cfeat dead)
    float* vr    = W + 3145728;
    // Persistent zone:
    float* h_ctx = W + 8388608;         // 393,216
    float* h_tgt = h_ctx + 393216;
    float* UV    = h_tgt + 393216;      // [u1|v1] then [u2c|v2c|u2t|v2t]
    float* u1  = UV;            float* v1  = UV + 393216;
    float* u2c = UV;            float* v2c = UV + 196608;
    float* u2t = UV + 393216;   float* v2t = UV + 589824;
    float* tfeat = UV + 786432;         // 196,608
    float* xyz1  = tfeat + 196608;      // 24,576
    float4* pts  = (float4*)(xyz1 + 24576);
    float* sqb     = (float*)pts + 32768;
    float* sq_hctx = sqb + N2;
    float* sq_htgt = sq_hctx + N2;
    int* cidx1 = (int*)(sq_htgt + N2);
    int* cidx2 = cidx1 + N2*16;
    int* tidx2 = cidx2 + N2*8;
    int* ridx  = tidx2 + N2*2;

    float* out_ctx = (float*)d_out;
    float* out_tgt = out_ctx + N2*3;

    dim3 b16(16, 16);
    const int NTRI = 32*33/2;
    const float* NUL = nullptr;

    // --- S1: rowsq, dist(tokens), knn16 (tgt conv1 uses first 4 of cidx1)
    rowsq_kernel<<<N2/4, 256, 0, stream>>>(ctx_tokens, sqb, CDIM);
    dist64tri_kernel<<<NTRI, b16, 0, stream>>>(ctx_tokens, sqb, dist, N2, CDIM);
    knn_dist_rt_kernel<<<N2/4, 256, 0, stream>>>(dist, dist, N2, cidx1, cidx1, 16, 16, N2/4);

    // --- S2: u1/v1 GEMMs (16-row tiles, 768 blocks); conv1 fused; row-sq
    gemm16quad_kernel<<<dim3(3, 128, 2), b16, 0, stream>>>(
        ctx_tokens, c1w1, c1w1 + 384*192, c1b1, u1,
        ctx_tokens, c1w1 + 384*192, NUL, NUL, v1,
        ctx_tokens, c1w1, NUL, NUL, u1,   // unused (z<2)
        ctx_tokens, c1w1, NUL, NUL, v1,
        H1C, CDIM);
    edge_fused1_kernel<<<dim3(3, 512, 2), b16, 0, stream>>>(u1, v1, cidx1, c1w2, c1b2,
                                                            h_ctx, h_tgt, N2);
    rowsqpair_kernel<<<dim3(N2/4, 2), 256, 0, stream>>>(h_ctx, sq_hctx, h_tgt, sq_htgt, H1C);

    // --- S3: dist(h_ctx)+dist(h_tgt), paired knn, u2/v2 quad (16-row tiles)
    distpairtri_kernel<<<dim3(NTRI, 1, 2), b16, 0, stream>>>(h_ctx, sq_hctx, dist,
                                                             h_tgt, sq_htgt, distB, N2, H1C);
    knn_dist_rt_kernel<<<2*(N2/4), 256, 0, stream>>>(dist, distB, N2, cidx2, tidx2, 8, 2, N2/4);
    gemm16quad_kernel<<<dim3(2, 128, 4), b16, 0, stream>>>(
        h_ctx, c2w1, c2w1 + 192*96, c2b1, u2c,
        h_ctx, c2w1 + 192*96, NUL, NUL, v2c,
        h_tgt, c2w1, c2w1 + 192*96, c2b1, u2t,
        h_tgt, c2w1 + 192*96, NUL, NUL, v2t,
        H2C, H1C);

    // --- S4: conv2 fused gather-GEMM+reg-max; cdef head
    edge_fused2_kernel<<<dim3(2, 256, 2), b16, 0, stream>>>(u2c, v2c, u2t, v2t, cidx2, tidx2,
                                                            c2w2, c2b2, cfeat, tfeat, N2);
    cdef_kernel<<<N2, 128, 0, stream>>>(cfeat, cdw1, cdb1, cdw2, cdb2, ctx_xyz, out_ctx);

    // --- S6: folding MLP (fused upsample+noise; emits xyz1 + packed pts)
    fold_kernel<<<N8/16, 256, 0, stream>>>(pred_xyz, noise, tfeat, fw1, fb1, fw2, fb2, fw3, fb3, xyz1, pts);

    // --- S7: refiner knn (512 thr, 2 rows/wave, 16 rows/block)
    knn_xyz512_kernel<<<N8/16, 512, 0, stream>>>(pts, N8, ridx);

    // --- S8: refiner u/v gather-GEMMs, residual EdgeConv to output
    gatherpair_kernel<<<dim3(6, N8/64, 2), b16, 0, stream>>>(
        tfeat, xyz1,
        rw1, rw1 + 99*384, rb1, ur,
        rw1 + 99*384, NUL, NUL, vr,
        384, 99);
    edge_ref_kernel<<<N8/4, 256, 0, stream>>>(ur, vr, rw2, rb2, ridx, xyz1, out_tgt, N8);
}

// Round 16
// 420.151 us; speedup vs baseline: 1.1355x; 1.0418x over previous
//
#include <hip/hip_runtime.h>

#define N2 2048      // B*P
#define N8 8192      // B*P*UP
#define CDIM 384
#define H1C 192      // C/2
#define H2C 96       // C/4
#define PDIM 512
#define KRR 16
#define FOLDH 256
#define XCAP 256
#define XCAPX 128
#define XTILE 1024
#define INFF 3.0e38f

__device__ __forceinline__ float frelu(float x) { return x > 0.f ? x : 0.f; }

// ---------------- 64-lane bitonic sorts (ascending) --------------------------------
__device__ __forceinline__ void bitonic64_val(float& d, int lane) {
    #pragma unroll
    for (int k = 2; k <= 64; k <<= 1) {
        #pragma unroll
        for (int j = k >> 1; j > 0; j >>= 1) {
            float od = __shfl_xor(d, j);
            bool lower = (lane & j) == 0;
            bool olt = od < d;
            bool take = lower ? olt : !olt;
            if (lane & k) take = !take;
            if (take) d = od;
        }
    }
}

__device__ __forceinline__ void bitonic64_pair(float& d, int& c, int lane) {
    #pragma unroll
    for (int k = 2; k <= 64; k <<= 1) {
        #pragma unroll
        for (int j = k >> 1; j > 0; j >>= 1) {
            float od = __shfl_xor(d, j);
            int   oc = __shfl_xor(c, j);
            bool lower = (lane & j) == 0;
            bool olt = (od < d) || (od == d && oc < c);
            bool take = lower ? olt : !olt;
            if (lane & k) take = !take;
            if (take) { d = od; c = oc; }
        }
    }
}

// ---------------- slow exact select fallback (cnt > 64, rare) ----------------------
__device__ __forceinline__ void select_slow(const float* bd, const int* bi, int cnt,
                                            int ksel, int row, int n, int* out, int lane) {
    float cd[4]; int cix[4];
    #pragma unroll
    for (int s = 0; s < 4; ++s) {
        int c = lane + 64*s;
        bool v = c < cnt;
        cd[s]  = v ? bd[c] : INFF;
        cix[s] = v ? bi[c] : 0x7fffffff;
    }
    for (int r = 0; r < ksel; ++r) {
        float lv = cd[0]; int li = cix[0];
        #pragma unroll
        for (int s = 1; s < 4; ++s) {
            if (cd[s] < lv || (cd[s] == lv && cix[s] < li)) { lv = cd[s]; li = cix[s]; }
        }
        float wv = lv; int wi = li;
        #pragma unroll
        for (int s = 1; s < 64; s <<= 1) {
            float ov = __shfl_xor(wv, s); int oi = __shfl_xor(wi, s);
            if (ov < wv || (ov == wv && oi < wi)) { wv = ov; wi = oi; }
        }
        if (lane == 0) {
            int safe = ((unsigned)wi < (unsigned)n) ? wi : ((row + 1) & (n - 1));
            out[row*ksel + r] = safe;
        }
        #pragma unroll
        for (int s = 0; s < 4; ++s) {
            if (cd[s] == wv && cix[s] == wi) { cd[s] = INFF; cix[s] = 0x7fffffff; }
        }
    }
}

// ---------------- row squared norms (wave per row; single + paired) ----------------
__global__ __launch_bounds__(256) void rowsq_kernel(const float* __restrict__ x,
                                                    float* __restrict__ sq, int d) {
    int wave = threadIdx.x >> 6, lane = threadIdx.x & 63;
    int row = blockIdx.x*4 + wave;
    float acc = 0.f;
    for (int k = lane; k < d; k += 64) { float v = x[(size_t)row*d + k]; acc += v*v; }
    #pragma unroll
    for (int s = 1; s < 64; s <<= 1) acc += __shfl_xor(acc, s);
    if (lane == 0) sq[row] = acc;
}

__global__ __launch_bounds__(256) void rowsqpair_kernel(const float* __restrict__ xA,
                                                        float* __restrict__ sqA,
                                                        const float* __restrict__ xB,
                                                        float* __restrict__ sqB, int d) {
    const float* x = blockIdx.y ? xB : xA;
    float* sq = blockIdx.y ? sqB : sqA;
    int wave = threadIdx.x >> 6, lane = threadIdx.x & 63;
    int row = blockIdx.x*4 + wave;
    float acc = 0.f;
    for (int k = lane; k < d; k += 64) { float v = x[(size_t)row*d + k]; acc += v*v; }
    #pragma unroll
    for (int s = 1; s < 64; s <<= 1) acc += __shfl_xor(acc, s);
    if (lane == 0) sq[row] = acc;
}

// ---------------- triangular symmetric dist: direct + mirrored tile ----------------
__device__ __forceinline__ void disttri_body(const float* __restrict__ x, const float* __restrict__ sq,
                                             float* __restrict__ dist, int n, int K) {
    int l = blockIdx.x;
    int by = (int)((sqrtf(8.f*(float)l + 1.f) - 1.f)*0.5f);
    while ((by+1)*(by+2)/2 <= l) ++by;
    while (by*(by+1)/2 > l) --by;
    int bx = l - by*(by+1)/2;
    int row0 = by*64, col0 = bx*64;
    __shared__ __align__(16) float As[16][68];
    __shared__ __align__(16) float Bs[16][68];
    __shared__ __align__(16) float T[64][68];
    int tx = threadIdx.x, ty = threadIdx.y;
    int t = ty*16 + tx;
    float acc[4][4] = {};
    for (int k0 = 0; k0 < K; k0 += 16) {
        #pragma unroll
        for (int r = 0; r < 4; ++r) {
            int e = t + 256*r; int kk = e & 15, mm = e >> 4;
            As[kk][mm] = x[(size_t)(row0+mm)*K + k0+kk];
            Bs[kk][mm] = x[(size_t)(col0+mm)*K + k0+kk];
        }
        __syncthreads();
        #pragma unroll
        for (int kk = 0; kk < 16; ++kk) {
            float4 a4 = *(const float4*)&As[kk][ty*4];
            float4 b4 = *(const float4*)&Bs[kk][tx*4];
            acc[0][0] += a4.x*b4.x; acc[0][1] += a4.x*b4.y; acc[0][2] += a4.x*b4.z; acc[0][3] += a4.x*b4.w;
            acc[1][0] += a4.y*b4.x; acc[1][1] += a4.y*b4.y; acc[1][2] += a4.y*b4.z; acc[1][3] += a4.y*b4.w;
            acc[2][0] += a4.z*b4.x; acc[2][1] += a4.z*b4.y; acc[2][2] += a4.z*b4.z; acc[2][3] += a4.z*b4.w;
            acc[3][0] += a4.w*b4.x; acc[3][1] += a4.w*b4.y; acc[3][2] += a4.w*b4.z; acc[3][3] += a4.w*b4.w;
        }
        __syncthreads();
    }
    bool mirror = (row0 != col0);
    #pragma unroll
    for (int i2 = 0; i2 < 4; ++i2) {
        int row = row0 + ty*4 + i2;
        float sr = sq[row];
        float4 o;
        o.x = sr + sq[col0+tx*4+0] - 2.f*acc[i2][0];
        o.y = sr + sq[col0+tx*4+1] - 2.f*acc[i2][1];
        o.z = sr + sq[col0+tx*4+2] - 2.f*acc[i2][2];
        o.w = sr + sq[col0+tx*4+3] - 2.f*acc[i2][3];
        *(float4*)&dist[(size_t)row*n + col0 + tx*4] = o;
        if (mirror) {
            T[tx*4+0][ty*4+i2] = o.x;
            T[tx*4+1][ty*4+i2] = o.y;
            T[tx*4+2][ty*4+i2] = o.z;
            T[tx*4+3][ty*4+i2] = o.w;
        }
    }
    if (mirror) {
        __syncthreads();
        #pragma unroll
        for (int i2 = 0; i2 < 4; ++i2) {
            int orow = col0 + ty*4 + i2;
            float4 o = *(const float4*)&T[ty*4+i2][tx*4];
            *(float4*)&dist[(size_t)orow*n + row0 + tx*4] = o;
        }
    }
}

__global__ __launch_bounds__(256) void dist64tri_kernel(const float* __restrict__ x,
                                                        const float* __restrict__ sq,
                                                        float* __restrict__ dist, int n, int K) {
    disttri_body(x, sq, dist, n, K);
}

__global__ __launch_bounds__(256) void distpairtri_kernel(const float* __restrict__ xA,
                                                          const float* __restrict__ sqA,
                                                          float* __restrict__ dA,
                                                          const float* __restrict__ xB,
                                                          const float* __restrict__ sqB,
                                                          float* __restrict__ dB, int n, int K) {
    const float* x  = blockIdx.z ? xB : xA;
    const float* sq = blockIdx.z ? sqB : sqA;
    float* dist     = blockIdx.z ? dB : dA;
    disttri_body(x, sq, dist, n, K);
}

// ---------------- 16x64 GEMM tile (high block count for small GEMMs) ---------------
__device__ __forceinline__ void gemm16_body(const float* __restrict__ A, const float* __restrict__ Bw,
                                            const float* __restrict__ BwB, const float* __restrict__ bias,
                                            float* __restrict__ C, int m, int K) {
    __shared__ __align__(16) float As[16][17];
    __shared__ __align__(16) float Bs[16][68];
    int tx = threadIdx.x, ty = threadIdx.y;
    int t = ty*16 + tx;
    int row0 = blockIdx.y*16, col0 = blockIdx.x*64;
    float acc[4] = {};
    for (int k0 = 0; k0 < K; k0 += 16) {
        {
            int kk = t & 15, mm = t >> 4;
            As[kk][mm] = (k0 + kk < K) ? A[(size_t)(row0+mm)*K + k0+kk] : 0.f;
        }
        #pragma unroll
        for (int r = 0; r < 4; ++r) {
            int e = t + 256*r; int nn = e & 63, kk = e >> 6;
            int col = col0 + nn, k = k0 + kk;
            float bv = 0.f;
            if (k < K && col < m) {
                bv = Bw[(size_t)k*m + col];
                if (BwB) bv -= BwB[(size_t)k*m + col];
            }
            Bs[kk][nn] = bv;
        }
        __syncthreads();
        #pragma unroll
        for (int kk = 0; kk < 16; ++kk) {
            float a = As[kk][ty];
            float4 b4 = *(const float4*)&Bs[kk][tx*4];
            acc[0] += a*b4.x; acc[1] += a*b4.y; acc[2] += a*b4.z; acc[3] += a*b4.w;
        }
        __syncthreads();
    }
    int row = row0 + ty;
    #pragma unroll
    for (int j2 = 0; j2 < 4; ++j2) {
        int col = col0 + tx*4 + j2;
        if (col < m) C[(size_t)row*m + col] = acc[j2] + (bias ? bias[col] : 0.f);
    }
}

__global__ __launch_bounds__(256) void gemm16quad_kernel(
    const float* A0, const float* Bw0, const float* BwB0, const float* bias0, float* C0,
    const float* A1, const float* Bw1, const float* BwB1, const float* bias1, float* C1,
    const float* A2, const float* Bw2, const float* BwB2, const float* bias2, float* C2,
    const float* A3, const float* Bw3, const float* BwB3, const float* bias3, float* C3,
    int m, int K) {
    int z = blockIdx.z;
    const float* A    = (z==0)?A0 :(z==1)?A1 :(z==2)?A2 :A3;
    const float* Bw   = (z==0)?Bw0:(z==1)?Bw1:(z==2)?Bw2:Bw3;
    const float* BwB  = (z==0)?BwB0:(z==1)?BwB1:(z==2)?BwB2:BwB3;
    const float* bias = (z==0)?bias0:(z==1)?bias1:(z==2)?bias2:bias3;
    float* C          = (z==0)?C0 :(z==1)?C1 :(z==2)?C2 :C3;
    gemm16_body(A, Bw, BwB, bias, C, m, K);
}

// ---------------- EdgeConv layer-2 gather-GEMM, reg-max, coalesced fill ------------
template<int EPT, int SELF, int EREAL, int IDXS, int YT>
__device__ __forceinline__ void edge_fused_body(const float* __restrict__ u, const float* __restrict__ v,
                                                const int* __restrict__ idx,
                                                const float* __restrict__ Bw, const float* __restrict__ bias,
                                                float* __restrict__ hout, int m, int K, int npts) {
    if ((int)blockIdx.y >= YT) return;
    constexpr int LOG2EPT = (EPT == 16) ? 4 : (EPT == 8) ? 3 : 2;
    __shared__ __align__(16) float As[16][68];
    __shared__ __align__(16) float Bs[16][68];
    int tx = threadIdx.x, ty = threadIdx.y;
    int t = ty*16 + tx;
    int row0 = blockIdx.y*64, col0 = blockIdx.x*64;
    int mmA = t >> 2;
    int kqA = (t & 3) * 4;
    int rowA = row0 + mmA;
    int iA = rowA >> LOG2EPT;
    int eA = rowA - (iA << LOG2EPT);
    int jA;
    if (SELF && eA == 0) jA = iA;
    else if (eA < EREAL) jA = idx[iA*IDXS + (eA - SELF)];
    else jA = iA;
    jA = ((unsigned)jA < (unsigned)npts) ? jA : iA;
    const float* uRow = u + (size_t)iA*K + kqA;
    const float* vRow = v + (size_t)jA*K + kqA;
    int nnB = (t & 15) * 4, kkB = t >> 4;
    float acc[4][4] = {};
    for (int k0 = 0; k0 < K; k0 += 16) {
        float4 u4 = *(const float4*)(uRow + k0);
        float4 v4 = *(const float4*)(vRow + k0);
        As[kqA+0][mmA] = frelu(u4.x + v4.x);
        As[kqA+1][mmA] = frelu(u4.y + v4.y);
        As[kqA+2][mmA] = frelu(u4.z + v4.z);
        As[kqA+3][mmA] = frelu(u4.w + v4.w);
        int colB = col0 + nnB;
        if (colB + 3 < m) {
            *(float4*)&Bs[kkB][nnB] = *(const float4*)&Bw[(size_t)(k0+kkB)*m + colB];
        } else {
            #pragma unroll
            for (int q = 0; q < 4; ++q) {
                int col = colB + q;
                Bs[kkB][nnB+q] = (col < m) ? Bw[(size_t)(k0+kkB)*m + col] : 0.f;
            }
        }
        __syncthreads();
        #pragma unroll
        for (int kk = 0; kk < 16; ++kk) {
            float4 a4 = *(const float4*)&As[kk][ty*4];
            float4 b4 = *(const float4*)&Bs[kk][tx*4];
            acc[0][0] += a4.x*b4.x; acc[0][1] += a4.x*b4.y; acc[0][2] += a4.x*b4.z; acc[0][3] += a4.x*b4.w;
            acc[1][0] += a4.y*b4.x; acc[1][1] += a4.y*b4.y; acc[1][2] += a4.y*b4.z; acc[1][3] += a4.y*b4.w;
            acc[2][0] += a4.z*b4.x; acc[2][1] += a4.z*b4.y; acc[2][2] += a4.z*b4.z; acc[2][3] += a4.z*b4.w;
            acc[3][0] += a4.w*b4.x; acc[3][1] += a4.w*b4.y; acc[3][2] += a4.w*b4.z; acc[3][3] += a4.w*b4.w;
        }
        __syncthreads();
    }
    float bestv[4];
    #pragma unroll
    for (int j2 = 0; j2 < 4; ++j2)
        bestv[j2] = fmaxf(fmaxf(acc[0][j2], acc[1][j2]), fmaxf(acc[2][j2], acc[3][j2]));
    if (EPT >= 8) {
        #pragma unroll
        for (int j2 = 0; j2 < 4; ++j2) bestv[j2] = fmaxf(bestv[j2], __shfl_xor(bestv[j2], 16));
    }
    if (EPT == 16) {
        #pragma unroll
        for (int j2 = 0; j2 < 4; ++j2) bestv[j2] = fmaxf(bestv[j2], __shfl_xor(bestv[j2], 32));
    }
    bool writer; int p;
    if (EPT == 16) { writer = (ty & 3) == 0; p = (row0 >> 4) + (ty >> 2); }
    else if (EPT == 8) { writer = (ty & 1) == 0; p = (row0 >> 3) + (ty >> 1); }
    else { writer = true; p = (row0 >> 2) + ty; }
    if (writer) {
        #pragma unroll
        for (int j2 = 0; j2 < 4; ++j2) {
            int col = col0 + tx*4 + j2;
            if (col < m) hout[(size_t)p*m + col] = bestv[j2] + bias[col];
        }
    }
}

__global__ __launch_bounds__(256) void edge_fused1_kernel(const float* u1, const float* v1,
                                                          const int* cidx1,
                                                          const float* Bw, const float* bias,
                                                          float* h_ctx, float* h_tgt, int npts) {
    if (blockIdx.z == 0) edge_fused_body<16,0,16,16,512>(u1, v1, cidx1, Bw, bias, h_ctx, H1C, H1C, npts);
    else                 edge_fused_body<8,1,5,16,256>(u1, v1, cidx1, Bw, bias, h_tgt, H1C, H1C, npts);
}

__global__ __launch_bounds__(256) void edge_fused2_kernel(const float* u2c, const float* v2c,
                                                          const float* u2t, const float* v2t,
                                                          const int* cidx2, const int* tidx2,
                                                          const float* Bw, const float* bias,
                                                          float* cfeat, float* tfeat, int npts) {
    if (blockIdx.z == 0) edge_fused_body<8,0,8,8,256>(u2c, v2c, cidx2, Bw, bias, cfeat, H2C, H2C, npts);
    else                 edge_fused_body<4,1,3,2,128>(u2t, v2t, tidx2, Bw, bias, tfeat, H2C, H2C, npts);
}

// ---------------- ctx deform head: out = xyz + 0.05 * mlp2(cfeat) ------------------
__global__ __launch_bounds__(128) void cdef_kernel(const float* __restrict__ cfeat,
                                                   const float* __restrict__ cdw1, const float* __restrict__ cdb1,
                                                   const float* __restrict__ cdw2, const float* __restrict__ cdb2,
                                                   const float* __restrict__ ctx_xyz,
                                                   float* __restrict__ out_ctx) {
    int i = blockIdx.x, tid = threadIdx.x, wave = tid >> 6, lane = tid & 63;
    __shared__ float sf_[96], st2_[96];
    if (tid < 96) sf_[tid] = cfeat[(size_t)i*H2C + tid];
    __syncthreads();
    if (tid < 96) {
        float a = cdb1[tid];
        for (int k = 0; k < 96; ++k) a += sf_[k]*cdw1[k*96 + tid];
        st2_[tid] = frelu(a);
    }
    __syncthreads();
    if (wave == 0) {
        float s0 = st2_[lane];
        float p0 = s0*cdw2[lane*3+0], p1 = s0*cdw2[lane*3+1], p2 = s0*cdw2[lane*3+2];
        if (lane < 32) {
            float s1 = st2_[lane+64];
            p0 += s1*cdw2[(lane+64)*3+0];
            p1 += s1*cdw2[(lane+64)*3+1];
            p2 += s1*cdw2[(lane+64)*3+2];
        }
        #pragma unroll
        for (int s = 1; s < 64; s <<= 1) {
            p0 += __shfl_xor(p0, s); p1 += __shfl_xor(p1, s); p2 += __shfl_xor(p2, s);
        }
        if (lane == 0) {
            out_ctx[i*3+0] = ctx_xyz[i*3+0] + 0.05f*(cdb2[0] + p0);
            out_ctx[i*3+1] = ctx_xyz[i*3+1] + 0.05f*(cdb2[1] + p1);
            out_ctx[i*3+2] = ctx_xyz[i*3+2] + 0.05f*(cdb2[2] + p2);
        }
    }
}

// refiner gather-GEMM pair: A row gathered from [featd(96) | xyzg(3)], K = 99
__global__ __launch_bounds__(256) void gatherpair_kernel(
    const float* __restrict__ featd, const float* __restrict__ xyzg,
    const float* Bw0, const float* BwB0, const float* bias0, float* C0,
    const float* Bw1, const float* BwB1, const float* bias1, float* C1,
    int m, int K) {
    int z = blockIdx.z;
    const float* Bw   = z ? Bw1 : Bw0;
    const float* BwB  = z ? BwB1 : BwB0;
    const float* bias = z ? bias1 : bias0;
    float* C          = z ? C1 : C0;
    __shared__ __align__(16) float As[16][68];
    __shared__ __align__(16) float Bs[16][68];
    int tx = threadIdx.x, ty = threadIdx.y;
    int t = ty*16 + tx;
    int row0 = blockIdx.y*64, col0 = blockIdx.x*64;
    float acc[4][4] = {};
    for (int k0 = 0; k0 < K; k0 += 16) {
        #pragma unroll
        for (int r = 0; r < 4; ++r) {
            int e = t + 256*r; int kk = e & 15, mm = e >> 4;
            int k = k0 + kk, grow = row0 + mm;
            float av = 0.f;
            if (k < K) {
                if (k < 96) { int b = grow >> 11, p = (grow & 2047) >> 2;
                              av = featd[(size_t)(b*PDIM + p)*H2C + k]; }
                else av = xyzg[(size_t)grow*3 + (k - 96)];
            }
            As[kk][mm] = av;
        }
        #pragma unroll
        for (int r = 0; r < 4; ++r) {
            int e = t + 256*r; int nn = e & 63, kk = e >> 6;
            int col = col0 + nn, k = k0 + kk;
            float bv = 0.f;
            if (k < K && col < m) {
                bv = Bw[(size_t)k*m + col];
                if (BwB) bv -= BwB[(size_t)k*m + col];
            }
            Bs[kk][nn] = bv;
        }
        __syncthreads();
        #pragma unroll
        for (int kk = 0; kk < 16; ++kk) {
            float4 a4 = *(const float4*)&As[kk][ty*4];
            float4 b4 = *(const float4*)&Bs[kk][tx*4];
            acc[0][0] += a4.x*b4.x; acc[0][1] += a4.x*b4.y; acc[0][2] += a4.x*b4.z; acc[0][3] += a4.x*b4.w;
            acc[1][0] += a4.y*b4.x; acc[1][1] += a4.y*b4.y; acc[1][2] += a4.y*b4.z; acc[1][3] += a4.y*b4.w;
            acc[2][0] += a4.z*b4.x; acc[2][1] += a4.z*b4.y; acc[2][2] += a4.z*b4.z; acc[2][3] += a4.z*b4.w;
            acc[3][0] += a4.w*b4.x; acc[3][1] += a4.w*b4.y; acc[3][2] += a4.w*b4.z; acc[3][3] += a4.w*b4.w;
        }
        __syncthreads();
    }
    #pragma unroll
    for (int i2 = 0; i2 < 4; ++i2) {
        int row = row0 + ty*4 + i2;
        #pragma unroll
        for (int j2 = 0; j2 < 4; ++j2) {
            int col = col0 + tx*4 + j2;
            if (col < m) C[(size_t)row*m + col] = acc[i2][j2] + (bias ? bias[col] : 0.f);
        }
    }
}

// ---------------- knn from dist rows (4 rows/block, bitonic select) ----------------
__global__ __launch_bounds__(256) void knn_dist_rt_kernel(const float* __restrict__ dA,
                                                          const float* __restrict__ dB, int n,
                                                          int* __restrict__ outA, int* __restrict__ outB,
                                                          int kA, int kB, int nblkA) {
    int wave = threadIdx.x >> 6, lane = threadIdx.x & 63;
    bool useB = (int)blockIdx.x >= nblkA;
    const float* dist = useB ? dB : dA;
    int* out = useB ? outB : outA;
    int ksel = useB ? kB : kA;
    int bx = useB ? (int)blockIdx.x - nblkA : (int)blockIdx.x;
    int row = bx*4 + wave;
    __shared__ float bufd[4][XCAP];
    __shared__ int   bufi[4][XCAP];
    __shared__ int   lcnt[4];
    const float4* drow = (const float4*)(dist + (size_t)row*n);
    int nq = n >> 2;
    float mv = INFF;
    for (int i = lane; i < nq; i += 64) {
        float4 d4 = drow[i]; int base = i*4;
        float a = (base+0 == row) ? INFF : d4.x;
        float b = (base+1 == row) ? INFF : d4.y;
        float c = (base+2 == row) ? INFF : d4.z;
        float d = (base+3 == row) ? INFF : d4.w;
        mv = fminf(mv, fminf(fminf(a,b), fminf(c,d)));
    }
    float sd = mv;
    bitonic64_val(sd, lane);
    float Tv = __shfl(sd, ksel - 1);
    if (lane == 0) lcnt[wave] = 0;
    for (int i = lane; i < nq; i += 64) {
        float4 d4 = drow[i]; int base = i*4;
        float dv4[4] = {d4.x, d4.y, d4.z, d4.w};
        #pragma unroll
        for (int q = 0; q < 4; ++q) {
            int col = base + q;
            if (col != row && dv4[q] <= Tv) {
                int pos = atomicAdd(&lcnt[wave], 1);
                if (pos < XCAP) { bufd[wave][pos] = dv4[q]; bufi[wave][pos] = col; }
            }
        }
    }
    int cnt = lcnt[wave]; if (cnt > XCAP) cnt = XCAP;
    if (cnt <= 64) {
        float d = (lane < cnt) ? bufd[wave][lane] : INFF;
        int   c = (lane < cnt) ? bufi[wave][lane] : 0x7fffffff;
        bitonic64_pair(d, c, lane);
        if (lane < ksel) {
            int safe = ((unsigned)c < (unsigned)n) ? c : ((row + 1) & (n - 1));
            out[row*ksel + lane] = safe;
        }
    } else {
        select_slow(bufd[wave], bufi[wave], cnt, ksel, row, n, out, lane);
    }
}

// ---------------- knn over packed xyz: 16 rows/block, 512 thr, 2 rows/wave ---------
// Phase A: no self-check (self d~0 may enter lane minima); threshold = 17th smallest
// of lane minima (>= 16th of legit minima >= true 16th distance -> superset collect).
// d computed with identical fmaf expression in both phases.
__global__ __launch_bounds__(512) void knn_xyz512_kernel(const float4* __restrict__ pts, int n,
                                                         int* __restrict__ out_idx) {
    int tid = threadIdx.x, wave = tid >> 6, lane = tid & 63;
    int rbase = blockIdx.x*16 + wave*2;
    __shared__ __align__(16) float4 tile[XTILE];
    __shared__ float bufd[16][XCAPX];
    __shared__ int   bufi[16][XCAPX];
    __shared__ int   lcnt[16];
    float4 P0 = pts[rbase], P1 = pts[rbase+1];
    float nx0 = -2.f*P0.x, ny0 = -2.f*P0.y, nz0 = -2.f*P0.z, sr0 = P0.w;
    float nx1 = -2.f*P1.x, ny1 = -2.f*P1.y, nz1 = -2.f*P1.z, sr1 = P1.w;
    float mv0 = INFF, mv1 = INFF;
    for (int t0 = 0; t0 < n; t0 += XTILE) {
        __syncthreads();
        #pragma unroll
        for (int k = 0; k < XTILE/512; ++k) tile[tid + 512*k] = pts[t0 + tid + 512*k];
        __syncthreads();
        for (int c = lane; c < XTILE; c += 64) {
            float4 q = tile[c];
            float d0 = fmaf(nx0, q.x, fmaf(ny0, q.y, fmaf(nz0, q.z, sr0 + q.w)));
            float d1 = fmaf(nx1, q.x, fmaf(ny1, q.y, fmaf(nz1, q.z, sr1 + q.w)));
            mv0 = fminf(mv0, d0);
            mv1 = fminf(mv1, d1);
        }
    }
    bitonic64_val(mv0, lane);
    bitonic64_val(mv1, lane);
    float Tv0 = __shfl(mv0, 16), Tv1 = __shfl(mv1, 16);   // 17th smallest (self-safe)
    if (lane < 2) lcnt[wave*2 + lane] = 0;
    for (int t0 = 0; t0 < n; t0 += XTILE) {
        __syncthreads();
        #pragma unroll
        for (int k = 0; k < XTILE/512; ++k) tile[tid + 512*k] = pts[t0 + tid + 512*k];
        __syncthreads();
        for (int c = lane; c < XTILE; c += 64) {
            float4 q = tile[c];
            int col = t0 + c;
            float d0 = fmaf(nx0, q.x, fmaf(ny0, q.y, fmaf(nz0, q.z, sr0 + q.w)));
            float d1 = fmaf(nx1, q.x, fmaf(ny1, q.y, fmaf(nz1, q.z, sr1 + q.w)));
            if (col != rbase && d0 <= Tv0) {
                int pos = atomicAdd(&lcnt[wave*2+0], 1);
                if (pos < XCAPX) { bufd[wave*2+0][pos] = d0; bufi[wave*2+0][pos] = col; }
            }
            if (col != rbase+1 && d1 <= Tv1) {
                int pos = atomicAdd(&lcnt[wave*2+1], 1);
                if (pos < XCAPX) { bufd[wave*2+1][pos] = d1; bufi[wave*2+1][pos] = col; }
            }
        }
    }
    for (int jj = 0; jj < 2; ++jj) {
        int brow = wave*2 + jj, row = rbase + jj;
        int cnt = lcnt[brow]; if (cnt > XCAPX) cnt = XCAPX;
        if (cnt <= 64) {
            float d = (lane < cnt) ? bufd[brow][lane] : INFF;
            int   c = (lane < cnt) ? bufi[brow][lane] : 0x7fffffff;
            bitonic64_pair(d, c, lane);
            if (lane < 16) {
                int safe = ((unsigned)c < (unsigned)n) ? c : ((row + 1) & (n - 1));
                out_idx[row*16 + lane] = safe;
            }
        } else {
            float cd[2]; int cix[2];
            #pragma unroll
            for (int s = 0; s < 2; ++s) {
                int c = lane + 64*s;
                bool v = c < cnt;
                cd[s]  = v ? bufd[brow][c] : INFF;
                cix[s] = v ? bufi[brow][c] : 0x7fffffff;
            }
            for (int r = 0; r < 16; ++r) {
                float lv = cd[0]; int li = cix[0];
                if (cd[1] < lv || (cd[1] == lv && cix[1] < li)) { lv = cd[1]; li = cix[1]; }
                float wv = lv; int wi = li;
                #pragma unroll
                for (int s = 1; s < 64; s <<= 1) {
                    float ov = __shfl_xor(wv, s); int oi = __shfl_xor(wi, s);
                    if (ov < wv || (ov == wv && oi < wi)) { wv = ov; wi = oi; }
                }
                if (lane == 0) {
                    int safe = ((unsigned)wi < (unsigned)n) ? wi : ((row + 1) & (n - 1));
                    out_idx[row*16 + r] = safe;
                }
                #pragma unroll
                for (int s = 0; s < 2; ++s) {
                    if (cd[s] == wv && cix[s] == wi) { cd[s] = INFF; cix[s] = 0x7fffffff; }
                }
            }
        }
    }
}

// ---------------- refiner EdgeConv (H1=384, H2=3), wave per point ------------------
__global__ __launch_bounds__(256) void edge_ref_kernel(const float* __restrict__ ur,
                                                       const float* __restrict__ vr,
                                                       const float* __restrict__ w2,
                                                       const float* __restrict__ b2,
                                                       const int* __restrict__ idx,
                                                       const float* __restrict__ xyz_in,
                                                       float* __restrict__ out, int n) {
    int wave = threadIdx.x >> 6, lane = threadIdx.x & 63;
    int i = blockIdx.x*4 + wave;
    if (i >= n) return;
    float m0 = -INFF, m1 = -INFF, m2 = -INFF;
    float uh[6];
    #pragma unroll
    for (int t = 0; t < 6; ++t) uh[t] = ur[(size_t)i*384 + lane + 64*t];
    for (int e = 0; e < KRR; ++e) {
        int j = idx[i*KRR + e];
        j = ((unsigned)j < (unsigned)n) ? j : i;
        float a0 = 0.f, a1 = 0.f, a2 = 0.f;
        #pragma unroll
        for (int t = 0; t < 6; ++t) {
            int h = lane + 64*t;
            float tv = frelu(uh[t] + vr[(size_t)j*384 + h]);
            a0 += tv*w2[h*3+0]; a1 += tv*w2[h*3+1]; a2 += tv*w2[h*3+2];
        }
        #pragma unroll
        for (int s = 32; s > 0; s >>= 1) {
            a0 += __shfl_xor(a0, s); a1 += __shfl_xor(a1, s); a2 += __shfl_xor(a2, s);
        }
        m0 = fmaxf(m0, a0 + b2[0]); m1 = fmaxf(m1, a1 + b2[1]); m2 = fmaxf(m2, a2 + b2[2]);
    }
    if (lane == 0) {
        out[i*3+0] = xyz_in[i*3+0] + m0;
        out[i*3+1] = xyz_in[i*3+1] + m1;
        out[i*3+2] = xyz_in[i*3+2] + m2;
    }
}

// ---------------- folding MLP, fused upsample+noise in, xyz1 + packed pts out ------
__global__ __launch_bounds__(256) void fold_kernel(const float* __restrict__ pred_xyz,
                                                   const float* __restrict__ noise,
                                                   const float* __restrict__ featd,
                                                   const float* __restrict__ w1, const float* __restrict__ b1,
                                                   const float* __restrict__ w2, const float* __restrict__ b2,
                                                   const float* __restrict__ w3, const float* __restrict__ b3,
                                                   float* __restrict__ xyz1, float4* __restrict__ pts_out) {
    const int PTS = 16;
    int base = blockIdx.x * PTS;
    int tid = threadIdx.x;
    __shared__ __align__(16) float xin[PTS][100];
    __shared__ __align__(16) float h1[PTS][FOLDH];
    __shared__ __align__(16) float h2s[PTS][FOLDH];
    __shared__ float oxyz[PTS][3];
    for (int t = tid; t < PTS*100; t += 256) {
        int pt = t/100, k = t - pt*100;
        int gi = base + pt;
        float vv = 0.f;
        if (k < 3) {
            int b = gi >> 11, p = (gi & 2047) >> 2;
            vv = pred_xyz[(size_t)(b*PDIM + p)*3 + k] + 0.02f*noise[(size_t)gi*3 + k];
        } else if (k < 99) {
            int b = gi >> 11, p = (gi & 2047) >> 2;
            vv = featd[(size_t)(b*PDIM + p)*H2C + (k - 3)];
        }
        xin[pt][k] = vv;
    }
    __syncthreads();
    int c = tid;
    float acc[PTS];
    #pragma unroll
    for (int pt = 0; pt < PTS; ++pt) acc[pt] = b1[c];
    for (int k0 = 0; k0 < 96; k0 += 4) {
        float wa = w1[(k0+0)*FOLDH + c], wb = w1[(k0+1)*FOLDH + c];
        float wc = w1[(k0+2)*FOLDH + c], wd = w1[(k0+3)*FOLDH + c];
        #pragma unroll
        for (int pt = 0; pt < PTS; ++pt) {
            float4 xv = *(const float4*)&xin[pt][k0];
            acc[pt] += xv.x*wa + xv.y*wb + xv.z*wc + xv.w*wd;
        }
    }
    {
        float wa = w1[96*FOLDH + c], wb = w1[97*FOLDH + c], wc = w1[98*FOLDH + c];
        #pragma unroll
        for (int pt = 0; pt < PTS; ++pt) {
            float4 xv = *(const float4*)&xin[pt][96];
            acc[pt] += xv.x*wa + xv.y*wb + xv.z*wc;
        }
    }
    #pragma unroll
    for (int pt = 0; pt < PTS; ++pt) h1[pt][c] = frelu(acc[pt]);
    __syncthreads();
    #pragma unroll
    for (int pt = 0; pt < PTS; ++pt) acc[pt] = b2[c];
    for (int k0 = 0; k0 < FOLDH; k0 += 4) {
        float wa = w2[(k0+0)*FOLDH + c], wb = w2[(k0+1)*FOLDH + c];
        float wc = w2[(k0+2)*FOLDH + c], wd = w2[(k0+3)*FOLDH + c];
        #pragma unroll
        for (int pt = 0; pt < PTS; ++pt) {
            float4 hv = *(const float4*)&h1[pt][k0];
            acc[pt] += hv.x*wa + hv.y*wb + hv.z*wc + hv.w*wd;
        }
    }
    #pragma unroll
    for (int pt = 0; pt < PTS; ++pt) h2s[pt][c] = frelu(acc[pt]);
    __syncthreads();
    if (tid < PTS*3) {
        int pt = tid/3, cc = tid - pt*3;
        float a = b3[cc];
        for (int k0 = 0; k0 < FOLDH; k0 += 4) {
            float4 hv = *(const float4*)&h2s[pt][k0];
            a += hv.x*w3[(k0+0)*3+cc] + hv.y*w3[(k0+1)*3+cc] + hv.z*w3[(k0+2)*3+cc] + hv.w*w3[(k0+3)*3+cc];
        }
        int gi = base + pt;
        float res = xin[pt][cc] + a;
        xyz1[(size_t)gi*3 + cc] = res;
        oxyz[pt][cc] = res;
    }
    __syncthreads();
    if (tid < PTS) {
        float x = oxyz[tid][0], y = oxyz[tid][1], z = oxyz[tid][2];
        pts_out[base + tid] = make_float4(x, y, z, x*x + y*y + z*z);
    }
}

extern "C" void kernel_launch(void* const* d_in, const int* in_sizes, int n_in,
                              void* d_out, int out_size, void* d_ws, size_t ws_size,
                              hipStream_t stream) {
    const float* ctx_xyz    = (const float*)d_in[0];
    const float* ctx_tokens = (const float*)d_in[1];
    const float* pred_xyz   = (const float*)d_in[2];
    const float* noise      = (const float*)d_in[4];
    const float* c1w1 = (const float*)d_in[5];
    const float* c1b1 = (const float*)d_in[6];
    const float* c1w2 = (const float*)d_in[7];
    const float* c1b2 = (const float*)d_in[8];
    const float* c2w1 = (const float*)d_in[9];
    const float* c2b1 = (const float*)d_in[10];
    const float* c2w2 = (const float*)d_in[11];
    const float* c2b2 = (const float*)d_in[12];
    const float* cdw1 = (const float*)d_in[13];
    const float* cdb1 = (const float*)d_in[14];
    const float* cdw2 = (const float*)d_in[15];
    const float* cdb2 = (const float*)d_in[16];
    const float* fw1  = (const float*)d_in[17];
    const float* fb1  = (const float*)d_in[18];
    const float* fw2  = (const float*)d_in[19];
    const float* fb2  = (const float*)d_in[20];
    const float* fw3  = (const float*)d_in[21];
    const float* fb3  = (const float*)d_in[22];
    const float* rw1  = (const float*)d_in[23];
    const float* rb1  = (const float*)d_in[24];
    const float* rw2  = (const float*)d_in[25];
    const float* rb2  = (const float*)d_in[26];

    float* W = (float*)d_ws;
    // Zone A (staged aliasing): dist/distB (S1/S3) -> cfeat (S4) -> ur/vr (S8)
    float* dist  = W;                   // 2048*2048
    float* distB = W + 4194304;
    float* cfeat = W;                   // 2048*96 (after dist dead)
    float* ur    = W;                   // 8192*384 (after cfeat dead)
    float* vr    = W + 3145728;
    // Persistent zone:
    float* h_ctx = W + 8388608;         // 393,216
    float* h_tgt = h_ctx + 393216;
    float* UV    = h_tgt + 393216;      // [u1|v1] then [u2c|v2c|u2t|v2t]
    float* u1  = UV;            float* v1  = UV + 393216;
    float* u2c = UV;            float* v2c = UV + 196608;
    float* u2t = UV + 393216;   float* v2t = UV + 589824;
    float* tfeat = UV + 786432;         // 196,608
    float* xyz1  = tfeat + 196608;      // 24,576
    float4* pts  = (float4*)(xyz1 + 24576);
    float* sqb     = (float*)pts + 32768;
    float* sq_hctx = sqb + N2;
    float* sq_htgt = sq_hctx + N2;
    int* cidx1 = (int*)(sq_htgt + N2);
    int* cidx2 = cidx1 + N2*16;
    int* tidx2 = cidx2 + N2*8;
    int* ridx  = tidx2 + N2*2;

    float* out_ctx = (float*)d_out;
    float* out_tgt = out_ctx + N2*3;

    dim3 b16(16, 16);
    const int NTRI = 32*33/2;
    const float* NUL = nullptr;

    // --- S1: rowsq, dist(tokens), knn16 (tgt conv1 uses first 4 of cidx1)
    rowsq_kernel<<<N2/4, 256, 0, stream>>>(ctx_tokens, sqb, CDIM);
    dist64tri_kernel<<<NTRI, b16, 0, stream>>>(ctx_tokens, sqb, dist, N2, CDIM);
    knn_dist_rt_kernel<<<N2/4, 256, 0, stream>>>(dist, dist, N2, cidx1, cidx1, 16, 16, N2/4);

    // --- S2: u1/v1 GEMMs (16-row tiles); conv1 fused; row-sq
    gemm16quad_kernel<<<dim3(3, 128, 2), b16, 0, stream>>>(
        ctx_tokens, c1w1, c1w1 + 384*192, c1b1, u1,
        ctx_tokens, c1w1 + 384*192, NUL, NUL, v1,
        ctx_tokens, c1w1, NUL, NUL, u1,   // unused (z<2)
        ctx_tokens, c1w1, NUL, NUL, v1,
        H1C, CDIM);
    edge_fused1_kernel<<<dim3(3, 512, 2), b16, 0, stream>>>(u1, v1, cidx1, c1w2, c1b2,
                                                            h_ctx, h_tgt, N2);
    rowsqpair_kernel<<<dim3(N2/4, 2), 256, 0, stream>>>(h_ctx, sq_hctx, h_tgt, sq_htgt, H1C);

    // --- S3: dist(h_ctx)+dist(h_tgt), paired knn, u2/v2 quad (16-row tiles)
    distpairtri_kernel<<<dim3(NTRI, 1, 2), b16, 0, stream>>>(h_ctx, sq_hctx, dist,
                                                             h_tgt, sq_htgt, distB, N2, H1C);
    knn_dist_rt_kernel<<<2*(N2/4), 256, 0, stream>>>(dist, distB, N2, cidx2, tidx2, 8, 2, N2/4);
    gemm16quad_kernel<<<dim3(2, 128, 4), b16, 0, stream>>>(
        h_ctx, c2w1, c2w1 + 192*96, c2b1, u2c,
        h_ctx, c2w1 + 192*96, NUL, NUL, v2c,
        h_tgt, c2w1, c2w1 + 192*96, c2b1, u2t,
        h_tgt, c2w1 + 192*96, NUL, NUL, v2t,
        H2C, H1C);

    // --- S4: conv2 fused gather-GEMM+reg-max; cdef head
    edge_fused2_kernel<<<dim3(2, 256, 2), b16, 0, stream>>>(u2c, v2c, u2t, v2t, cidx2, tidx2,
                                                            c2w2, c2b2, cfeat, tfeat, N2);
    cdef_kernel<<<N2, 128, 0, stream>>>(cfeat, cdw1, cdb1, cdw2, cdb2, ctx_xyz, out_ctx);

    // --- S6: folding MLP (fused upsample+noise; emits xyz1 + packed pts)
    fold_kernel<<<N8/16, 256, 0, stream>>>(pred_xyz, noise, tfeat, fw1, fb1, fw2, fb2, fw3, fb3, xyz1, pts);

    // --- S7: refiner knn (512 thr, 2 rows/wave, fmaf-lean scan, 17th-thr)
    knn_xyz512_kernel<<<N8/16, 512, 0, stream>>>(pts, N8, ridx);

    // --- S8: refiner u/v gather-GEMMs, residual EdgeConv to output
    gatherpair_kernel<<<dim3(6, N8/64, 2), b16, 0, stream>>>(
        tfeat, xyz1,
        rw1, rw1 + 99*384, rb1, ur,
        rw1 + 99*384, NUL, NUL, vr,
        384, 99);
    edge_ref_kernel<<<N8/4, 256, 0, stream>>>(ur, vr, rw2, rb2, ridx, xyz1, out_tgt, N8);
}

// Round 17
// 416.421 us; speedup vs baseline: 1.1456x; 1.0090x over previous
//
#include <hip/hip_runtime.h>

#define N2 2048      // B*P
#define N8 8192      // B*P*UP
#define CDIM 384
#define H1C 192      // C/2
#define H2C 96       // C/4
#define PDIM 512
#define KRR 16
#define FOLDH 256
#define FOLDP 260
#define XCAP 256
#define XCAPX 128
#define XTILE 1024
#define INFF 3.0e38f

__device__ __forceinline__ float frelu(float x) { return x > 0.f ? x : 0.f; }

// ---------------- 64-lane bitonic sorts (ascending) --------------------------------
__device__ __forceinline__ void bitonic64_val(float& d, int lane) {
    #pragma unroll
    for (int k = 2; k <= 64; k <<= 1) {
        #pragma unroll
        for (int j = k >> 1; j > 0; j >>= 1) {
            float od = __shfl_xor(d, j);
            bool lower = (lane & j) == 0;
            bool olt = od < d;
            bool take = lower ? olt : !olt;
            if (lane & k) take = !take;
            if (take) d = od;
        }
    }
}

__device__ __forceinline__ void bitonic64_pair(float& d, int& c, int lane) {
    #pragma unroll
    for (int k = 2; k <= 64; k <<= 1) {
        #pragma unroll
        for (int j = k >> 1; j > 0; j >>= 1) {
            float od = __shfl_xor(d, j);
            int   oc = __shfl_xor(c, j);
            bool lower = (lane & j) == 0;
            bool olt = (od < d) || (od == d && oc < c);
            bool take = lower ? olt : !olt;
            if (lane & k) take = !take;
            if (take) { d = od; c = oc; }
        }
    }
}

// ---------------- slow exact select fallback (cnt > 64, rare) ----------------------
__device__ __forceinline__ void select_slow(const float* bd, const int* bi, int cnt,
                                            int ksel, int row, int n, int* out, int lane) {
    float cd[4]; int cix[4];
    #pragma unroll
    for (int s = 0; s < 4; ++s) {
        int c = lane + 64*s;
        bool v = c < cnt;
        cd[s]  = v ? bd[c] : INFF;
        cix[s] = v ? bi[c] : 0x7fffffff;
    }
    for (int r = 0; r < ksel; ++r) {
        float lv = cd[0]; int li = cix[0];
        #pragma unroll
        for (int s = 1; s < 4; ++s) {
            if (cd[s] < lv || (cd[s] == lv && cix[s] < li)) { lv = cd[s]; li = cix[s]; }
        }
        float wv = lv; int wi = li;
        #pragma unroll
        for (int s = 1; s < 64; s <<= 1) {
            float ov = __shfl_xor(wv, s); int oi = __shfl_xor(wi, s);
            if (ov < wv || (ov == wv && oi < wi)) { wv = ov; wi = oi; }
        }
        if (lane == 0) {
            int safe = ((unsigned)wi < (unsigned)n) ? wi : ((row + 1) & (n - 1));
            out[row*ksel + r] = safe;
        }
        #pragma unroll
        for (int s = 0; s < 4; ++s) {
            if (cd[s] == wv && cix[s] == wi) { cd[s] = INFF; cix[s] = 0x7fffffff; }
        }
    }
}

// ---------------- row squared norms (wave per row; single + paired) ----------------
__global__ __launch_bounds__(256) void rowsq_kernel(const float* __restrict__ x,
                                                    float* __restrict__ sq, int d) {
    int wave = threadIdx.x >> 6, lane = threadIdx.x & 63;
    int row = blockIdx.x*4 + wave;
    float acc = 0.f;
    for (int k = lane; k < d; k += 64) { float v = x[(size_t)row*d + k]; acc += v*v; }
    #pragma unroll
    for (int s = 1; s < 64; s <<= 1) acc += __shfl_xor(acc, s);
    if (lane == 0) sq[row] = acc;
}

__global__ __launch_bounds__(256) void rowsqpair_kernel(const float* __restrict__ xA,
                                                        float* __restrict__ sqA,
                                                        const float* __restrict__ xB,
                                                        float* __restrict__ sqB, int d) {
    const float* x = blockIdx.y ? xB : xA;
    float* sq = blockIdx.y ? sqB : sqA;
    int wave = threadIdx.x >> 6, lane = threadIdx.x & 63;
    int row = blockIdx.x*4 + wave;
    float acc = 0.f;
    for (int k = lane; k < d; k += 64) { float v = x[(size_t)row*d + k]; acc += v*v; }
    #pragma unroll
    for (int s = 1; s < 64; s <<= 1) acc += __shfl_xor(acc, s);
    if (lane == 0) sq[row] = acc;
}

// ---------------- triangular symmetric dist: direct + mirrored tile ----------------
__device__ __forceinline__ void disttri_body(const float* __restrict__ x, const float* __restrict__ sq,
                                             float* __restrict__ dist, int n, int K) {
    int l = blockIdx.x;
    int by = (int)((sqrtf(8.f*(float)l + 1.f) - 1.f)*0.5f);
    while ((by+1)*(by+2)/2 <= l) ++by;
    while (by*(by+1)/2 > l) --by;
    int bx = l - by*(by+1)/2;
    int row0 = by*64, col0 = bx*64;
    __shared__ __align__(16) float As[16][68];
    __shared__ __align__(16) float Bs[16][68];
    __shared__ __align__(16) float T[64][68];
    int tx = threadIdx.x, ty = threadIdx.y;
    int t = ty*16 + tx;
    float acc[4][4] = {};
    for (int k0 = 0; k0 < K; k0 += 16) {
        #pragma unroll
        for (int r = 0; r < 4; ++r) {
            int e = t + 256*r; int kk = e & 15, mm = e >> 4;
            As[kk][mm] = x[(size_t)(row0+mm)*K + k0+kk];
            Bs[kk][mm] = x[(size_t)(col0+mm)*K + k0+kk];
        }
        __syncthreads();
        #pragma unroll
        for (int kk = 0; kk < 16; ++kk) {
            float4 a4 = *(const float4*)&As[kk][ty*4];
            float4 b4 = *(const float4*)&Bs[kk][tx*4];
            acc[0][0] += a4.x*b4.x; acc[0][1] += a4.x*b4.y; acc[0][2] += a4.x*b4.z; acc[0][3] += a4.x*b4.w;
            acc[1][0] += a4.y*b4.x; acc[1][1] += a4.y*b4.y; acc[1][2] += a4.y*b4.z; acc[1][3] += a4.y*b4.w;
            acc[2][0] += a4.z*b4.x; acc[2][1] += a4.z*b4.y; acc[2][2] += a4.z*b4.z; acc[2][3] += a4.z*b4.w;
            acc[3][0] += a4.w*b4.x; acc[3][1] += a4.w*b4.y; acc[3][2] += a4.w*b4.z; acc[3][3] += a4.w*b4.w;
        }
        __syncthreads();
    }
    bool mirror = (row0 != col0);
    #pragma unroll
    for (int i2 = 0; i2 < 4; ++i2) {
        int row = row0 + ty*4 + i2;
        float sr = sq[row];
        float4 o;
        o.x = sr + sq[col0+tx*4+0] - 2.f*acc[i2][0];
        o.y = sr + sq[col0+tx*4+1] - 2.f*acc[i2][1];
        o.z = sr + sq[col0+tx*4+2] - 2.f*acc[i2][2];
        o.w = sr + sq[col0+tx*4+3] - 2.f*acc[i2][3];
        *(float4*)&dist[(size_t)row*n + col0 + tx*4] = o;
        if (mirror) {
            T[tx*4+0][ty*4+i2] = o.x;
            T[tx*4+1][ty*4+i2] = o.y;
            T[tx*4+2][ty*4+i2] = o.z;
            T[tx*4+3][ty*4+i2] = o.w;
        }
    }
    if (mirror) {
        __syncthreads();
        #pragma unroll
        for (int i2 = 0; i2 < 4; ++i2) {
            int orow = col0 + ty*4 + i2;
            float4 o = *(const float4*)&T[ty*4+i2][tx*4];
            *(float4*)&dist[(size_t)orow*n + row0 + tx*4] = o;
        }
    }
}

__global__ __launch_bounds__(256) void dist64tri_kernel(const float* __restrict__ x,
                                                        const float* __restrict__ sq,
                                                        float* __restrict__ dist, int n, int K) {
    disttri_body(x, sq, dist, n, K);
}

__global__ __launch_bounds__(256) void distpairtri_kernel(const float* __restrict__ xA,
                                                          const float* __restrict__ sqA,
                                                          float* __restrict__ dA,
                                                          const float* __restrict__ xB,
                                                          const float* __restrict__ sqB,
                                                          float* __restrict__ dB, int n, int K) {
    const float* x  = blockIdx.z ? xB : xA;
    const float* sq = blockIdx.z ? sqB : sqA;
    float* dist     = blockIdx.z ? dB : dA;
    disttri_body(x, sq, dist, n, K);
}

// ---------------- 16x64 GEMM tile (high block count for small GEMMs) ---------------
__device__ __forceinline__ void gemm16_body(const float* __restrict__ A, const float* __restrict__ Bw,
                                            const float* __restrict__ BwB, const float* __restrict__ bias,
                                            float* __restrict__ C, int m, int K) {
    __shared__ __align__(16) float As[16][17];
    __shared__ __align__(16) float Bs[16][68];
    int tx = threadIdx.x, ty = threadIdx.y;
    int t = ty*16 + tx;
    int row0 = blockIdx.y*16, col0 = blockIdx.x*64;
    float acc[4] = {};
    for (int k0 = 0; k0 < K; k0 += 16) {
        {
            int kk = t & 15, mm = t >> 4;
            As[kk][mm] = (k0 + kk < K) ? A[(size_t)(row0+mm)*K + k0+kk] : 0.f;
        }
        #pragma unroll
        for (int r = 0; r < 4; ++r) {
            int e = t + 256*r; int nn = e & 63, kk = e >> 6;
            int col = col0 + nn, k = k0 + kk;
            float bv = 0.f;
            if (k < K && col < m) {
                bv = Bw[(size_t)k*m + col];
                if (BwB) bv -= BwB[(size_t)k*m + col];
            }
            Bs[kk][nn] = bv;
        }
        __syncthreads();
        #pragma unroll
        for (int kk = 0; kk < 16; ++kk) {
            float a = As[kk][ty];
            float4 b4 = *(const float4*)&Bs[kk][tx*4];
            acc[0] += a*b4.x; acc[1] += a*b4.y; acc[2] += a*b4.z; acc[3] += a*b4.w;
        }
        __syncthreads();
    }
    int row = row0 + ty;
    #pragma unroll
    for (int j2 = 0; j2 < 4; ++j2) {
        int col = col0 + tx*4 + j2;
        if (col < m) C[(size_t)row*m + col] = acc[j2] + (bias ? bias[col] : 0.f);
    }
}

__global__ __launch_bounds__(256) void gemm16quad_kernel(
    const float* A0, const float* Bw0, const float* BwB0, const float* bias0, float* C0,
    const float* A1, const float* Bw1, const float* BwB1, const float* bias1, float* C1,
    const float* A2, const float* Bw2, const float* BwB2, const float* bias2, float* C2,
    const float* A3, const float* Bw3, const float* BwB3, const float* bias3, float* C3,
    int m, int K) {
    int z = blockIdx.z;
    const float* A    = (z==0)?A0 :(z==1)?A1 :(z==2)?A2 :A3;
    const float* Bw   = (z==0)?Bw0:(z==1)?Bw1:(z==2)?Bw2:Bw3;
    const float* BwB  = (z==0)?BwB0:(z==1)?BwB1:(z==2)?BwB2:BwB3;
    const float* bias = (z==0)?bias0:(z==1)?bias1:(z==2)?bias2:bias3;
    float* C          = (z==0)?C0 :(z==1)?C1 :(z==2)?C2 :C3;
    gemm16_body(A, Bw, BwB, bias, C, m, K);
}

// ---------------- EdgeConv layer-2 gather-GEMM, reg-max, coalesced fill ------------
template<int EPT, int SELF, int EREAL, int IDXS, int YT>
__device__ __forceinline__ void edge_fused_body(const float* __restrict__ u, const float* __restrict__ v,
                                                const int* __restrict__ idx,
                                                const float* __restrict__ Bw, const float* __restrict__ bias,
                                                float* __restrict__ hout, int m, int K, int npts) {
    if ((int)blockIdx.y >= YT) return;
    constexpr int LOG2EPT = (EPT == 16) ? 4 : (EPT == 8) ? 3 : 2;
    __shared__ __align__(16) float As[16][68];
    __shared__ __align__(16) float Bs[16][68];
    int tx = threadIdx.x, ty = threadIdx.y;
    int t = ty*16 + tx;
    int row0 = blockIdx.y*64, col0 = blockIdx.x*64;
    int mmA = t >> 2;
    int kqA = (t & 3) * 4;
    int rowA = row0 + mmA;
    int iA = rowA >> LOG2EPT;
    int eA = rowA - (iA << LOG2EPT);
    int jA;
    if (SELF && eA == 0) jA = iA;
    else if (eA < EREAL) jA = idx[iA*IDXS + (eA - SELF)];
    else jA = iA;
    jA = ((unsigned)jA < (unsigned)npts) ? jA : iA;
    const float* uRow = u + (size_t)iA*K + kqA;
    const float* vRow = v + (size_t)jA*K + kqA;
    int nnB = (t & 15) * 4, kkB = t >> 4;
    float acc[4][4] = {};
    for (int k0 = 0; k0 < K; k0 += 16) {
        float4 u4 = *(const float4*)(uRow + k0);
        float4 v4 = *(const float4*)(vRow + k0);
        As[kqA+0][mmA] = frelu(u4.x + v4.x);
        As[kqA+1][mmA] = frelu(u4.y + v4.y);
        As[kqA+2][mmA] = frelu(u4.z + v4.z);
        As[kqA+3][mmA] = frelu(u4.w + v4.w);
        int colB = col0 + nnB;
        if (colB + 3 < m) {
            *(float4*)&Bs[kkB][nnB] = *(const float4*)&Bw[(size_t)(k0+kkB)*m + colB];
        } else {
            #pragma unroll
            for (int q = 0; q < 4; ++q) {
                int col = colB + q;
                Bs[kkB][nnB+q] = (col < m) ? Bw[(size_t)(k0+kkB)*m + col] : 0.f;
            }
        }
        __syncthreads();
        #pragma unroll
        for (int kk = 0; kk < 16; ++kk) {
            float4 a4 = *(const float4*)&As[kk][ty*4];
            float4 b4 = *(const float4*)&Bs[kk][tx*4];
            acc[0][0] += a4.x*b4.x; acc[0][1] += a4.x*b4.y; acc[0][2] += a4.x*b4.z; acc[0][3] += a4.x*b4.w;
            acc[1][0] += a4.y*b4.x; acc[1][1] += a4.y*b4.y; acc[1][2] += a4.y*b4.z; acc[1][3] += a4.y*b4.w;
            acc[2][0] += a4.z*b4.x; acc[2][1] += a4.z*b4.y; acc[2][2] += a4.z*b4.z; acc[2][3] += a4.z*b4.w;
            acc[3][0] += a4.w*b4.x; acc[3][1] += a4.w*b4.y; acc[3][2] += a4.w*b4.z; acc[3][3] += a4.w*b4.w;
        }
        __syncthreads();
    }
    float bestv[4];
    #pragma unroll
    for (int j2 = 0; j2 < 4; ++j2)
        bestv[j2] = fmaxf(fmaxf(acc[0][j2], acc[1][j2]), fmaxf(acc[2][j2], acc[3][j2]));
    if (EPT >= 8) {
        #pragma unroll
        for (int j2 = 0; j2 < 4; ++j2) bestv[j2] = fmaxf(bestv[j2], __shfl_xor(bestv[j2], 16));
    }
    if (EPT == 16) {
        #pragma unroll
        for (int j2 = 0; j2 < 4; ++j2) bestv[j2] = fmaxf(bestv[j2], __shfl_xor(bestv[j2], 32));
    }
    bool writer; int p;
    if (EPT == 16) { writer = (ty & 3) == 0; p = (row0 >> 4) + (ty >> 2); }
    else if (EPT == 8) { writer = (ty & 1) == 0; p = (row0 >> 3) + (ty >> 1); }
    else { writer = true; p = (row0 >> 2) + ty; }
    if (writer) {
        #pragma unroll
        for (int j2 = 0; j2 < 4; ++j2) {
            int col = col0 + tx*4 + j2;
            if (col < m) hout[(size_t)p*m + col] = bestv[j2] + bias[col];
        }
    }
}

__global__ __launch_bounds__(256) void edge_fused1_kernel(const float* u1, const float* v1,
                                                          const int* cidx1,
                                                          const float* Bw, const float* bias,
                                                          float* h_ctx, float* h_tgt, int npts) {
    if (blockIdx.z == 0) edge_fused_body<16,0,16,16,512>(u1, v1, cidx1, Bw, bias, h_ctx, H1C, H1C, npts);
    else                 edge_fused_body<8,1,5,16,256>(u1, v1, cidx1, Bw, bias, h_tgt, H1C, H1C, npts);
}

__global__ __launch_bounds__(256) void edge_fused2_kernel(const float* u2c, const float* v2c,
                                                          const float* u2t, const float* v2t,
                                                          const int* cidx2, const int* tidx2,
                                                          const float* Bw, const float* bias,
                                                          float* cfeat, float* tfeat, int npts) {
    if (blockIdx.z == 0) edge_fused_body<8,0,8,8,256>(u2c, v2c, cidx2, Bw, bias, cfeat, H2C, H2C, npts);
    else                 edge_fused_body<4,1,3,2,128>(u2t, v2t, tidx2, Bw, bias, tfeat, H2C, H2C, npts);
}

// ---------------- ctx deform head: out = xyz + 0.05 * mlp2(cfeat) ------------------
__global__ __launch_bounds__(128) void cdef_kernel(const float* __restrict__ cfeat,
                                                   const float* __restrict__ cdw1, const float* __restrict__ cdb1,
                                                   const float* __restrict__ cdw2, const float* __restrict__ cdb2,
                                                   const float* __restrict__ ctx_xyz,
                                                   float* __restrict__ out_ctx) {
    int i = blockIdx.x, tid = threadIdx.x, wave = tid >> 6, lane = tid & 63;
    __shared__ float sf_[96], st2_[96];
    if (tid < 96) sf_[tid] = cfeat[(size_t)i*H2C + tid];
    __syncthreads();
    if (tid < 96) {
        float a = cdb1[tid];
        for (int k = 0; k < 96; ++k) a += sf_[k]*cdw1[k*96 + tid];
        st2_[tid] = frelu(a);
    }
    __syncthreads();
    if (wave == 0) {
        float s0 = st2_[lane];
        float p0 = s0*cdw2[lane*3+0], p1 = s0*cdw2[lane*3+1], p2 = s0*cdw2[lane*3+2];
        if (lane < 32) {
            float s1 = st2_[lane+64];
            p0 += s1*cdw2[(lane+64)*3+0];
            p1 += s1*cdw2[(lane+64)*3+1];
            p2 += s1*cdw2[(lane+64)*3+2];
        }
        #pragma unroll
        for (int s = 1; s < 64; s <<= 1) {
            p0 += __shfl_xor(p0, s); p1 += __shfl_xor(p1, s); p2 += __shfl_xor(p2, s);
        }
        if (lane == 0) {
            out_ctx[i*3+0] = ctx_xyz[i*3+0] + 0.05f*(cdb2[0] + p0);
            out_ctx[i*3+1] = ctx_xyz[i*3+1] + 0.05f*(cdb2[1] + p1);
            out_ctx[i*3+2] = ctx_xyz[i*3+2] + 0.05f*(cdb2[2] + p2);
        }
    }
}

// refiner gather-GEMM pair: A row gathered from [featd(96) | xyzg(3)], K = 99
__global__ __launch_bounds__(256) void gatherpair_kernel(
    const float* __restrict__ featd, const float* __restrict__ xyzg,
    const float* Bw0, const float* BwB0, const float* bias0, float* C0,
    const float* Bw1, const float* BwB1, const float* bias1, float* C1,
    int m, int K) {
    int z = blockIdx.z;
    const float* Bw   = z ? Bw1 : Bw0;
    const float* BwB  = z ? BwB1 : BwB0;
    const float* bias = z ? bias1 : bias0;
    float* C          = z ? C1 : C0;
    __shared__ __align__(16) float As[16][68];
    __shared__ __align__(16) float Bs[16][68];
    int tx = threadIdx.x, ty = threadIdx.y;
    int t = ty*16 + tx;
    int row0 = blockIdx.y*64, col0 = blockIdx.x*64;
    float acc[4][4] = {};
    for (int k0 = 0; k0 < K; k0 += 16) {
        #pragma unroll
        for (int r = 0; r < 4; ++r) {
            int e = t + 256*r; int kk = e & 15, mm = e >> 4;
            int k = k0 + kk, grow = row0 + mm;
            float av = 0.f;
            if (k < K) {
                if (k < 96) { int b = grow >> 11, p = (grow & 2047) >> 2;
                              av = featd[(size_t)(b*PDIM + p)*H2C + k]; }
                else av = xyzg[(size_t)grow*3 + (k - 96)];
            }
            As[kk][mm] = av;
        }
        #pragma unroll
        for (int r = 0; r < 4; ++r) {
            int e = t + 256*r; int nn = e & 63, kk = e >> 6;
            int col = col0 + nn, k = k0 + kk;
            float bv = 0.f;
            if (k < K && col < m) {
                bv = Bw[(size_t)k*m + col];
                if (BwB) bv -= BwB[(size_t)k*m + col];
            }
            Bs[kk][nn] = bv;
        }
        __syncthreads();
        #pragma unroll
        for (int kk = 0; kk < 16; ++kk) {
            float4 a4 = *(const float4*)&As[kk][ty*4];
            float4 b4 = *(const float4*)&Bs[kk][tx*4];
            acc[0][0] += a4.x*b4.x; acc[0][1] += a4.x*b4.y; acc[0][2] += a4.x*b4.z; acc[0][3] += a4.x*b4.w;
            acc[1][0] += a4.y*b4.x; acc[1][1] += a4.y*b4.y; acc[1][2] += a4.y*b4.z; acc[1][3] += a4.y*b4.w;
            acc[2][0] += a4.z*b4.x; acc[2][1] += a4.z*b4.y; acc[2][2] += a4.z*b4.z; acc[2][3] += a4.z*b4.w;
            acc[3][0] += a4.w*b4.x; acc[3][1] += a4.w*b4.y; acc[3][2] += a4.w*b4.z; acc[3][3] += a4.w*b4.w;
        }
        __syncthreads();
    }
    #pragma unroll
    for (int i2 = 0; i2 < 4; ++i2) {
        int row = row0 + ty*4 + i2;
        #pragma unroll
        for (int j2 = 0; j2 < 4; ++j2) {
            int col = col0 + tx*4 + j2;
            if (col < m) C[(size_t)row*m + col] = acc[i2][j2] + (bias ? bias[col] : 0.f);
        }
    }
}

// ---------------- knn from dist rows (4 rows/block, bitonic select) ----------------
__global__ __launch_bounds__(256) void knn_dist_rt_kernel(const float* __restrict__ dA,
                                                          const float* __restrict__ dB, int n,
                                                          int* __restrict__ outA, int* __restrict__ outB,
                                                          int kA, int kB, int nblkA) {
    int wave = threadIdx.x >> 6, lane = threadIdx.x & 63;
    bool useB = (int)blockIdx.x >= nblkA;
    const float* dist = useB ? dB : dA;
    int* out = useB ? outB : outA;
    int ksel = useB ? kB : kA;
    int bx = useB ? (int)blockIdx.x - nblkA : (int)blockIdx.x;
    int row = bx*4 + wave;
    __shared__ float bufd[4][XCAP];
    __shared__ int   bufi[4][XCAP];
    __shared__ int   lcnt[4];
    const float4* drow = (const float4*)(dist + (size_t)row*n);
    int nq = n >> 2;
    float mv = INFF;
    for (int i = lane; i < nq; i += 64) {
        float4 d4 = drow[i]; int base = i*4;
        float a = (base+0 == row) ? INFF : d4.x;
        float b = (base+1 == row) ? INFF : d4.y;
        float c = (base+2 == row) ? INFF : d4.z;
        float d = (base+3 == row) ? INFF : d4.w;
        mv = fminf(mv, fminf(fminf(a,b), fminf(c,d)));
    }
    float sd = mv;
    bitonic64_val(sd, lane);
    float Tv = __shfl(sd, ksel - 1);
    if (lane == 0) lcnt[wave] = 0;
    for (int i = lane; i < nq; i += 64) {
        float4 d4 = drow[i]; int base = i*4;
        float dv4[4] = {d4.x, d4.y, d4.z, d4.w};
        #pragma unroll
        for (int q = 0; q < 4; ++q) {
            int col = base + q;
            if (col != row && dv4[q] <= Tv) {
                int pos = atomicAdd(&lcnt[wave], 1);
                if (pos < XCAP) { bufd[wave][pos] = dv4[q]; bufi[wave][pos] = col; }
            }
        }
    }
    int cnt = lcnt[wave]; if (cnt > XCAP) cnt = XCAP;
    if (cnt <= 64) {
        float d = (lane < cnt) ? bufd[wave][lane] : INFF;
        int   c = (lane < cnt) ? bufi[wave][lane] : 0x7fffffff;
        bitonic64_pair(d, c, lane);
        if (lane < ksel) {
            int safe = ((unsigned)c < (unsigned)n) ? c : ((row + 1) & (n - 1));
            out[row*ksel + lane] = safe;
        }
    } else {
        select_slow(bufd[wave], bufi[wave], cnt, ksel, row, n, out, lane);
    }
}

// ---------------- knn over packed xyz: 16 rows/block, 512 thr, 2 rows/wave ---------
__global__ __launch_bounds__(512) void knn_xyz512_kernel(const float4* __restrict__ pts, int n,
                                                         int* __restrict__ out_idx) {
    int tid = threadIdx.x, wave = tid >> 6, lane = tid & 63;
    int rbase = blockIdx.x*16 + wave*2;
    __shared__ __align__(16) float4 tile[XTILE];
    __shared__ float bufd[16][XCAPX];
    __shared__ int   bufi[16][XCAPX];
    __shared__ int   lcnt[16];
    float4 P0 = pts[rbase], P1 = pts[rbase+1];
    float nx0 = -2.f*P0.x, ny0 = -2.f*P0.y, nz0 = -2.f*P0.z, sr0 = P0.w;
    float nx1 = -2.f*P1.x, ny1 = -2.f*P1.y, nz1 = -2.f*P1.z, sr1 = P1.w;
    float mv0 = INFF, mv1 = INFF;
    for (int t0 = 0; t0 < n; t0 += XTILE) {
        __syncthreads();
        #pragma unroll
        for (int k = 0; k < XTILE/512; ++k) tile[tid + 512*k] = pts[t0 + tid + 512*k];
        __syncthreads();
        for (int c = lane; c < XTILE; c += 64) {
            float4 q = tile[c];
            float d0 = fmaf(nx0, q.x, fmaf(ny0, q.y, fmaf(nz0, q.z, sr0 + q.w)));
            float d1 = fmaf(nx1, q.x, fmaf(ny1, q.y, fmaf(nz1, q.z, sr1 + q.w)));
            mv0 = fminf(mv0, d0);
            mv1 = fminf(mv1, d1);
        }
    }
    bitonic64_val(mv0, lane);
    bitonic64_val(mv1, lane);
    float Tv0 = __shfl(mv0, 16), Tv1 = __shfl(mv1, 16);   // 17th smallest (self-safe)
    if (lane < 2) lcnt[wave*2 + lane] = 0;
    for (int t0 = 0; t0 < n; t0 += XTILE) {
        __syncthreads();
        #pragma unroll
        for (int k = 0; k < XTILE/512; ++k) tile[tid + 512*k] = pts[t0 + tid + 512*k];
        __syncthreads();
        for (int c = lane; c < XTILE; c += 64) {
            float4 q = tile[c];
            int col = t0 + c;
            float d0 = fmaf(nx0, q.x, fmaf(ny0, q.y, fmaf(nz0, q.z, sr0 + q.w)));
            float d1 = fmaf(nx1, q.x, fmaf(ny1, q.y, fmaf(nz1, q.z, sr1 + q.w)));
            if (col != rbase && d0 <= Tv0) {
                int pos = atomicAdd(&lcnt[wave*2+0], 1);
                if (pos < XCAPX) { bufd[wave*2+0][pos] = d0; bufi[wave*2+0][pos] = col; }
            }
            if (col != rbase+1 && d1 <= Tv1) {
                int pos = atomicAdd(&lcnt[wave*2+1], 1);
                if (pos < XCAPX) { bufd[wave*2+1][pos] = d1; bufi[wave*2+1][pos] = col; }
            }
        }
    }
    for (int jj = 0; jj < 2; ++jj) {
        int brow = wave*2 + jj, row = rbase + jj;
        int cnt = lcnt[brow]; if (cnt > XCAPX) cnt = XCAPX;
        if (cnt <= 64) {
            float d = (lane < cnt) ? bufd[brow][lane] : INFF;
            int   c = (lane < cnt) ? bufi[brow][lane] : 0x7fffffff;
            bitonic64_pair(d, c, lane);
            if (lane < 16) {
                int safe = ((unsigned)c < (unsigned)n) ? c : ((row + 1) & (n - 1));
                out_idx[row*16 + lane] = safe;
            }
        } else {
            float cd[2]; int cix[2];
            #pragma unroll
            for (int s = 0; s < 2; ++s) {
                int c = lane + 64*s;
                bool v = c < cnt;
                cd[s]  = v ? bufd[brow][c] : INFF;
                cix[s] = v ? bufi[brow][c] : 0x7fffffff;
            }
            for (int r = 0; r < 16; ++r) {
                float lv = cd[0]; int li = cix[0];
                if (cd[1] < lv || (cd[1] == lv && cix[1] < li)) { lv = cd[1]; li = cix[1]; }
                float wv = lv; int wi = li;
                #pragma unroll
                for (int s = 1; s < 64; s <<= 1) {
                    float ov = __shfl_xor(wv, s); int oi = __shfl_xor(wi, s);
                    if (ov < wv || (ov == wv && oi < wi)) { wv = ov; wi = oi; }
                }
                if (lane == 0) {
                    int safe = ((unsigned)wi < (unsigned)n) ? wi : ((row + 1) & (n - 1));
                    out_idx[row*16 + r] = safe;
                }
                #pragma unroll
                for (int s = 0; s < 2; ++s) {
                    if (cd[s] == wv && cix[s] == wi) { cd[s] = INFF; cix[s] = 0x7fffffff; }
                }
            }
        }
    }
}

// ---------------- refiner EdgeConv (H1=384, H2=3), wave per point ------------------
__global__ __launch_bounds__(256) void edge_ref_kernel(const float* __restrict__ ur,
                                                       const float* __restrict__ vr,
                                                       const float* __restrict__ w2,
                                                       const float* __restrict__ b2,
                                                       const int* __restrict__ idx,
                                                       const float* __restrict__ xyz_in,
                                                       float* __restrict__ out, int n) {
    int wave = threadIdx.x >> 6, lane = threadIdx.x & 63;
    int i = blockIdx.x*4 + wave;
    if (i >= n) return;
    float m0 = -INFF, m1 = -INFF, m2 = -INFF;
    float uh[6];
    #pragma unroll
    for (int t = 0; t < 6; ++t) uh[t] = ur[(size_t)i*384 + lane + 64*t];
    for (int e = 0; e < KRR; ++e) {
        int j = idx[i*KRR + e];
        j = ((unsigned)j < (unsigned)n) ? j : i;
        float a0 = 0.f, a1 = 0.f, a2 = 0.f;
        #pragma unroll
        for (int t = 0; t < 6; ++t) {
            int h = lane + 64*t;
            float tv = frelu(uh[t] + vr[(size_t)j*384 + h]);
            a0 += tv*w2[h*3+0]; a1 += tv*w2[h*3+1]; a2 += tv*w2[h*3+2];
        }
        #pragma unroll
        for (int s = 32; s > 0; s >>= 1) {
            a0 += __shfl_xor(a0, s); a1 += __shfl_xor(a1, s); a2 += __shfl_xor(a2, s);
        }
        m0 = fmaxf(m0, a0 + b2[0]); m1 = fmaxf(m1, a1 + b2[1]); m2 = fmaxf(m2, a2 + b2[2]);
    }
    if (lane == 0) {
        out[i*3+0] = xyz_in[i*3+0] + m0;
        out[i*3+1] = xyz_in[i*3+1] + m1;
        out[i*3+2] = xyz_in[i*3+2] + m2;
    }
}

// ---------------- folding MLP: PTS=8, padded LDS (20 KB, 1024 blocks) --------------
__global__ __launch_bounds__(256) void fold_kernel(const float* __restrict__ pred_xyz,
                                                   const float* __restrict__ noise,
                                                   const float* __restrict__ featd,
                                                   const float* __restrict__ w1, const float* __restrict__ b1,
                                                   const float* __restrict__ w2, const float* __restrict__ b2,
                                                   const float* __restrict__ w3, const float* __restrict__ b3,
                                                   float* __restrict__ xyz1, float4* __restrict__ pts_out) {
    const int PTS = 8;
    int base = blockIdx.x * PTS;
    int tid = threadIdx.x;
    __shared__ __align__(16) float xin[PTS][104];
    __shared__ __align__(16) float h1[PTS][FOLDP];
    __shared__ __align__(16) float h2s[PTS][FOLDP];
    __shared__ float oxyz[PTS][3];
    for (int t = tid; t < PTS*100; t += 256) {
        int pt = t/100, k = t - pt*100;
        int gi = base + pt;
        float vv = 0.f;
        if (k < 3) {
            int b = gi >> 11, p = (gi & 2047) >> 2;
            vv = pred_xyz[(size_t)(b*PDIM + p)*3 + k] + 0.02f*noise[(size_t)gi*3 + k];
        } else if (k < 99) {
            int b = gi >> 11, p = (gi & 2047) >> 2;
            vv = featd[(size_t)(b*PDIM + p)*H2C + (k - 3)];
        }
        xin[pt][k] = vv;
    }
    __syncthreads();
    int c = tid;
    float acc[PTS];
    #pragma unroll
    for (int pt = 0; pt < PTS; ++pt) acc[pt] = b1[c];
    for (int k0 = 0; k0 < 96; k0 += 4) {
        float wa = w1[(k0+0)*FOLDH + c], wb = w1[(k0+1)*FOLDH + c];
        float wc = w1[(k0+2)*FOLDH + c], wd = w1[(k0+3)*FOLDH + c];
        #pragma unroll
        for (int pt = 0; pt < PTS; ++pt) {
            float4 xv = *(const float4*)&xin[pt][k0];
            acc[pt] += xv.x*wa + xv.y*wb + xv.z*wc + xv.w*wd;
        }
    }
    {
        float wa = w1[96*FOLDH + c], wb = w1[97*FOLDH + c], wc = w1[98*FOLDH + c];
        #pragma unroll
        for (int pt = 0; pt < PTS; ++pt) {
            float4 xv = *(const float4*)&xin[pt][96];
            acc[pt] += xv.x*wa + xv.y*wb + xv.z*wc;
        }
    }
    #pragma unroll
    for (int pt = 0; pt < PTS; ++pt) h1[pt][c] = frelu(acc[pt]);
    __syncthreads();
    #pragma unroll
    for (int pt = 0; pt < PTS; ++pt) acc[pt] = b2[c];
    for (int k0 = 0; k0 < FOLDH; k0 += 4) {
        float wa = w2[(k0+0)*FOLDH + c], wb = w2[(k0+1)*FOLDH + c];
        float wc = w2[(k0+2)*FOLDH + c], wd = w2[(k0+3)*FOLDH + c];
        #pragma unroll
        for (int pt = 0; pt < PTS; ++pt) {
            float4 hv = *(const float4*)&h1[pt][k0];
            acc[pt] += hv.x*wa + hv.y*wb + hv.z*wc + hv.w*wd;
        }
    }
    #pragma unroll
    for (int pt = 0; pt < PTS; ++pt) h2s[pt][c] = frelu(acc[pt]);
    __syncthreads();
    if (tid < PTS*3) {
        int pt = tid/3, cc = tid - pt*3;
        float a = b3[cc];
        for (int k0 = 0; k0 < FOLDH; k0 += 4) {
            float4 hv = *(const float4*)&h2s[pt][k0];
            a += hv.x*w3[(k0+0)*3+cc] + hv.y*w3[(k0+1)*3+cc] + hv.z*w3[(k0+2)*3+cc] + hv.w*w3[(k0+3)*3+cc];
        }
        int gi = base + pt;
        float res = xin[pt][cc] + a;
        xyz1[(size_t)gi*3 + cc] = res;
        oxyz[pt][cc] = res;
    }
    __syncthreads();
    if (tid < PTS) {
        float x = oxyz[tid][0], y = oxyz[tid][1], z = oxyz[tid][2];
        pts_out[base + tid] = make_float4(x, y, z, x*x + y*y + z*z);
    }
}

extern "C" void kernel_launch(void* const* d_in, const int* in_sizes, int n_in,
                              void* d_out, int out_size, void* d_ws, size_t ws_size,
                              hipStream_t stream) {
    const float* ctx_xyz    = (const float*)d_in[0];
    const float* ctx_tokens = (const float*)d_in[1];
    const float* pred_xyz   = (const float*)d_in[2];
    const float* noise      = (const float*)d_in[4];
    const float* c1w1 = (const float*)d_in[5];
    const float* c1b1 = (const float*)d_in[6];
    const float* c1w2 = (const float*)d_in[7];
    const float* c1b2 = (const float*)d_in[8];
    const float* c2w1 = (const float*)d_in[9];
    const float* c2b1 = (const float*)d_in[10];
    const float* c2w2 = (const float*)d_in[11];
    const float* c2b2 = (const float*)d_in[12];
    const float* cdw1 = (const float*)d_in[13];
    const float* cdb1 = (const float*)d_in[14];
    const float* cdw2 = (const float*)d_in[15];
    const float* cdb2 = (const float*)d_in[16];
    const float* fw1  = (const float*)d_in[17];
    const float* fb1  = (const float*)d_in[18];
    const float* fw2  = (const float*)d_in[19];
    const float* fb2  = (const float*)d_in[20];
    const float* fw3  = (const float*)d_in[21];
    const float* fb3  = (const float*)d_in[22];
    const float* rw1  = (const float*)d_in[23];
    const float* rb1  = (const float*)d_in[24];
    const float* rw2  = (const float*)d_in[25];
    const float* rb2  = (const float*)d_in[26];

    float* W = (float*)d_ws;
    // Zone A (staged aliasing): dist/distB (S1/S3) -> cfeat (S4) -> ur/vr (S8)
    float* dist  = W;                   // 2048*2048
    float* distB = W + 4194304;
    float* cfeat = W;                   // 2048*96 (after dist dead)
    float* ur    = W;                   // 8192*384 (after cfeat dead)
    float* vr    = W + 3145728;
    // Persistent zone:
    float* h_ctx = W + 8388608;         // 393,216
    float* h_tgt = h_ctx + 393216;
    float* UV    = h_tgt + 393216;      // [u1|v1] then [u2c|v2c|u2t|v2t]
    float* u1  = UV;            float* v1  = UV + 393216;
    float* u2c = UV;            float* v2c = UV + 196608;
    float* u2t = UV + 393216;   float* v2t = UV + 589824;
    float* tfeat = UV + 786432;         // 196,608
    float* xyz1  = tfeat + 196608;      // 24,576
    float4* pts  = (float4*)(xyz1 + 24576);
    float* sqb     = (float*)pts + 32768;
    float* sq_hctx = sqb + N2;
    float* sq_htgt = sq_hctx + N2;
    int* cidx1 = (int*)(sq_htgt + N2);
    int* cidx2 = cidx1 + N2*16;
    int* tidx2 = cidx2 + N2*8;
    int* ridx  = tidx2 + N2*2;

    float* out_ctx = (float*)d_out;
    float* out_tgt = out_ctx + N2*3;

    dim3 b16(16, 16);
    const int NTRI = 32*33/2;
    const float* NUL = nullptr;

    // --- S1: rowsq, dist(tokens), knn16 (tgt conv1 uses first 4 of cidx1)
    rowsq_kernel<<<N2/4, 256, 0, stream>>>(ctx_tokens, sqb, CDIM);
    dist64tri_kernel<<<NTRI, b16, 0, stream>>>(ctx_tokens, sqb, dist, N2, CDIM);
    knn_dist_rt_kernel<<<N2/4, 256, 0, stream>>>(dist, dist, N2, cidx1, cidx1, 16, 16, N2/4);

    // --- S2: u1/v1 GEMMs (16-row tiles); conv1 fused; row-sq
    gemm16quad_kernel<<<dim3(3, 128, 2), b16, 0, stream>>>(
        ctx_tokens, c1w1, c1w1 + 384*192, c1b1, u1,
        ctx_tokens, c1w1 + 384*192, NUL, NUL, v1,
        ctx_tokens, c1w1, NUL, NUL, u1,   // unused (z<2)
        ctx_tokens, c1w1, NUL, NUL, v1,
        H1C, CDIM);
    edge_fused1_kernel<<<dim3(3, 512, 2), b16, 0, stream>>>(u1, v1, cidx1, c1w2, c1b2,
                                                            h_ctx, h_tgt, N2);
    rowsqpair_kernel<<<dim3(N2/4, 2), 256, 0, stream>>>(h_ctx, sq_hctx, h_tgt, sq_htgt, H1C);

    // --- S3: dist(h_ctx)+dist(h_tgt), paired knn, u2/v2 quad (16-row tiles)
    distpairtri_kernel<<<dim3(NTRI, 1, 2), b16, 0, stream>>>(h_ctx, sq_hctx, dist,
                                                             h_tgt, sq_htgt, distB, N2, H1C);
    knn_dist_rt_kernel<<<2*(N2/4), 256, 0, stream>>>(dist, distB, N2, cidx2, tidx2, 8, 2, N2/4);
    gemm16quad_kernel<<<dim3(2, 128, 4), b16, 0, stream>>>(
        h_ctx, c2w1, c2w1 + 192*96, c2b1, u2c,
        h_ctx, c2w1 + 192*96, NUL, NUL, v2c,
        h_tgt, c2w1, c2w1 + 192*96, c2b1, u2t,
        h_tgt, c2w1 + 192*96, NUL, NUL, v2t,
        H2C, H1C);

    // --- S4: conv2 fused gather-GEMM+reg-max; cdef head
    edge_fused2_kernel<<<dim3(2, 256, 2), b16, 0, stream>>>(u2c, v2c, u2t, v2t, cidx2, tidx2,
                                                            c2w2, c2b2, cfeat, tfeat, N2);
    cdef_kernel<<<N2, 128, 0, stream>>>(cfeat, cdw1, cdb1, cdw2, cdb2, ctx_xyz, out_ctx);

    // --- S6: folding MLP (PTS=8, padded LDS; emits xyz1 + packed pts)
    fold_kernel<<<N8/8, 256, 0, stream>>>(pred_xyz, noise, tfeat, fw1, fb1, fw2, fb2, fw3, fb3, xyz1, pts);

    // --- S7: refiner knn (512 thr, 2 rows/wave, fmaf-lean scan, 17th-thr)
    knn_xyz512_kernel<<<N8/16, 512, 0, stream>>>(pts, N8, ridx);

    // --- S8: refiner u/v gather-GEMMs, residual EdgeConv to output
    gatherpair_kernel<<<dim3(6, N8/64, 2), b16, 0, stream>>>(
        tfeat, xyz1,
        rw1, rw1 + 99*384, rb1, ur,
        rw1 + 99*384, NUL, NUL, vr,
        384, 99);
    edge_ref_kernel<<<N8/4, 256, 0, stream>>>(ur, vr, rw2, rb2, ridx, xyz1, out_tgt, N8);
}